// Round 10
// baseline (934.029 us; speedup 1.0000x reference)
//
#include <hip/hip_runtime.h>

// ---------------------------------------------------------------------------
// GIN GraphEncoder on MI355X.
// All GEMMs: MFMA split-bf16 (hi/lo, 3-product ~f32 accuracy), PRESPLIT
// operands staged global->LDS via global_load_lds(16B), BK=32, single-buffer
// 32KB LDS. Storage swizzle: 16B k-groups XORed within 32-elem blocks with
// sw(row) = (row&3)^((row>>2)&3) (bank-spread; staging stays linear).
// Main GEMMs: XCD-pair block swizzle.
// R10: adjacency lists SORTED BY SOURCE per node (k_sortadj) -- concurrent
// waves sweep X in correlated address order, shrinking the live gather window
// to ~10MB so L3/L2 retain it (FETCH_SIZE was 397MB/dispatch = random-thrash).
// Per layer: agg (CSR gather f32 -> split) -> gemmA (z f32 + fused BN stats)
// -> k_bn (BN folded in, relu -> split) -> gemmB (+epilogue). Pool + 2 heads.
// Integer inputs arrive as int32. CSR scan 3-phase.
// ---------------------------------------------------------------------------

typedef __attribute__((ext_vector_type(8))) short short8;   // 8 bf16 for MFMA
typedef __attribute__((ext_vector_type(4))) float f32x4;
typedef __attribute__((ext_vector_type(4))) unsigned short us4;
typedef __attribute__((ext_vector_type(8))) unsigned short us8;

__device__ __forceinline__ unsigned short f2bf(float f) {
  unsigned int b = __float_as_uint(f);
  unsigned int r = 0x7FFFu + ((b >> 16) & 1u);   // round-to-nearest-even
  return (unsigned short)((b + r) >> 16);
}
__device__ __forceinline__ float bf2f(unsigned short u) {
  return __uint_as_float(((unsigned int)u) << 16);
}

// bank-spread row swizzle value (4-group domain)
__device__ __forceinline__ int swv(int row) {
  return (row & 3) ^ ((row >> 2) & 3);
}

// global->LDS 16B async copy; LDS dest is wave-uniform base (HW adds lane*16)
typedef const __attribute__((address_space(1))) unsigned int* gas1;
typedef __attribute__((address_space(3))) unsigned int* las3;
__device__ __forceinline__ void gload16(const void* g, void* l) {
  __builtin_amdgcn_global_load_lds((gas1)g, (las3)l, 16, 0, 0);
}

// swizzled flat index of element (row, k), row length K:
// 16B groups (8 us) XORed within each 32-elem block: g' = g ^ swv(row)
__device__ __forceinline__ size_t swz4_idx(int row, int k, int K) {
  int g = k >> 3;
  return (size_t)row * K + ((g >> 2) << 5) + ((((g & 3) ^ swv(row)) << 3)) + (k & 7);
}

// ---------------- CSR build + graph bounds (fused) ----------------
__global__ void k_histbounds(const int* __restrict__ ei, int* __restrict__ deg, int E,
                             int eb, const int* __restrict__ batch,
                             int* __restrict__ gs, int* __restrict__ ge, int N) {
  int b = blockIdx.x;
  if (b < eb) {
    int e = b * 256 + threadIdx.x;
    if (e < E) atomicAdd(&deg[ei[E + e]], 1);
  } else {
    int i = (b - eb) * 256 + threadIdx.x;
    if (i < N) {
      int bb = batch[i];
      if (i == 0 || batch[i - 1] != bb) gs[bb] = i;
      if (i == N - 1 || batch[i + 1] != bb) ge[bb] = i + 1;
    }
  }
}

// phase 1: per-block (1024 elems) inclusive scan + block sum
__global__ __launch_bounds__(1024) void k_scan1(const int* __restrict__ deg,
                                                int* __restrict__ partial,
                                                int* __restrict__ bsum, int N) {
  __shared__ int sd[1024];
  int tid = threadIdx.x;
  int i = blockIdx.x * 1024 + tid;
  int v = (i < N) ? deg[i] : 0;
  sd[tid] = v;
  __syncthreads();
  for (int off = 1; off < 1024; off <<= 1) {
    int t = (tid >= off) ? sd[tid - off] : 0;
    __syncthreads();
    sd[tid] += t;
    __syncthreads();
  }
  if (i < N) partial[i] = sd[tid];
  if (tid == 1023) bsum[blockIdx.x] = sd[1023];
}

// phase 2: exclusive scan of <=64 block sums in one wave
__global__ void k_scan2(int* __restrict__ bsum, int nb) {
  int l = threadIdx.x;
  int orig = (l < nb) ? bsum[l] : 0;
  int v = orig;
  for (int off = 1; off < 64; off <<= 1) {
    int t = __shfl_up(v, off);
    if (l >= off) v += t;
  }
  if (l < nb) bsum[l] = v - orig;
}

// phase 3: rowptr / cursor
__global__ void k_scan3(const int* __restrict__ deg, const int* __restrict__ partial,
                        const int* __restrict__ bsum, int* __restrict__ rowptr,
                        int* __restrict__ cursor, int N) {
  int i = blockIdx.x * 256 + threadIdx.x;
  if (i >= N) return;
  int incl = partial[i] + bsum[i >> 10];
  rowptr[i + 1] = incl;
  cursor[i] = incl - deg[i];
  if (i == 0) rowptr[0] = 0;
}

__global__ void k_fill(const int* __restrict__ ei, int* __restrict__ cursor,
                       int* __restrict__ adj, int E) {
  int e = blockIdx.x * 256 + threadIdx.x;
  if (e >= E) return;
  int s = ei[e];
  int d = ei[E + e];
  int pos = atomicAdd(&cursor[d], 1);
  adj[pos] = s;
}

// R10: sort each node's adjacency sub-list by source id (insertion sort,
// avg degree 16). Gives concurrent waves a correlated sweep through X
// (gather window ~10MB -> cache-resident) + deterministic sum order.
__global__ void k_sortadj(const int* __restrict__ rowptr, int* adj, int N) {
  int n = blockIdx.x * 256 + threadIdx.x;
  if (n >= N) return;
  int e0 = rowptr[n], e1 = rowptr[n + 1];
  for (int i = e0 + 1; i < e1; ++i) {
    int v = adj[i];
    int j = i - 1;
    while (j >= e0 && adj[j] > v) { adj[j + 1] = adj[j]; --j; }
    adj[j + 1] = v;
  }
}

// ---- ALL weights: transpose + split + swizzle in ONE kernel ----
__global__ void k_prep_all(const float* __restrict__ w1a, const float* __restrict__ w1b,
                           const float* __restrict__ w2a, const float* __restrict__ w2b,
                           const float* __restrict__ w3a, const float* __restrict__ w3b,
                           const float* __restrict__ wh1, const float* __restrict__ wh2,
                           unsigned short* __restrict__ Hi, unsigned short* __restrict__ Lo) {
  int idx = blockIdx.x * 256 + threadIdx.x;   // [0, 884736)
  const float* W; int K, Nout, lo_;
  if (idx < 32768)       { W = w1a; K = 128; Nout = 256; lo_ = 0; }
  else if (idx < 98304)  { W = w1b; K = 256; Nout = 256; lo_ = 32768; }
  else if (idx < 163840) { W = w2a; K = 256; Nout = 256; lo_ = 98304; }
  else if (idx < 229376) { W = w2b; K = 256; Nout = 256; lo_ = 163840; }
  else if (idx < 294912) { W = w3a; K = 256; Nout = 256; lo_ = 229376; }
  else if (idx < 360448) { W = w3b; K = 256; Nout = 256; lo_ = 294912; }
  else if (idx < 491520) { W = wh1; K = 256; Nout = 512; lo_ = 360448; }
  else                   { W = wh2; K = 512; Nout = 768; lo_ = 491520; }
  int li = idx - lo_;
  int n = li % Nout, k = li / Nout;
  float w = W[k * Nout + n];
  unsigned short h = f2bf(w);
  size_t oi = (size_t)lo_ + swz4_idx(n, k, K);
  Hi[oi] = h;
  Lo[oi] = f2bf(w - bf2f(h));
}

// -------- aggregation: h = X[i] + sum X[adj[e]]; write split+swizzled --------
template <int C>
__global__ __launch_bounds__(256) void k_agg(const float* __restrict__ X,
                                             unsigned short* __restrict__ HHi,
                                             unsigned short* __restrict__ HLo,
                                             const int* __restrict__ rowptr,
                                             const int* __restrict__ adj, int N) {
  int node = blockIdx.x * 4 + (threadIdx.x >> 6);
  if (node >= N) return;
  int lane = threadIdx.x & 63;
  int e0 = rowptr[node], e1 = rowptr[node + 1];
  if constexpr (C == 256) {
    float4 acc = ((const float4*)(X + (size_t)node * C))[lane];
    int e = e0;
    for (; e + 4 <= e1; e += 4) {
      int s0 = adj[e], s1 = adj[e + 1], s2 = adj[e + 2], s3 = adj[e + 3];
      float4 v0 = ((const float4*)(X + (size_t)s0 * C))[lane];
      float4 v1 = ((const float4*)(X + (size_t)s1 * C))[lane];
      float4 v2 = ((const float4*)(X + (size_t)s2 * C))[lane];
      float4 v3 = ((const float4*)(X + (size_t)s3 * C))[lane];
      acc.x += (v0.x + v1.x) + (v2.x + v3.x);
      acc.y += (v0.y + v1.y) + (v2.y + v3.y);
      acc.z += (v0.z + v1.z) + (v2.z + v3.z);
      acc.w += (v0.w + v1.w) + (v2.w + v3.w);
    }
    for (; e < e1; ++e) {
      int s = adj[e];
      float4 v = ((const float4*)(X + (size_t)s * C))[lane];
      acc.x += v.x; acc.y += v.y; acc.z += v.z; acc.w += v.w;
    }
    float vv[4] = {acc.x, acc.y, acc.z, acc.w};
    us4 hv, lv;
#pragma unroll
    for (int j = 0; j < 4; ++j) {
      unsigned short h = f2bf(vv[j]);
      hv[j] = h;
      lv[j] = f2bf(vv[j] - bf2f(h));
    }
    // lane covers cols lane*4..+3 -> group g = lane>>1, half = lane&1
    size_t oi = (size_t)node * 256 + ((lane >> 3) << 5) +
                ((((lane >> 1) & 3) ^ swv(node)) << 3) + ((lane & 1) << 2);
    *(us4*)(HHi + oi) = hv;
    *(us4*)(HLo + oi) = lv;
  } else {  // C == 128
    float2 acc = ((const float2*)(X + (size_t)node * C))[lane];
    int e = e0;
    for (; e + 4 <= e1; e += 4) {
      int s0 = adj[e], s1 = adj[e + 1], s2 = adj[e + 2], s3 = adj[e + 3];
      float2 v0 = ((const float2*)(X + (size_t)s0 * C))[lane];
      float2 v1 = ((const float2*)(X + (size_t)s1 * C))[lane];
      float2 v2 = ((const float2*)(X + (size_t)s2 * C))[lane];
      float2 v3 = ((const float2*)(X + (size_t)s3 * C))[lane];
      acc.x += (v0.x + v1.x) + (v2.x + v3.x);
      acc.y += (v0.y + v1.y) + (v2.y + v3.y);
    }
    for (; e < e1; ++e) {
      int s = adj[e];
      float2 v = ((const float2*)(X + (size_t)s * C))[lane];
      acc.x += v.x; acc.y += v.y;
    }
    unsigned short hx = f2bf(acc.x), hy = f2bf(acc.y);
    ushort2 hv = {hx, hy};
    ushort2 lv = {f2bf(acc.x - bf2f(hx)), f2bf(acc.y - bf2f(hy))};
    size_t oi = (size_t)node * 128 + ((lane >> 4) << 5) +
                ((((lane >> 2) & 3) ^ swv(node)) << 3) + ((lane & 3) << 1);
    *(ushort2*)(HHi + oi) = hv;
    *(ushort2*)(HLo + oi) = lv;
  }
}

// -------- BN+relu elementwise (finalize folded in): z f32 -> split bf16 -----
__global__ __launch_bounds__(256) void k_bn(const float* __restrict__ Z,
                                            const float* __restrict__ stats,
                                            const float* __restrict__ g,
                                            const float* __restrict__ be,
                                            unsigned short* __restrict__ OHi,
                                            unsigned short* __restrict__ OLo,
                                            int N) {
  int t = blockIdx.x * 256 + threadIdx.x;    // one 8-elem group per thread
  if (t >= N * 32) return;
  int row = t >> 5, gg_ = t & 31;
  int k0 = gg_ << 3;
  const float* zp = Z + (size_t)row * 256 + k0;
  float4 v0 = *(const float4*)zp;
  float4 v1 = *(const float4*)(zp + 4);
  float f[8] = {v0.x, v0.y, v0.z, v0.w, v1.x, v1.y, v1.z, v1.w};
  us8 hv, lv;
#pragma unroll
  for (int j = 0; j < 8; ++j) {
    int kc = k0 + j;
    float mu = stats[kc] / (float)N;
    float var = stats[256 + kc] / (float)N - mu * mu;
    float sc = g[kc] * rsqrtf(var + 1e-5f);
    float sh = be[kc] - mu * sc;
    float o = fmaxf(f[j] * sc + sh, 0.f);
    unsigned short h = f2bf(o);
    hv[j] = h;
    lv[j] = f2bf(o - bf2f(h));
  }
  size_t oi = (size_t)row * 256 + ((gg_ >> 2) << 5) + (((gg_ & 3) ^ swv(row)) << 3);
  *(us8*)(OHi + oi) = hv;
  *(us8*)(OLo + oi) = lv;
}

// ------------ MFMA GEMM: single-buffer BK=32, 32KB LDS, bank-spread swizzle --
// Out[M][Nld] = A[M][K] @ Wt^T + bias, A/W presplit+swizzled.
// EPI: 0 none, 1 relu, 2 tanh, 3 relu(tanh). STATS: fused BN sum/sumsq.
// OSPLIT: write split+swizzled (relu). XSWZ: XCD-pair block swizzle.
template <int EPI, bool STATS, bool OSPLIT, bool XSWZ>
__global__ __launch_bounds__(256) void k_gemm(
    const unsigned short* __restrict__ AHi, const unsigned short* __restrict__ ALo,
    int M, int K, int Nld, int mb, int per,
    const unsigned short* __restrict__ WHi, const unsigned short* __restrict__ WLo,
    const float* __restrict__ bias, float* __restrict__ Out,
    unsigned short* __restrict__ OHi, unsigned short* __restrict__ OLo,
    float* __restrict__ stats) {
  __shared__ unsigned short aHi[4096], aLo[4096], bHi[4096], bLo[4096];  // 4x8KB
  int bx, by;
  if constexpr (XSWZ) {
    int xcd = blockIdx.x & 7, slot = blockIdx.x >> 3;
    bx = xcd * per + (slot >> 1);
    by = slot & 1;
    if (bx >= mb) return;
  } else {
    bx = blockIdx.x;
    by = blockIdx.y;
  }
  const int tid = threadIdx.x;
  const int lane = tid & 63, w = tid >> 6;
  const int wm = w >> 1, wn = w & 1;
  const int m0 = bx * 128, n0 = by * 128;

  f32x4 zero = {0.f, 0.f, 0.f, 0.f};
  f32x4 acc[4][4];
#pragma unroll
  for (int i = 0; i < 4; ++i)
#pragma unroll
    for (int j = 0; j < 4; ++j) acc[i][j] = zero;

  // staging: wave w rows [32w,32w+32); issue q: rows 32w+16q+(lane>>2),
  // slot lane&3; LDS linear (lane*16 off wave-uniform base).
  const int rq = lane >> 2;
  const int k8s = lane & 3;

  for (int kb = 0; kb < K; kb += 32) {
    __syncthreads();
#pragma unroll
    for (int q = 0; q < 2; ++q) {
      int rloc = (w << 5) + (q << 4) + rq;
      int ra = m0 + rloc; if (ra >= M) ra = M - 1;   // clamp tail (junk never stored)
      size_t ga = (size_t)ra * K + kb + k8s * 8;     // swizzles cancel -> linear
      size_t gb = (size_t)(n0 + rloc) * K + kb + k8s * 8;
      unsigned bo = (w << 11) + (q << 10);           // wave-uniform LDS base
      gload16(AHi + ga, (char*)aHi + bo);
      gload16(ALo + ga, (char*)aLo + bo);
      gload16(WHi + gb, (char*)bHi + bo);
      gload16(WLo + gb, (char*)bLo + bo);
    }
    __syncthreads();   // compiler drains vmcnt(0) before s_barrier -> LDS ready

    const int j = lane >> 4;
    short8 bh[4], bl[4];
#pragma unroll
    for (int ni = 0; ni < 4; ++ni) {
      int r = wn * 64 + ni * 16 + (lane & 15);
      int bo = r * 64 + ((j ^ swv(r)) << 4);
      bh[ni] = *(const short8*)((const char*)bHi + bo);
      bl[ni] = *(const short8*)((const char*)bLo + bo);
    }
#pragma unroll
    for (int mi = 0; mi < 4; ++mi) {
      int r = wm * 64 + mi * 16 + (lane & 15);
      int bo = r * 64 + ((j ^ swv(r)) << 4);
      short8 ah = *(const short8*)((const char*)aHi + bo);
      short8 al = *(const short8*)((const char*)aLo + bo);
#pragma unroll
      for (int ni = 0; ni < 4; ++ni) {
        acc[mi][ni] = __builtin_amdgcn_mfma_f32_16x16x32_bf16(ah, bh[ni], acc[mi][ni], 0, 0, 0);
        acc[mi][ni] = __builtin_amdgcn_mfma_f32_16x16x32_bf16(ah, bl[ni], acc[mi][ni], 0, 0, 0);
        acc[mi][ni] = __builtin_amdgcn_mfma_f32_16x16x32_bf16(al, bh[ni], acc[mi][ni], 0, 0, 0);
      }
    }
  }

  // epilogue: C/D layout col = lane&15, row = (lane>>4)*4 + r   [m89-verified]
#pragma unroll
  for (int ni = 0; ni < 4; ++ni) {
    int col = n0 + wn * 64 + ni * 16 + (lane & 15);
    float bc = bias[col];
    float s = 0.f, q = 0.f;
#pragma unroll
    for (int mi = 0; mi < 4; ++mi) {
      int rbase = m0 + wm * 64 + mi * 16 + (lane >> 4) * 4;
#pragma unroll
      for (int r = 0; r < 4; ++r) {
        int row = rbase + r;
        if (row < M) {
          float o = acc[mi][ni][r] + bc;
          if (STATS) { s += o; q += o * o; }
          if (OSPLIT) {
            o = fmaxf(o, 0.f);   // relu (head1)
            unsigned short h = f2bf(o);
            size_t oi = swz4_idx(row, col, Nld);
            OHi[oi] = h;
            OLo[oi] = f2bf(o - bf2f(h));
          } else {
            if (EPI == 1) o = fmaxf(o, 0.f);
            else if (EPI == 2) o = tanhf(o);
            else if (EPI == 3) o = fmaxf(tanhf(o), 0.f);
            Out[(size_t)row * Nld + col] = o;
          }
        }
      }
    }
    if (STATS) {
      s += __shfl_xor(s, 16); s += __shfl_xor(s, 32);
      q += __shfl_xor(q, 16); q += __shfl_xor(q, 32);
      if ((lane >> 4) == 0) {
        atomicAdd(&stats[col], s);
        atomicAdd(&stats[256 + col], q);
      }
    }
  }
}

// ---------------- pooling ----------------
// 4 waves stride rows, float4 lanes, LDS reduce; write split+swizzled.
__global__ __launch_bounds__(256) void k_pool(const float* __restrict__ Hf,
                                              const int* __restrict__ gs,
                                              const int* __restrict__ ge,
                                              unsigned short* __restrict__ PHi,
                                              unsigned short* __restrict__ PLo) {
  __shared__ float4 red[4][64];
  int gi = blockIdx.x;
  int s = gs[gi], e = ge[gi];
  int w = threadIdx.x >> 6, lane = threadIdx.x & 63;
  float4 acc = {0.f, 0.f, 0.f, 0.f};
  for (int r = s + w; r < e; r += 4) {
    float4 v = ((const float4*)(Hf + (size_t)r * 256))[lane];
    acc.x += v.x; acc.y += v.y; acc.z += v.z; acc.w += v.w;
  }
  red[w][lane] = acc;
  __syncthreads();
  if (w == 0) {
    float4 a = red[0][lane], b = red[1][lane], c = red[2][lane], d = red[3][lane];
    float inv = 1.0f / fmaxf((float)(e - s), 1.0f);
    float vv[4] = {(a.x + b.x + c.x + d.x) * inv, (a.y + b.y + c.y + d.y) * inv,
                   (a.z + b.z + c.z + d.z) * inv, (a.w + b.w + c.w + d.w) * inv};
    us4 hv, lv;
#pragma unroll
    for (int j = 0; j < 4; ++j) {
      unsigned short h = f2bf(vv[j]);
      hv[j] = h;
      lv[j] = f2bf(vv[j] - bf2f(h));
    }
    size_t oi = (size_t)gi * 256 + ((lane >> 3) << 5) +
                ((((lane >> 1) & 3) ^ swv(gi)) << 3) + ((lane & 1) << 2);
    *(us4*)(PHi + oi) = hv;
    *(us4*)(PLo + oi) = lv;
  }
}

// ---------------------------------------------------------------------------
extern "C" void kernel_launch(void* const* d_in, const int* in_sizes, int n_in,
                              void* d_out, int out_size, void* d_ws, size_t ws_size,
                              hipStream_t stream) {
  const float* x      = (const float*)d_in[0];
  const int* ei       = (const int*)d_in[1];    // int32 from harness
  const int* bat      = (const int*)d_in[2];    // int32 from harness
  const float* w1a = (const float*)d_in[3];  const float* b1a = (const float*)d_in[4];
  const float* g1  = (const float*)d_in[5];  const float* be1 = (const float*)d_in[6];
  const float* w1b = (const float*)d_in[7];  const float* b1b = (const float*)d_in[8];
  const float* w2a = (const float*)d_in[9];  const float* b2a = (const float*)d_in[10];
  const float* g2  = (const float*)d_in[11]; const float* be2 = (const float*)d_in[12];
  const float* w2b = (const float*)d_in[13]; const float* b2b = (const float*)d_in[14];
  const float* w3a = (const float*)d_in[15]; const float* b3a = (const float*)d_in[16];
  const float* g3  = (const float*)d_in[17]; const float* be3 = (const float*)d_in[18];
  const float* w3b = (const float*)d_in[19]; const float* b3b = (const float*)d_in[20];
  const float* wh1 = (const float*)d_in[21]; const float* bh1 = (const float*)d_in[22];
  const float* wh2 = (const float*)d_in[23]; const float* bh2 = (const float*)d_in[24];
  float* out = (float*)d_out;

  const int N = in_sizes[0] / 128;   // 50000
  const int E = in_sizes[1] / 2;     // 800000
  const int G = 512;

  // ---- workspace layout: P = f32 region (z / act), Q = split region ----
  char* ws = (char*)d_ws;
  size_t off = 0;
  auto alloc = [&](size_t bytes) {
    void* p = ws + off;
    off = (off + bytes + 255) & ~(size_t)255;
    return p;
  };
  float* Pf = (float*)alloc((size_t)N * 256 * 4);
  unsigned short* Qhi = (unsigned short*)alloc((size_t)N * 256 * 2);
  unsigned short* Qlo = (unsigned short*)alloc((size_t)N * 256 * 2);
  int* adj     = (int*)alloc((size_t)E * 4);
  int* rowptr  = (int*)alloc((size_t)(N + 1) * 4);
  int* cursor  = (int*)alloc((size_t)N * 4);
  int* deg     = (int*)alloc((size_t)N * 4);
  int* partial = (int*)alloc((size_t)N * 4);
  int* bsum    = (int*)alloc(64 * 4);
  unsigned short* wHi = (unsigned short*)alloc(884736 * 2);
  unsigned short* wLo = (unsigned short*)alloc(884736 * 2);
  float* stats = (float*)alloc(512 * 4);
  int* gs      = (int*)alloc(G * 4);
  int* ge      = (int*)alloc(G * 4);
  unsigned short* poolHi = (unsigned short*)alloc((size_t)G * 256 * 2);
  unsigned short* poolLo = (unsigned short*)alloc((size_t)G * 256 * 2);
  unsigned short* thidHi = (unsigned short*)alloc((size_t)G * 512 * 2);
  unsigned short* thidLo = (unsigned short*)alloc((size_t)G * 512 * 2);

  // transposed-weight element offsets (match k_prep_all segment table)
  const int o1a = 0, o1b = 32768, o2a = 98304, o2b = 163840, o3a = 229376, o3b = 294912;
  const int oh1 = 360448, oh2 = 491520;   // ends at 884736

  hipMemsetAsync(deg, 0, (size_t)N * 4, stream);
  hipMemsetAsync(gs, 0, (size_t)G * 4, stream);
  hipMemsetAsync(ge, 0, (size_t)G * 4, stream);

  int eb = (E + 255) / 256;
  int nbN = (N + 255) / 256;
  int nb1 = (N + 1023) >> 10;   // 49 (<=64 required by k_scan2)
  k_histbounds<<<eb + nbN, 256, 0, stream>>>(ei, deg, E, eb, bat, gs, ge, N);
  k_scan1<<<nb1, 1024, 0, stream>>>(deg, partial, bsum, N);
  k_scan2<<<1, 64, 0, stream>>>(bsum, nb1);
  k_scan3<<<nbN, 256, 0, stream>>>(deg, partial, bsum, rowptr, cursor, N);
  k_fill<<<eb, 256, 0, stream>>>(ei, cursor, adj, E);
  k_sortadj<<<nbN, 256, 0, stream>>>(rowptr, adj, N);

  k_prep_all<<<3456, 256, 0, stream>>>(w1a, w1b, w2a, w2b, w3a, w3b, wh1, wh2, wHi, wLo);

  int nb4 = (N + 3) / 4;
  int bnb = (N * 32 + 255) / 256;
  const int mb = (N + 127) / 128;        // 391
  const int per = (mb + 7) / 8;          // 49
  dim3 gg(per * 16);                     // XCD-pair swizzled flat grid

  // ---- layer 1 ----
  k_agg<128><<<nb4, 256, 0, stream>>>(x, Qhi, Qlo, rowptr, adj, N);
  hipMemsetAsync(stats, 0, 512 * 4, stream);
  k_gemm<0, true, false, true><<<gg, 256, 0, stream>>>(Qhi, Qlo, N, 128, 256, mb, per, wHi + o1a, wLo + o1a, b1a, Pf, nullptr, nullptr, stats);
  k_bn<<<bnb, 256, 0, stream>>>(Pf, stats, g1, be1, Qhi, Qlo, N);
  k_gemm<1, false, false, true><<<gg, 256, 0, stream>>>(Qhi, Qlo, N, 256, 256, mb, per, wHi + o1b, wLo + o1b, b1b, Pf, nullptr, nullptr, nullptr);

  // ---- layer 2 ----
  k_agg<256><<<nb4, 256, 0, stream>>>(Pf, Qhi, Qlo, rowptr, adj, N);
  hipMemsetAsync(stats, 0, 512 * 4, stream);
  k_gemm<0, true, false, true><<<gg, 256, 0, stream>>>(Qhi, Qlo, N, 256, 256, mb, per, wHi + o2a, wLo + o2a, b2a, Pf, nullptr, nullptr, stats);
  k_bn<<<bnb, 256, 0, stream>>>(Pf, stats, g2, be2, Qhi, Qlo, N);
  k_gemm<3, false, false, true><<<gg, 256, 0, stream>>>(Qhi, Qlo, N, 256, 256, mb, per, wHi + o2b, wLo + o2b, b2b, Pf, nullptr, nullptr, nullptr);

  // ---- layer 3 ----
  k_agg<256><<<nb4, 256, 0, stream>>>(Pf, Qhi, Qlo, rowptr, adj, N);
  hipMemsetAsync(stats, 0, 512 * 4, stream);
  k_gemm<0, true, false, true><<<gg, 256, 0, stream>>>(Qhi, Qlo, N, 256, 256, mb, per, wHi + o3a, wLo + o3a, b3a, Pf, nullptr, nullptr, stats);
  k_bn<<<bnb, 256, 0, stream>>>(Pf, stats, g3, be3, Qhi, Qlo, N);
  k_gemm<2, false, false, true><<<gg, 256, 0, stream>>>(Qhi, Qlo, N, 256, 256, mb, per, wHi + o3b, wLo + o3b, b3b, Pf, nullptr, nullptr, nullptr);

  // ---- pool + MFMA heads ----
  k_pool<<<G, 256, 0, stream>>>(Pf, gs, ge, poolHi, poolLo);
  dim3 gh1(4, 4);   // M=512/128, N=512/128
  k_gemm<1, false, true, false><<<gh1, 256, 0, stream>>>(poolHi, poolLo, G, 256, 512, 0, 0, wHi + oh1, wLo + oh1, bh1, nullptr, thidHi, thidLo, nullptr);
  dim3 gh2(4, 6);   // M=512/128, N=768/128
  k_gemm<0, false, false, false><<<gh2, 256, 0, stream>>>(thidHi, thidLo, G, 512, 768, 0, 0, wHi + oh2, wLo + oh2, bh2, out, nullptr, nullptr, nullptr);
}

// Round 11
// 867.778 us; speedup vs baseline: 1.0763x; 1.0763x over previous
//
#include <hip/hip_runtime.h>

// ---------------------------------------------------------------------------
// GIN GraphEncoder on MI355X.
// All GEMMs: MFMA split-bf16 (hi/lo, 3-product ~f32 accuracy), PRESPLIT
// operands staged global->LDS via global_load_lds(16B), BK=32.
// R11: 64x256 tile -- each block computes the FULL output width, so A is
// read once (was twice) and the 256KB B-slab is L2-resident per XCD (stage
// latency ~200cy L2 instead of ~900cy HBM). 4 waves, each owns a 64x64
// quarter; acc/epilogue identical to the proven 128x128 kernel. LDS 40KB.
// Storage swizzle: 16B k-groups XORed within 32-elem blocks with
// sw(row) = (row&3)^((row>>2)&3) (bank-spread; staging stays linear).
// Main GEMMs: XCD block swizzle (contiguous M-tile chunks per XCD).
// Per layer: agg (CSR gather f32 -> split) -> gemmA (z f32 + fused BN stats)
// -> k_bn (BN folded in, relu -> split) -> gemmB (+epilogue). Pool + 2 heads.
// R10's per-node adjacency sort REVERTED (FETCH 397->395MB only, cost 80us).
// Integer inputs arrive as int32. CSR scan 3-phase.
// ---------------------------------------------------------------------------

typedef __attribute__((ext_vector_type(8))) short short8;   // 8 bf16 for MFMA
typedef __attribute__((ext_vector_type(4))) float f32x4;
typedef __attribute__((ext_vector_type(4))) unsigned short us4;
typedef __attribute__((ext_vector_type(8))) unsigned short us8;

__device__ __forceinline__ unsigned short f2bf(float f) {
  unsigned int b = __float_as_uint(f);
  unsigned int r = 0x7FFFu + ((b >> 16) & 1u);   // round-to-nearest-even
  return (unsigned short)((b + r) >> 16);
}
__device__ __forceinline__ float bf2f(unsigned short u) {
  return __uint_as_float(((unsigned int)u) << 16);
}

// bank-spread row swizzle value (4-group domain)
__device__ __forceinline__ int swv(int row) {
  return (row & 3) ^ ((row >> 2) & 3);
}

// global->LDS 16B async copy; LDS dest is wave-uniform base (HW adds lane*16)
typedef const __attribute__((address_space(1))) unsigned int* gas1;
typedef __attribute__((address_space(3))) unsigned int* las3;
__device__ __forceinline__ void gload16(const void* g, void* l) {
  __builtin_amdgcn_global_load_lds((gas1)g, (las3)l, 16, 0, 0);
}

// swizzled flat index of element (row, k), row length K:
// 16B groups (8 us) XORed within each 32-elem block: g' = g ^ swv(row)
__device__ __forceinline__ size_t swz4_idx(int row, int k, int K) {
  int g = k >> 3;
  return (size_t)row * K + ((g >> 2) << 5) + ((((g & 3) ^ swv(row)) << 3)) + (k & 7);
}

// ---------------- CSR build + graph bounds (fused) ----------------
__global__ void k_histbounds(const int* __restrict__ ei, int* __restrict__ deg, int E,
                             int eb, const int* __restrict__ batch,
                             int* __restrict__ gs, int* __restrict__ ge, int N) {
  int b = blockIdx.x;
  if (b < eb) {
    int e = b * 256 + threadIdx.x;
    if (e < E) atomicAdd(&deg[ei[E + e]], 1);
  } else {
    int i = (b - eb) * 256 + threadIdx.x;
    if (i < N) {
      int bb = batch[i];
      if (i == 0 || batch[i - 1] != bb) gs[bb] = i;
      if (i == N - 1 || batch[i + 1] != bb) ge[bb] = i + 1;
    }
  }
}

// phase 1: per-block (1024 elems) inclusive scan + block sum
__global__ __launch_bounds__(1024) void k_scan1(const int* __restrict__ deg,
                                                int* __restrict__ partial,
                                                int* __restrict__ bsum, int N) {
  __shared__ int sd[1024];
  int tid = threadIdx.x;
  int i = blockIdx.x * 1024 + tid;
  int v = (i < N) ? deg[i] : 0;
  sd[tid] = v;
  __syncthreads();
  for (int off = 1; off < 1024; off <<= 1) {
    int t = (tid >= off) ? sd[tid - off] : 0;
    __syncthreads();
    sd[tid] += t;
    __syncthreads();
  }
  if (i < N) partial[i] = sd[tid];
  if (tid == 1023) bsum[blockIdx.x] = sd[1023];
}

// phase 2: exclusive scan of <=64 block sums in one wave
__global__ void k_scan2(int* __restrict__ bsum, int nb) {
  int l = threadIdx.x;
  int orig = (l < nb) ? bsum[l] : 0;
  int v = orig;
  for (int off = 1; off < 64; off <<= 1) {
    int t = __shfl_up(v, off);
    if (l >= off) v += t;
  }
  if (l < nb) bsum[l] = v - orig;
}

// phase 3: rowptr / cursor
__global__ void k_scan3(const int* __restrict__ deg, const int* __restrict__ partial,
                        const int* __restrict__ bsum, int* __restrict__ rowptr,
                        int* __restrict__ cursor, int N) {
  int i = blockIdx.x * 256 + threadIdx.x;
  if (i >= N) return;
  int incl = partial[i] + bsum[i >> 10];
  rowptr[i + 1] = incl;
  cursor[i] = incl - deg[i];
  if (i == 0) rowptr[0] = 0;
}

__global__ void k_fill(const int* __restrict__ ei, int* __restrict__ cursor,
                       int* __restrict__ adj, int E) {
  int e = blockIdx.x * 256 + threadIdx.x;
  if (e >= E) return;
  int s = ei[e];
  int d = ei[E + e];
  int pos = atomicAdd(&cursor[d], 1);
  adj[pos] = s;
}

// ---- ALL weights: transpose + split + swizzle in ONE kernel ----
__global__ void k_prep_all(const float* __restrict__ w1a, const float* __restrict__ w1b,
                           const float* __restrict__ w2a, const float* __restrict__ w2b,
                           const float* __restrict__ w3a, const float* __restrict__ w3b,
                           const float* __restrict__ wh1, const float* __restrict__ wh2,
                           unsigned short* __restrict__ Hi, unsigned short* __restrict__ Lo) {
  int idx = blockIdx.x * 256 + threadIdx.x;   // [0, 884736)
  const float* W; int K, Nout, lo_;
  if (idx < 32768)       { W = w1a; K = 128; Nout = 256; lo_ = 0; }
  else if (idx < 98304)  { W = w1b; K = 256; Nout = 256; lo_ = 32768; }
  else if (idx < 163840) { W = w2a; K = 256; Nout = 256; lo_ = 98304; }
  else if (idx < 229376) { W = w2b; K = 256; Nout = 256; lo_ = 163840; }
  else if (idx < 294912) { W = w3a; K = 256; Nout = 256; lo_ = 229376; }
  else if (idx < 360448) { W = w3b; K = 256; Nout = 256; lo_ = 294912; }
  else if (idx < 491520) { W = wh1; K = 256; Nout = 512; lo_ = 360448; }
  else                   { W = wh2; K = 512; Nout = 768; lo_ = 491520; }
  int li = idx - lo_;
  int n = li % Nout, k = li / Nout;
  float w = W[k * Nout + n];
  unsigned short h = f2bf(w);
  size_t oi = (size_t)lo_ + swz4_idx(n, k, K);
  Hi[oi] = h;
  Lo[oi] = f2bf(w - bf2f(h));
}

// -------- aggregation: h = X[i] + sum X[adj[e]]; write split+swizzled --------
template <int C>
__global__ __launch_bounds__(256) void k_agg(const float* __restrict__ X,
                                             unsigned short* __restrict__ HHi,
                                             unsigned short* __restrict__ HLo,
                                             const int* __restrict__ rowptr,
                                             const int* __restrict__ adj, int N) {
  int node = blockIdx.x * 4 + (threadIdx.x >> 6);
  if (node >= N) return;
  int lane = threadIdx.x & 63;
  int e0 = rowptr[node], e1 = rowptr[node + 1];
  if constexpr (C == 256) {
    float4 acc = ((const float4*)(X + (size_t)node * C))[lane];
    int e = e0;
    for (; e + 4 <= e1; e += 4) {
      int s0 = adj[e], s1 = adj[e + 1], s2 = adj[e + 2], s3 = adj[e + 3];
      float4 v0 = ((const float4*)(X + (size_t)s0 * C))[lane];
      float4 v1 = ((const float4*)(X + (size_t)s1 * C))[lane];
      float4 v2 = ((const float4*)(X + (size_t)s2 * C))[lane];
      float4 v3 = ((const float4*)(X + (size_t)s3 * C))[lane];
      acc.x += (v0.x + v1.x) + (v2.x + v3.x);
      acc.y += (v0.y + v1.y) + (v2.y + v3.y);
      acc.z += (v0.z + v1.z) + (v2.z + v3.z);
      acc.w += (v0.w + v1.w) + (v2.w + v3.w);
    }
    for (; e < e1; ++e) {
      int s = adj[e];
      float4 v = ((const float4*)(X + (size_t)s * C))[lane];
      acc.x += v.x; acc.y += v.y; acc.z += v.z; acc.w += v.w;
    }
    float vv[4] = {acc.x, acc.y, acc.z, acc.w};
    us4 hv, lv;
#pragma unroll
    for (int j = 0; j < 4; ++j) {
      unsigned short h = f2bf(vv[j]);
      hv[j] = h;
      lv[j] = f2bf(vv[j] - bf2f(h));
    }
    // lane covers cols lane*4..+3 -> group g = lane>>1, half = lane&1
    size_t oi = (size_t)node * 256 + ((lane >> 3) << 5) +
                ((((lane >> 1) & 3) ^ swv(node)) << 3) + ((lane & 1) << 2);
    *(us4*)(HHi + oi) = hv;
    *(us4*)(HLo + oi) = lv;
  } else {  // C == 128
    float2 acc = ((const float2*)(X + (size_t)node * C))[lane];
    int e = e0;
    for (; e + 4 <= e1; e += 4) {
      int s0 = adj[e], s1 = adj[e + 1], s2 = adj[e + 2], s3 = adj[e + 3];
      float2 v0 = ((const float2*)(X + (size_t)s0 * C))[lane];
      float2 v1 = ((const float2*)(X + (size_t)s1 * C))[lane];
      float2 v2 = ((const float2*)(X + (size_t)s2 * C))[lane];
      float2 v3 = ((const float2*)(X + (size_t)s3 * C))[lane];
      acc.x += (v0.x + v1.x) + (v2.x + v3.x);
      acc.y += (v0.y + v1.y) + (v2.y + v3.y);
    }
    for (; e < e1; ++e) {
      int s = adj[e];
      float2 v = ((const float2*)(X + (size_t)s * C))[lane];
      acc.x += v.x; acc.y += v.y;
    }
    unsigned short hx = f2bf(acc.x), hy = f2bf(acc.y);
    ushort2 hv = {hx, hy};
    ushort2 lv = {f2bf(acc.x - bf2f(hx)), f2bf(acc.y - bf2f(hy))};
    size_t oi = (size_t)node * 128 + ((lane >> 4) << 5) +
                ((((lane >> 2) & 3) ^ swv(node)) << 3) + ((lane & 3) << 1);
    *(ushort2*)(HHi + oi) = hv;
    *(ushort2*)(HLo + oi) = lv;
  }
}

// -------- BN+relu elementwise (finalize folded in): z f32 -> split bf16 -----
__global__ __launch_bounds__(256) void k_bn(const float* __restrict__ Z,
                                            const float* __restrict__ stats,
                                            const float* __restrict__ g,
                                            const float* __restrict__ be,
                                            unsigned short* __restrict__ OHi,
                                            unsigned short* __restrict__ OLo,
                                            int N) {
  int t = blockIdx.x * 256 + threadIdx.x;    // one 8-elem group per thread
  if (t >= N * 32) return;
  int row = t >> 5, gg_ = t & 31;
  int k0 = gg_ << 3;
  const float* zp = Z + (size_t)row * 256 + k0;
  float4 v0 = *(const float4*)zp;
  float4 v1 = *(const float4*)(zp + 4);
  float f[8] = {v0.x, v0.y, v0.z, v0.w, v1.x, v1.y, v1.z, v1.w};
  us8 hv, lv;
#pragma unroll
  for (int j = 0; j < 8; ++j) {
    int kc = k0 + j;
    float mu = stats[kc] / (float)N;
    float var = stats[256 + kc] / (float)N - mu * mu;
    float sc = g[kc] * rsqrtf(var + 1e-5f);
    float sh = be[kc] - mu * sc;
    float o = fmaxf(f[j] * sc + sh, 0.f);
    unsigned short h = f2bf(o);
    hv[j] = h;
    lv[j] = f2bf(o - bf2f(h));
  }
  size_t oi = (size_t)row * 256 + ((gg_ >> 2) << 5) + (((gg_ & 3) ^ swv(row)) << 3);
  *(us8*)(OHi + oi) = hv;
  *(us8*)(OLo + oi) = lv;
}

// ------- MFMA GEMM: 64x256 tile, BK=32, 40KB LDS, full-width per block ------
// Out[M][n0..n0+256) = A[M][K] @ W[K][n0..n0+256)^T + bias, presplit+swizzled.
// 4 waves; wave w owns 64 rows x cols [w*64, w*64+64): acc[4][4] (as before).
// A staged once per block (read once per GEMM); B slab (256 rows x K) is
// L2-resident. Staging: 2560 16B-chunks/iter = 10 gload16 rounds x 256 lanes.
// EPI: 0 none, 1 relu, 2 tanh, 3 relu(tanh). STATS: fused BN sum/sumsq.
// OSPLIT: write split+swizzled (relu). XSWZ: XCD chunked M-tile swizzle.
template <int EPI, bool STATS, bool OSPLIT, bool XSWZ>
__global__ __launch_bounds__(256) void k_gemm(
    const unsigned short* __restrict__ AHi, const unsigned short* __restrict__ ALo,
    int M, int K, int Nld, int mb, int per,
    const unsigned short* __restrict__ WHi, const unsigned short* __restrict__ WLo,
    const float* __restrict__ bias, float* __restrict__ Out,
    unsigned short* __restrict__ OHi, unsigned short* __restrict__ OLo,
    float* __restrict__ stats) {
  __shared__ unsigned short aHi[2048], aLo[2048], bHi[8192], bLo[8192];  // 40KB
  int bx, n0;
  if constexpr (XSWZ) {
    int xcd = blockIdx.x & 7, slot = blockIdx.x >> 3;
    bx = xcd * per + slot;
    if (bx >= mb) return;
    n0 = 0;
  } else {
    bx = blockIdx.x;
    n0 = blockIdx.y * 256;           // heads: 256-col slabs of W/out
  }
  const int tid = threadIdx.x;
  const int lane = tid & 63, w = tid >> 6;
  const int m0 = bx * 64;

  f32x4 zero = {0.f, 0.f, 0.f, 0.f};
  f32x4 acc[4][4];
#pragma unroll
  for (int i = 0; i < 4; ++i)
#pragma unroll
    for (int j = 0; j < 4; ++j) acc[i][j] = zero;

  for (int kb = 0; kb < K; kb += 32) {
    __syncthreads();
    // stage 2560 chunks: aHi[0,256) aLo[256,512) bHi[512,1536) bLo[1536,2560)
#pragma unroll
    for (int i = 0; i < 10; ++i) {
      int cb = (i << 8) + (w << 6);          // wave-uniform chunk base
      int cl = cb + lane;
      if (cb < 512) {                        // A: 64 rows x 4 slots x {hi,lo}
        int ca = cl & 255;
        int ra = m0 + (ca >> 2); if (ra >= M) ra = M - 1;  // clamp (junk never stored)
        size_t ga = (size_t)ra * K + kb + (ca & 3) * 8;    // swizzles cancel -> linear
        if (cb < 256) gload16(AHi + ga, (char*)aHi + ((cb & 255) << 4));
        else          gload16(ALo + ga, (char*)aLo + ((cb & 255) << 4));
      } else {                               // B: 256 rows x 4 slots x {hi,lo}
        int cw = (cl - 512) & 1023;
        size_t gb = (size_t)(n0 + (cw >> 2)) * K + kb + (cw & 3) * 8;
        int lb = ((cb - 512) & 1023) << 4;   // wave-uniform LDS byte base
        if (cb < 1536) gload16(WHi + gb, (char*)bHi + lb);
        else           gload16(WLo + gb, (char*)bLo + lb);
      }
    }
    __syncthreads();   // compiler drains vmcnt(0) before s_barrier -> LDS ready

    const int j = lane >> 4;
    short8 bh[4], bl[4];
#pragma unroll
    for (int ni = 0; ni < 4; ++ni) {
      int r = (w << 6) + ni * 16 + (lane & 15);            // 0..255
      int bo = r * 64 + ((j ^ swv(r)) << 4);
      bh[ni] = *(const short8*)((const char*)bHi + bo);
      bl[ni] = *(const short8*)((const char*)bLo + bo);
    }
#pragma unroll
    for (int mi = 0; mi < 4; ++mi) {
      int r = mi * 16 + (lane & 15);                       // 0..63
      int bo = r * 64 + ((j ^ swv(r)) << 4);
      short8 ah = *(const short8*)((const char*)aHi + bo);
      short8 al = *(const short8*)((const char*)aLo + bo);
#pragma unroll
      for (int ni = 0; ni < 4; ++ni) {
        acc[mi][ni] = __builtin_amdgcn_mfma_f32_16x16x32_bf16(ah, bh[ni], acc[mi][ni], 0, 0, 0);
        acc[mi][ni] = __builtin_amdgcn_mfma_f32_16x16x32_bf16(ah, bl[ni], acc[mi][ni], 0, 0, 0);
        acc[mi][ni] = __builtin_amdgcn_mfma_f32_16x16x32_bf16(al, bh[ni], acc[mi][ni], 0, 0, 0);
      }
    }
  }

  // epilogue: C/D layout col = lane&15, row = (lane>>4)*4 + r   [m89-verified]
#pragma unroll
  for (int ni = 0; ni < 4; ++ni) {
    int col = n0 + (w << 6) + ni * 16 + (lane & 15);
    float bc = bias[col];
    float s = 0.f, q = 0.f;
#pragma unroll
    for (int mi = 0; mi < 4; ++mi) {
      int rbase = m0 + mi * 16 + (lane >> 4) * 4;
#pragma unroll
      for (int r = 0; r < 4; ++r) {
        int row = rbase + r;
        if (row < M) {
          float o = acc[mi][ni][r] + bc;
          if (STATS) { s += o; q += o * o; }
          if (OSPLIT) {
            o = fmaxf(o, 0.f);   // relu (head1)
            unsigned short h = f2bf(o);
            size_t oi = swz4_idx(row, col, Nld);
            OHi[oi] = h;
            OLo[oi] = f2bf(o - bf2f(h));
          } else {
            if (EPI == 1) o = fmaxf(o, 0.f);
            else if (EPI == 2) o = tanhf(o);
            else if (EPI == 3) o = fmaxf(tanhf(o), 0.f);
            Out[(size_t)row * Nld + col] = o;
          }
        }
      }
    }
    if (STATS) {
      s += __shfl_xor(s, 16); s += __shfl_xor(s, 32);
      q += __shfl_xor(q, 16); q += __shfl_xor(q, 32);
      if ((lane >> 4) == 0) {
        atomicAdd(&stats[col], s);
        atomicAdd(&stats[256 + col], q);
      }
    }
  }
}

// ---------------- pooling ----------------
// 4 waves stride rows, float4 lanes, LDS reduce; write split+swizzled.
__global__ __launch_bounds__(256) void k_pool(const float* __restrict__ Hf,
                                              const int* __restrict__ gs,
                                              const int* __restrict__ ge,
                                              unsigned short* __restrict__ PHi,
                                              unsigned short* __restrict__ PLo) {
  __shared__ float4 red[4][64];
  int gi = blockIdx.x;
  int s = gs[gi], e = ge[gi];
  int w = threadIdx.x >> 6, lane = threadIdx.x & 63;
  float4 acc = {0.f, 0.f, 0.f, 0.f};
  for (int r = s + w; r < e; r += 4) {
    float4 v = ((const float4*)(Hf + (size_t)r * 256))[lane];
    acc.x += v.x; acc.y += v.y; acc.z += v.z; acc.w += v.w;
  }
  red[w][lane] = acc;
  __syncthreads();
  if (w == 0) {
    float4 a = red[0][lane], b = red[1][lane], c = red[2][lane], d = red[3][lane];
    float inv = 1.0f / fmaxf((float)(e - s), 1.0f);
    float vv[4] = {(a.x + b.x + c.x + d.x) * inv, (a.y + b.y + c.y + d.y) * inv,
                   (a.z + b.z + c.z + d.z) * inv, (a.w + b.w + c.w + d.w) * inv};
    us4 hv, lv;
#pragma unroll
    for (int j = 0; j < 4; ++j) {
      unsigned short h = f2bf(vv[j]);
      hv[j] = h;
      lv[j] = f2bf(vv[j] - bf2f(h));
    }
    size_t oi = (size_t)gi * 256 + ((lane >> 3) << 5) +
                ((((lane >> 1) & 3) ^ swv(gi)) << 3) + ((lane & 1) << 2);
    *(us4*)(PHi + oi) = hv;
    *(us4*)(PLo + oi) = lv;
  }
}

// ---------------------------------------------------------------------------
extern "C" void kernel_launch(void* const* d_in, const int* in_sizes, int n_in,
                              void* d_out, int out_size, void* d_ws, size_t ws_size,
                              hipStream_t stream) {
  const float* x      = (const float*)d_in[0];
  const int* ei       = (const int*)d_in[1];    // int32 from harness
  const int* bat      = (const int*)d_in[2];    // int32 from harness
  const float* w1a = (const float*)d_in[3];  const float* b1a = (const float*)d_in[4];
  const float* g1  = (const float*)d_in[5];  const float* be1 = (const float*)d_in[6];
  const float* w1b = (const float*)d_in[7];  const float* b1b = (const float*)d_in[8];
  const float* w2a = (const float*)d_in[9];  const float* b2a = (const float*)d_in[10];
  const float* g2  = (const float*)d_in[11]; const float* be2 = (const float*)d_in[12];
  const float* w2b = (const float*)d_in[13]; const float* b2b = (const float*)d_in[14];
  const float* w3a = (const float*)d_in[15]; const float* b3a = (const float*)d_in[16];
  const float* g3  = (const float*)d_in[17]; const float* be3 = (const float*)d_in[18];
  const float* w3b = (const float*)d_in[19]; const float* b3b = (const float*)d_in[20];
  const float* wh1 = (const float*)d_in[21]; const float* bh1 = (const float*)d_in[22];
  const float* wh2 = (const float*)d_in[23]; const float* bh2 = (const float*)d_in[24];
  float* out = (float*)d_out;

  const int N = in_sizes[0] / 128;   // 50000
  const int E = in_sizes[1] / 2;     // 800000
  const int G = 512;

  // ---- workspace layout: P = f32 region (z / act), Q = split region ----
  char* ws = (char*)d_ws;
  size_t off = 0;
  auto alloc = [&](size_t bytes) {
    void* p = ws + off;
    off = (off + bytes + 255) & ~(size_t)255;
    return p;
  };
  float* Pf = (float*)alloc((size_t)N * 256 * 4);
  unsigned short* Qhi = (unsigned short*)alloc((size_t)N * 256 * 2);
  unsigned short* Qlo = (unsigned short*)alloc((size_t)N * 256 * 2);
  int* adj     = (int*)alloc((size_t)E * 4);
  int* rowptr  = (int*)alloc((size_t)(N + 1) * 4);
  int* cursor  = (int*)alloc((size_t)N * 4);
  int* deg     = (int*)alloc((size_t)N * 4);
  int* partial = (int*)alloc((size_t)N * 4);
  int* bsum    = (int*)alloc(64 * 4);
  unsigned short* wHi = (unsigned short*)alloc(884736 * 2);
  unsigned short* wLo = (unsigned short*)alloc(884736 * 2);
  float* stats = (float*)alloc(512 * 4);
  int* gs      = (int*)alloc(G * 4);
  int* ge      = (int*)alloc(G * 4);
  unsigned short* poolHi = (unsigned short*)alloc((size_t)G * 256 * 2);
  unsigned short* poolLo = (unsigned short*)alloc((size_t)G * 256 * 2);
  unsigned short* thidHi = (unsigned short*)alloc((size_t)G * 512 * 2);
  unsigned short* thidLo = (unsigned short*)alloc((size_t)G * 512 * 2);

  // transposed-weight element offsets (match k_prep_all segment table)
  const int o1a = 0, o1b = 32768, o2a = 98304, o2b = 163840, o3a = 229376, o3b = 294912;
  const int oh1 = 360448, oh2 = 491520;   // ends at 884736

  hipMemsetAsync(deg, 0, (size_t)N * 4, stream);
  hipMemsetAsync(gs, 0, (size_t)G * 4, stream);
  hipMemsetAsync(ge, 0, (size_t)G * 4, stream);

  int eb = (E + 255) / 256;
  int nbN = (N + 255) / 256;
  int nb1 = (N + 1023) >> 10;   // 49 (<=64 required by k_scan2)
  k_histbounds<<<eb + nbN, 256, 0, stream>>>(ei, deg, E, eb, bat, gs, ge, N);
  k_scan1<<<nb1, 1024, 0, stream>>>(deg, partial, bsum, N);
  k_scan2<<<1, 64, 0, stream>>>(bsum, nb1);
  k_scan3<<<nbN, 256, 0, stream>>>(deg, partial, bsum, rowptr, cursor, N);
  k_fill<<<eb, 256, 0, stream>>>(ei, cursor, adj, E);

  k_prep_all<<<3456, 256, 0, stream>>>(w1a, w1b, w2a, w2b, w3a, w3b, wh1, wh2, wHi, wLo);

  int nb4 = (N + 3) / 4;
  int bnb = (N * 32 + 255) / 256;
  const int mb = (N + 63) / 64;          // 782 M-tiles of 64 rows
  const int per = (mb + 7) / 8;          // 98
  dim3 gg(per * 8);                      // XCD-chunked flat grid (full-N blocks)

  // ---- layer 1 ----
  k_agg<128><<<nb4, 256, 0, stream>>>(x, Qhi, Qlo, rowptr, adj, N);
  hipMemsetAsync(stats, 0, 512 * 4, stream);
  k_gemm<0, true, false, true><<<gg, 256, 0, stream>>>(Qhi, Qlo, N, 128, 256, mb, per, wHi + o1a, wLo + o1a, b1a, Pf, nullptr, nullptr, stats);
  k_bn<<<bnb, 256, 0, stream>>>(Pf, stats, g1, be1, Qhi, Qlo, N);
  k_gemm<1, false, false, true><<<gg, 256, 0, stream>>>(Qhi, Qlo, N, 256, 256, mb, per, wHi + o1b, wLo + o1b, b1b, Pf, nullptr, nullptr, nullptr);

  // ---- layer 2 ----
  k_agg<256><<<nb4, 256, 0, stream>>>(Pf, Qhi, Qlo, rowptr, adj, N);
  hipMemsetAsync(stats, 0, 512 * 4, stream);
  k_gemm<0, true, false, true><<<gg, 256, 0, stream>>>(Qhi, Qlo, N, 256, 256, mb, per, wHi + o2a, wLo + o2a, b2a, Pf, nullptr, nullptr, stats);
  k_bn<<<bnb, 256, 0, stream>>>(Pf, stats, g2, be2, Qhi, Qlo, N);
  k_gemm<3, false, false, true><<<gg, 256, 0, stream>>>(Qhi, Qlo, N, 256, 256, mb, per, wHi + o2b, wLo + o2b, b2b, Pf, nullptr, nullptr, nullptr);

  // ---- layer 3 ----
  k_agg<256><<<nb4, 256, 0, stream>>>(Pf, Qhi, Qlo, rowptr, adj, N);
  hipMemsetAsync(stats, 0, 512 * 4, stream);
  k_gemm<0, true, false, true><<<gg, 256, 0, stream>>>(Qhi, Qlo, N, 256, 256, mb, per, wHi + o3a, wLo + o3a, b3a, Pf, nullptr, nullptr, stats);
  k_bn<<<bnb, 256, 0, stream>>>(Pf, stats, g3, be3, Qhi, Qlo, N);
  k_gemm<2, false, false, true><<<gg, 256, 0, stream>>>(Qhi, Qlo, N, 256, 256, mb, per, wHi + o3b, wLo + o3b, b3b, Pf, nullptr, nullptr, nullptr);

  // ---- pool + MFMA heads ----
  k_pool<<<G, 256, 0, stream>>>(Pf, gs, ge, poolHi, poolLo);
  dim3 gh1(8, 2);   // M=512/64 tiles x 2 col-slabs (N=512)
  k_gemm<1, false, true, false><<<gh1, 256, 0, stream>>>(poolHi, poolLo, G, 256, 512, 0, 0, wHi + oh1, wLo + oh1, bh1, nullptr, thidHi, thidLo, nullptr);
  dim3 gh2(8, 3);   // M=512/64 tiles x 3 col-slabs (N=768)
  k_gemm<0, false, false, false><<<gh2, 256, 0, stream>>>(thidHi, thidLo, G, 512, 768, 0, 0, wHi + oh2, wLo + oh2, bh2, out, nullptr, nullptr, nullptr);
}

// Round 12
// 812.402 us; speedup vs baseline: 1.1497x; 1.0682x over previous
//
#include <hip/hip_runtime.h>

// ---------------------------------------------------------------------------
// GIN GraphEncoder on MI355X.
// All GEMMs: MFMA split-bf16 (hi/lo, 3-product ~f32 accuracy), 128x128 tile,
// BK=32, single-buffer 32KB LDS (R9 structure -- best measured).
// R12: k_bn ELIMINATED -- gemmB applies BN+relu+split inline in its A-staging
// (BNP path: reg-stage z f32, sc/sh precomputed per-column into LDS, split,
// ds_write_b128; B still global_load_lds). Saves ~205MB/layer intermediate
// traffic + 3 launches. Buffers: 3 rotating 51.2MB regions
// (act -> {splitHi,splitLo} -> z -> act), same total footprint.
// Storage swizzle: 16B k-groups XORed within 32-elem blocks with
// sw(row)=(row&3)^((row>>2)&3) (bank-spread; staging global addr stays linear).
// Main GEMMs: XCD-pair block swizzle. Integer inputs arrive as int32.
// Ledger: dbuf +-0 (R8), bank-swizzle -12 (R9), sort +82 regress (R10),
// 64x256 tile -16 regress (R11) -- both reverted.
// ---------------------------------------------------------------------------

typedef __attribute__((ext_vector_type(8))) short short8;   // 8 bf16 for MFMA
typedef __attribute__((ext_vector_type(4))) float f32x4;
typedef __attribute__((ext_vector_type(4))) unsigned short us4;
typedef __attribute__((ext_vector_type(8))) unsigned short us8;

__device__ __forceinline__ unsigned short f2bf(float f) {
  unsigned int b = __float_as_uint(f);
  unsigned int r = 0x7FFFu + ((b >> 16) & 1u);   // round-to-nearest-even
  return (unsigned short)((b + r) >> 16);
}
__device__ __forceinline__ float bf2f(unsigned short u) {
  return __uint_as_float(((unsigned int)u) << 16);
}

// bank-spread row swizzle value (4-group domain)
__device__ __forceinline__ int swv(int row) {
  return (row & 3) ^ ((row >> 2) & 3);
}

// global->LDS 16B async copy; LDS dest is wave-uniform base (HW adds lane*16)
typedef const __attribute__((address_space(1))) unsigned int* gas1;
typedef __attribute__((address_space(3))) unsigned int* las3;
__device__ __forceinline__ void gload16(const void* g, void* l) {
  __builtin_amdgcn_global_load_lds((gas1)g, (las3)l, 16, 0, 0);
}

// swizzled flat index of element (row, k), row length K:
// 16B groups (8 us) XORed within each 32-elem block: g' = g ^ swv(row)
__device__ __forceinline__ size_t swz4_idx(int row, int k, int K) {
  int g = k >> 3;
  return (size_t)row * K + ((g >> 2) << 5) + ((((g & 3) ^ swv(row)) << 3)) + (k & 7);
}

// ---------------- CSR build + graph bounds (fused) ----------------
__global__ void k_histbounds(const int* __restrict__ ei, int* __restrict__ deg, int E,
                             int eb, const int* __restrict__ batch,
                             int* __restrict__ gs, int* __restrict__ ge, int N) {
  int b = blockIdx.x;
  if (b < eb) {
    int e = b * 256 + threadIdx.x;
    if (e < E) atomicAdd(&deg[ei[E + e]], 1);
  } else {
    int i = (b - eb) * 256 + threadIdx.x;
    if (i < N) {
      int bb = batch[i];
      if (i == 0 || batch[i - 1] != bb) gs[bb] = i;
      if (i == N - 1 || batch[i + 1] != bb) ge[bb] = i + 1;
    }
  }
}

// phase 1: per-block (1024 elems) inclusive scan + block sum
__global__ __launch_bounds__(1024) void k_scan1(const int* __restrict__ deg,
                                                int* __restrict__ partial,
                                                int* __restrict__ bsum, int N) {
  __shared__ int sd[1024];
  int tid = threadIdx.x;
  int i = blockIdx.x * 1024 + tid;
  int v = (i < N) ? deg[i] : 0;
  sd[tid] = v;
  __syncthreads();
  for (int off = 1; off < 1024; off <<= 1) {
    int t = (tid >= off) ? sd[tid - off] : 0;
    __syncthreads();
    sd[tid] += t;
    __syncthreads();
  }
  if (i < N) partial[i] = sd[tid];
  if (tid == 1023) bsum[blockIdx.x] = sd[1023];
}

// phase 2: exclusive scan of <=64 block sums in one wave
__global__ void k_scan2(int* __restrict__ bsum, int nb) {
  int l = threadIdx.x;
  int orig = (l < nb) ? bsum[l] : 0;
  int v = orig;
  for (int off = 1; off < 64; off <<= 1) {
    int t = __shfl_up(v, off);
    if (l >= off) v += t;
  }
  if (l < nb) bsum[l] = v - orig;
}

// phase 3: rowptr / cursor
__global__ void k_scan3(const int* __restrict__ deg, const int* __restrict__ partial,
                        const int* __restrict__ bsum, int* __restrict__ rowptr,
                        int* __restrict__ cursor, int N) {
  int i = blockIdx.x * 256 + threadIdx.x;
  if (i >= N) return;
  int incl = partial[i] + bsum[i >> 10];
  rowptr[i + 1] = incl;
  cursor[i] = incl - deg[i];
  if (i == 0) rowptr[0] = 0;
}

__global__ void k_fill(const int* __restrict__ ei, int* __restrict__ cursor,
                       int* __restrict__ adj, int E) {
  int e = blockIdx.x * 256 + threadIdx.x;
  if (e >= E) return;
  int s = ei[e];
  int d = ei[E + e];
  int pos = atomicAdd(&cursor[d], 1);
  adj[pos] = s;
}

// ---- ALL weights: transpose + split + swizzle in ONE kernel ----
__global__ void k_prep_all(const float* __restrict__ w1a, const float* __restrict__ w1b,
                           const float* __restrict__ w2a, const float* __restrict__ w2b,
                           const float* __restrict__ w3a, const float* __restrict__ w3b,
                           const float* __restrict__ wh1, const float* __restrict__ wh2,
                           unsigned short* __restrict__ Hi, unsigned short* __restrict__ Lo) {
  int idx = blockIdx.x * 256 + threadIdx.x;   // [0, 884736)
  const float* W; int K, Nout, lo_;
  if (idx < 32768)       { W = w1a; K = 128; Nout = 256; lo_ = 0; }
  else if (idx < 98304)  { W = w1b; K = 256; Nout = 256; lo_ = 32768; }
  else if (idx < 163840) { W = w2a; K = 256; Nout = 256; lo_ = 98304; }
  else if (idx < 229376) { W = w2b; K = 256; Nout = 256; lo_ = 163840; }
  else if (idx < 294912) { W = w3a; K = 256; Nout = 256; lo_ = 229376; }
  else if (idx < 360448) { W = w3b; K = 256; Nout = 256; lo_ = 294912; }
  else if (idx < 491520) { W = wh1; K = 256; Nout = 512; lo_ = 360448; }
  else                   { W = wh2; K = 512; Nout = 768; lo_ = 491520; }
  int li = idx - lo_;
  int n = li % Nout, k = li / Nout;
  float w = W[k * Nout + n];
  unsigned short h = f2bf(w);
  size_t oi = (size_t)lo_ + swz4_idx(n, k, K);
  Hi[oi] = h;
  Lo[oi] = f2bf(w - bf2f(h));
}

// -------- aggregation: h = X[i] + sum X[adj[e]]; write split+swizzled --------
template <int C>
__global__ __launch_bounds__(256) void k_agg(const float* __restrict__ X,
                                             unsigned short* __restrict__ HHi,
                                             unsigned short* __restrict__ HLo,
                                             const int* __restrict__ rowptr,
                                             const int* __restrict__ adj, int N) {
  int node = blockIdx.x * 4 + (threadIdx.x >> 6);
  if (node >= N) return;
  int lane = threadIdx.x & 63;
  int e0 = rowptr[node], e1 = rowptr[node + 1];
  if constexpr (C == 256) {
    float4 acc = ((const float4*)(X + (size_t)node * C))[lane];
    int e = e0;
    for (; e + 4 <= e1; e += 4) {
      int s0 = adj[e], s1 = adj[e + 1], s2 = adj[e + 2], s3 = adj[e + 3];
      float4 v0 = ((const float4*)(X + (size_t)s0 * C))[lane];
      float4 v1 = ((const float4*)(X + (size_t)s1 * C))[lane];
      float4 v2 = ((const float4*)(X + (size_t)s2 * C))[lane];
      float4 v3 = ((const float4*)(X + (size_t)s3 * C))[lane];
      acc.x += (v0.x + v1.x) + (v2.x + v3.x);
      acc.y += (v0.y + v1.y) + (v2.y + v3.y);
      acc.z += (v0.z + v1.z) + (v2.z + v3.z);
      acc.w += (v0.w + v1.w) + (v2.w + v3.w);
    }
    for (; e < e1; ++e) {
      int s = adj[e];
      float4 v = ((const float4*)(X + (size_t)s * C))[lane];
      acc.x += v.x; acc.y += v.y; acc.z += v.z; acc.w += v.w;
    }
    float vv[4] = {acc.x, acc.y, acc.z, acc.w};
    us4 hv, lv;
#pragma unroll
    for (int j = 0; j < 4; ++j) {
      unsigned short h = f2bf(vv[j]);
      hv[j] = h;
      lv[j] = f2bf(vv[j] - bf2f(h));
    }
    // lane covers cols lane*4..+3 -> group g = lane>>1, half = lane&1
    size_t oi = (size_t)node * 256 + ((lane >> 3) << 5) +
                ((((lane >> 1) & 3) ^ swv(node)) << 3) + ((lane & 1) << 2);
    *(us4*)(HHi + oi) = hv;
    *(us4*)(HLo + oi) = lv;
  } else {  // C == 128
    float2 acc = ((const float2*)(X + (size_t)node * C))[lane];
    int e = e0;
    for (; e + 4 <= e1; e += 4) {
      int s0 = adj[e], s1 = adj[e + 1], s2 = adj[e + 2], s3 = adj[e + 3];
      float2 v0 = ((const float2*)(X + (size_t)s0 * C))[lane];
      float2 v1 = ((const float2*)(X + (size_t)s1 * C))[lane];
      float2 v2 = ((const float2*)(X + (size_t)s2 * C))[lane];
      float2 v3 = ((const float2*)(X + (size_t)s3 * C))[lane];
      acc.x += (v0.x + v1.x) + (v2.x + v3.x);
      acc.y += (v0.y + v1.y) + (v2.y + v3.y);
    }
    for (; e < e1; ++e) {
      int s = adj[e];
      float2 v = ((const float2*)(X + (size_t)s * C))[lane];
      acc.x += v.x; acc.y += v.y;
    }
    unsigned short hx = f2bf(acc.x), hy = f2bf(acc.y);
    ushort2 hv = {hx, hy};
    ushort2 lv = {f2bf(acc.x - bf2f(hx)), f2bf(acc.y - bf2f(hy))};
    size_t oi = (size_t)node * 128 + ((lane >> 4) << 5) +
                ((((lane >> 2) & 3) ^ swv(node)) << 3) + ((lane & 3) << 1);
    *(ushort2*)(HHi + oi) = hv;
    *(ushort2*)(HLo + oi) = lv;
  }
}

// ------------ MFMA GEMM: single-buffer BK=32, 128x128 tile (R9) -------------
// Out[M][Nld] = A[M][K] @ Wt^T + bias.
// A source: BNP=false -> presplit+swizzled arrays via gload16 (pure copy);
//           BNP=true  -> f32 z, BN+relu (sc/sh from LDS precompute) + split
//                        in registers, ds_write_b128 (k_bn fused away).
// EPI: 0 none, 1 relu, 2 tanh, 3 relu(tanh). STATS: fused BN sum/sumsq out.
// OSPLIT: write split+swizzled (relu). XSWZ: XCD-pair block swizzle.
template <int EPI, bool STATS, bool OSPLIT, bool XSWZ, bool BNP>
__global__ __launch_bounds__(256) void k_gemm(
    const unsigned short* __restrict__ AHi, const unsigned short* __restrict__ ALo,
    const float* __restrict__ Zf,
    int M, int K, int Nld, int mb, int per,
    const unsigned short* __restrict__ WHi, const unsigned short* __restrict__ WLo,
    const float* __restrict__ bias,
    const float* __restrict__ statsIn, const float* __restrict__ gvec,
    const float* __restrict__ bevec,
    float* __restrict__ Out,
    unsigned short* __restrict__ OHi, unsigned short* __restrict__ OLo,
    float* __restrict__ statsOut) {
  __shared__ unsigned short aHi[4096], aLo[4096], bHi[4096], bLo[4096];  // 4x8KB
  __shared__ float sBNsc[BNP ? 256 : 1], sBNsh[BNP ? 256 : 1];
  int bx, by;
  if constexpr (XSWZ) {
    int xcd = blockIdx.x & 7, slot = blockIdx.x >> 3;
    bx = xcd * per + (slot >> 1);
    by = slot & 1;
    if (bx >= mb) return;
  } else {
    bx = blockIdx.x;
    by = blockIdx.y;
  }
  const int tid = threadIdx.x;
  const int lane = tid & 63, w = tid >> 6;
  const int wm = w >> 1, wn = w & 1;
  const int m0 = bx * 128, n0 = by * 128;

  if constexpr (BNP) {
    // per-column scale/shift, exact op order of the old k_bn (bit-identical)
    float mu = statsIn[tid] / (float)M;
    float var = statsIn[256 + tid] / (float)M - mu * mu;
    float sc = gvec[tid] * rsqrtf(var + 1e-5f);
    sBNsc[tid] = sc;
    sBNsh[tid] = bevec[tid] - mu * sc;
    // first loop-iteration barrier makes these visible before staging reads
  }

  f32x4 zero = {0.f, 0.f, 0.f, 0.f};
  f32x4 acc[4][4];
#pragma unroll
  for (int i = 0; i < 4; ++i)
#pragma unroll
    for (int j = 0; j < 4; ++j) acc[i][j] = zero;

  // gload16 staging map: wave w rows [32w,32w+32); issue q: rows 32w+16q+(lane>>2),
  // slot lane&3; LDS linear (lane*16 off wave-uniform base).
  const int rq = lane >> 2;
  const int k8s = lane & 3;

  for (int kb = 0; kb < K; kb += 32) {
    __syncthreads();
    if constexpr (BNP) {
      // A: reg-staged from f32 z, BN+relu+split, swizzled ds_write_b128
#pragma unroll
      for (int p = 0; p < 2; ++p) {
        int idx = tid + p * 256;            // 512 (row, 8-col-group) tasks
        int row = idx >> 2, gq = idx & 3;
        int ra = m0 + row; if (ra >= M) ra = M - 1;   // clamp (junk never stored)
        const float* zp = Zf + (size_t)ra * K + kb + gq * 8;
        float4 v0 = *(const float4*)zp;
        float4 v1 = *(const float4*)(zp + 4);
        float f[8] = {v0.x, v0.y, v0.z, v0.w, v1.x, v1.y, v1.z, v1.w};
        us8 hv, lv;
#pragma unroll
        for (int jj = 0; jj < 8; ++jj) {
          int kc = kb + gq * 8 + jj;
          float o = fmaxf(f[jj] * sBNsc[kc] + sBNsh[kc], 0.f);
          unsigned short h = f2bf(o);
          hv[jj] = h;
          lv[jj] = f2bf(o - bf2f(h));
        }
        int bo = row * 64 + ((gq ^ swv(row)) << 4);
        *(us8*)((char*)aHi + bo) = hv;
        *(us8*)((char*)aLo + bo) = lv;
      }
      // B via gload16 (pure copy)
#pragma unroll
      for (int q = 0; q < 2; ++q) {
        int rloc = (w << 5) + (q << 4) + rq;
        size_t gb = (size_t)(n0 + rloc) * K + kb + k8s * 8;
        unsigned bo = (w << 11) + (q << 10);
        gload16(WHi + gb, (char*)bHi + bo);
        gload16(WLo + gb, (char*)bLo + bo);
      }
    } else {
#pragma unroll
      for (int q = 0; q < 2; ++q) {
        int rloc = (w << 5) + (q << 4) + rq;
        int ra = m0 + rloc; if (ra >= M) ra = M - 1;   // clamp tail
        size_t ga = (size_t)ra * K + kb + k8s * 8;     // swizzles cancel -> linear
        size_t gb = (size_t)(n0 + rloc) * K + kb + k8s * 8;
        unsigned bo = (w << 11) + (q << 10);           // wave-uniform LDS base
        gload16(AHi + ga, (char*)aHi + bo);
        gload16(ALo + ga, (char*)aLo + bo);
        gload16(WHi + gb, (char*)bHi + bo);
        gload16(WLo + gb, (char*)bLo + bo);
      }
    }
    __syncthreads();   // drains vmcnt+lgkmcnt before s_barrier -> LDS ready

    const int j = lane >> 4;
    short8 bh[4], bl[4];
#pragma unroll
    for (int ni = 0; ni < 4; ++ni) {
      int r = wn * 64 + ni * 16 + (lane & 15);
      int bo = r * 64 + ((j ^ swv(r)) << 4);
      bh[ni] = *(const short8*)((const char*)bHi + bo);
      bl[ni] = *(const short8*)((const char*)bLo + bo);
    }
#pragma unroll
    for (int mi = 0; mi < 4; ++mi) {
      int r = wm * 64 + mi * 16 + (lane & 15);
      int bo = r * 64 + ((j ^ swv(r)) << 4);
      short8 ah = *(const short8*)((const char*)aHi + bo);
      short8 al = *(const short8*)((const char*)aLo + bo);
#pragma unroll
      for (int ni = 0; ni < 4; ++ni) {
        acc[mi][ni] = __builtin_amdgcn_mfma_f32_16x16x32_bf16(ah, bh[ni], acc[mi][ni], 0, 0, 0);
        acc[mi][ni] = __builtin_amdgcn_mfma_f32_16x16x32_bf16(ah, bl[ni], acc[mi][ni], 0, 0, 0);
        acc[mi][ni] = __builtin_amdgcn_mfma_f32_16x16x32_bf16(al, bh[ni], acc[mi][ni], 0, 0, 0);
      }
    }
  }

  // epilogue: C/D layout col = lane&15, row = (lane>>4)*4 + r   [m89-verified]
#pragma unroll
  for (int ni = 0; ni < 4; ++ni) {
    int col = n0 + wn * 64 + ni * 16 + (lane & 15);
    float bc = bias[col];
    float s = 0.f, q = 0.f;
#pragma unroll
    for (int mi = 0; mi < 4; ++mi) {
      int rbase = m0 + wm * 64 + mi * 16 + (lane >> 4) * 4;
#pragma unroll
      for (int r = 0; r < 4; ++r) {
        int row = rbase + r;
        if (row < M) {
          float o = acc[mi][ni][r] + bc;
          if (STATS) { s += o; q += o * o; }
          if (OSPLIT) {
            o = fmaxf(o, 0.f);   // relu (head1)
            unsigned short h = f2bf(o);
            size_t oi = swz4_idx(row, col, Nld);
            OHi[oi] = h;
            OLo[oi] = f2bf(o - bf2f(h));
          } else {
            if (EPI == 1) o = fmaxf(o, 0.f);
            else if (EPI == 2) o = tanhf(o);
            else if (EPI == 3) o = fmaxf(tanhf(o), 0.f);
            Out[(size_t)row * Nld + col] = o;
          }
        }
      }
    }
    if (STATS) {
      s += __shfl_xor(s, 16); s += __shfl_xor(s, 32);
      q += __shfl_xor(q, 16); q += __shfl_xor(q, 32);
      if ((lane >> 4) == 0) {
        atomicAdd(&statsOut[col], s);
        atomicAdd(&statsOut[256 + col], q);
      }
    }
  }
}

// ---------------- pooling ----------------
// 4 waves stride rows, float4 lanes, LDS reduce; write split+swizzled.
__global__ __launch_bounds__(256) void k_pool(const float* __restrict__ Hf,
                                              const int* __restrict__ gs,
                                              const int* __restrict__ ge,
                                              unsigned short* __restrict__ PHi,
                                              unsigned short* __restrict__ PLo) {
  __shared__ float4 red[4][64];
  int gi = blockIdx.x;
  int s = gs[gi], e = ge[gi];
  int w = threadIdx.x >> 6, lane = threadIdx.x & 63;
  float4 acc = {0.f, 0.f, 0.f, 0.f};
  for (int r = s + w; r < e; r += 4) {
    float4 v = ((const float4*)(Hf + (size_t)r * 256))[lane];
    acc.x += v.x; acc.y += v.y; acc.z += v.z; acc.w += v.w;
  }
  red[w][lane] = acc;
  __syncthreads();
  if (w == 0) {
    float4 a = red[0][lane], b = red[1][lane], c = red[2][lane], d = red[3][lane];
    float inv = 1.0f / fmaxf((float)(e - s), 1.0f);
    float vv[4] = {(a.x + b.x + c.x + d.x) * inv, (a.y + b.y + c.y + d.y) * inv,
                   (a.z + b.z + c.z + d.z) * inv, (a.w + b.w + c.w + d.w) * inv};
    us4 hv, lv;
#pragma unroll
    for (int j = 0; j < 4; ++j) {
      unsigned short h = f2bf(vv[j]);
      hv[j] = h;
      lv[j] = f2bf(vv[j] - bf2f(h));
    }
    size_t oi = (size_t)gi * 256 + ((lane >> 3) << 5) +
                ((((lane >> 1) & 3) ^ swv(gi)) << 3) + ((lane & 1) << 2);
    *(us4*)(PHi + oi) = hv;
    *(us4*)(PLo + oi) = lv;
  }
}

// ---------------------------------------------------------------------------
extern "C" void kernel_launch(void* const* d_in, const int* in_sizes, int n_in,
                              void* d_out, int out_size, void* d_ws, size_t ws_size,
                              hipStream_t stream) {
  const float* x      = (const float*)d_in[0];
  const int* ei       = (const int*)d_in[1];    // int32 from harness
  const int* bat      = (const int*)d_in[2];    // int32 from harness
  const float* w1a = (const float*)d_in[3];  const float* b1a = (const float*)d_in[4];
  const float* g1  = (const float*)d_in[5];  const float* be1 = (const float*)d_in[6];
  const float* w1b = (const float*)d_in[7];  const float* b1b = (const float*)d_in[8];
  const float* w2a = (const float*)d_in[9];  const float* b2a = (const float*)d_in[10];
  const float* g2  = (const float*)d_in[11]; const float* be2 = (const float*)d_in[12];
  const float* w2b = (const float*)d_in[13]; const float* b2b = (const float*)d_in[14];
  const float* w3a = (const float*)d_in[15]; const float* b3a = (const float*)d_in[16];
  const float* g3  = (const float*)d_in[17]; const float* be3 = (const float*)d_in[18];
  const float* w3b = (const float*)d_in[19]; const float* b3b = (const float*)d_in[20];
  const float* wh1 = (const float*)d_in[21]; const float* bh1 = (const float*)d_in[22];
  const float* wh2 = (const float*)d_in[23]; const float* bh2 = (const float*)d_in[24];
  float* out = (float*)d_out;

  const int N = in_sizes[0] / 128;   // 50000
  const int E = in_sizes[1] / 2;     // 800000
  const int G = 512;

  // ---- workspace: 3 rotating 51.2MB regions (act | splitHi | splitLo | z) ----
  char* ws = (char*)d_ws;
  size_t off = 0;
  auto alloc = [&](size_t bytes) {
    void* p = ws + off;
    off = (off + bytes + 255) & ~(size_t)255;
    return p;
  };
  char* reg0 = (char*)alloc((size_t)N * 256 * 4);
  char* reg1 = (char*)alloc((size_t)N * 256 * 4);
  char* reg2 = (char*)alloc((size_t)N * 256 * 4);
  int* adj     = (int*)alloc((size_t)E * 4);
  int* rowptr  = (int*)alloc((size_t)(N + 1) * 4);
  int* cursor  = (int*)alloc((size_t)N * 4);
  int* deg     = (int*)alloc((size_t)N * 4);
  int* partial = (int*)alloc((size_t)N * 4);
  int* bsum    = (int*)alloc(64 * 4);
  unsigned short* wHi = (unsigned short*)alloc(884736 * 2);
  unsigned short* wLo = (unsigned short*)alloc(884736 * 2);
  float* stats = (float*)alloc(512 * 4);
  int* gs      = (int*)alloc(G * 4);
  int* ge      = (int*)alloc(G * 4);
  unsigned short* poolHi = (unsigned short*)alloc((size_t)G * 256 * 2);
  unsigned short* poolLo = (unsigned short*)alloc((size_t)G * 256 * 2);
  unsigned short* thidHi = (unsigned short*)alloc((size_t)G * 512 * 2);
  unsigned short* thidLo = (unsigned short*)alloc((size_t)G * 512 * 2);

  // region views
  float* f0 = (float*)reg0; float* f1 = (float*)reg1; float* f2 = (float*)reg2;
  unsigned short* u0 = (unsigned short*)reg0;
  unsigned short* u1 = (unsigned short*)reg1;
  unsigned short* u2 = (unsigned short*)reg2;

  // transposed-weight element offsets (match k_prep_all segment table)
  const int o1a = 0, o1b = 32768, o2a = 98304, o2b = 163840, o3a = 229376, o3b = 294912;
  const int oh1 = 360448, oh2 = 491520;   // ends at 884736

  hipMemsetAsync(deg, 0, (size_t)N * 4, stream);
  hipMemsetAsync(gs, 0, (size_t)G * 4, stream);
  hipMemsetAsync(ge, 0, (size_t)G * 4, stream);

  int eb = (E + 255) / 256;
  int nbN = (N + 255) / 256;
  int nb1 = (N + 1023) >> 10;   // 49 (<=64 required by k_scan2)
  k_histbounds<<<eb + nbN, 256, 0, stream>>>(ei, deg, E, eb, bat, gs, ge, N);
  k_scan1<<<nb1, 1024, 0, stream>>>(deg, partial, bsum, N);
  k_scan2<<<1, 64, 0, stream>>>(bsum, nb1);
  k_scan3<<<nbN, 256, 0, stream>>>(deg, partial, bsum, rowptr, cursor, N);
  k_fill<<<eb, 256, 0, stream>>>(ei, cursor, adj, E);

  k_prep_all<<<3456, 256, 0, stream>>>(w1a, w1b, w2a, w2b, w3a, w3b, wh1, wh2, wHi, wLo);

  int nb4 = (N + 3) / 4;
  const int mb = (N + 127) / 128;        // 391
  const int per = (mb + 7) / 8;          // 49
  dim3 gg(per * 16);                     // XCD-pair swizzled flat grid

  // ---- layer 1: x -> split@{reg0,reg1} -> z@reg2 -> act@reg0 ----
  k_agg<128><<<nb4, 256, 0, stream>>>(x, u0, u1, rowptr, adj, N);
  hipMemsetAsync(stats, 0, 512 * 4, stream);
  k_gemm<0, true, false, true, false><<<gg, 256, 0, stream>>>(
      u0, u1, nullptr, N, 128, 256, mb, per, wHi + o1a, wLo + o1a, b1a,
      nullptr, nullptr, nullptr, f2, nullptr, nullptr, stats);
  k_gemm<1, false, false, true, true><<<gg, 256, 0, stream>>>(
      nullptr, nullptr, f2, N, 256, 256, mb, per, wHi + o1b, wLo + o1b, b1b,
      stats, g1, be1, f0, nullptr, nullptr, nullptr);

  // ---- layer 2: act@reg0 -> split@{reg1,reg2} -> z@reg0 -> act@reg1 ----
  k_agg<256><<<nb4, 256, 0, stream>>>(f0, u1, u2, rowptr, adj, N);
  hipMemsetAsync(stats, 0, 512 * 4, stream);
  k_gemm<0, true, false, true, false><<<gg, 256, 0, stream>>>(
      u1, u2, nullptr, N, 256, 256, mb, per, wHi + o2a, wLo + o2a, b2a,
      nullptr, nullptr, nullptr, f0, nullptr, nullptr, stats);
  k_gemm<3, false, false, true, true><<<gg, 256, 0, stream>>>(
      nullptr, nullptr, f0, N, 256, 256, mb, per, wHi + o2b, wLo + o2b, b2b,
      stats, g2, be2, f1, nullptr, nullptr, nullptr);

  // ---- layer 3: act@reg1 -> split@{reg2,reg0} -> z@reg1 -> act@reg2 ----
  k_agg<256><<<nb4, 256, 0, stream>>>(f1, u2, u0, rowptr, adj, N);
  hipMemsetAsync(stats, 0, 512 * 4, stream);
  k_gemm<0, true, false, true, false><<<gg, 256, 0, stream>>>(
      u2, u0, nullptr, N, 256, 256, mb, per, wHi + o3a, wLo + o3a, b3a,
      nullptr, nullptr, nullptr, f1, nullptr, nullptr, stats);
  k_gemm<2, false, false, true, true><<<gg, 256, 0, stream>>>(
      nullptr, nullptr, f1, N, 256, 256, mb, per, wHi + o3b, wLo + o3b, b3b,
      stats, g3, be3, f2, nullptr, nullptr, nullptr);

  // ---- pool + MFMA heads ----
  k_pool<<<G, 256, 0, stream>>>(f2, gs, ge, poolHi, poolLo);
  dim3 gh1(4, 4);   // M=512/128, N=512/128
  k_gemm<1, false, true, false, false><<<gh1, 256, 0, stream>>>(
      poolHi, poolLo, nullptr, G, 256, 512, 0, 0, wHi + oh1, wLo + oh1, bh1,
      nullptr, nullptr, nullptr, nullptr, thidHi, thidLo, nullptr);
  dim3 gh2(4, 6);   // M=512/128, N=768/128
  k_gemm<0, false, false, false, false><<<gh2, 256, 0, stream>>>(
      thidHi, thidLo, nullptr, G, 512, 768, 0, 0, wHi + oh2, wLo + oh2, bh2,
      nullptr, nullptr, nullptr, out, nullptr, nullptr, nullptr);
}

// Round 13
// 795.245 us; speedup vs baseline: 1.1745x; 1.0216x over previous
//
#include <hip/hip_runtime.h>

// ---------------------------------------------------------------------------
// GIN GraphEncoder on MI355X.
// Main GEMMs (R13): 2-PRODUCT split -- acc = aHi*wHi + aLo*wHi = exact-a x
// bf16(W). Omitted a*wLo term ~1e-4 abs/GEMM, washed by following BN.
// B-side wLo never staged: LDS 24KB, staging 6 gload16 rounds (was 8),
// MFMA/K-step 32 (was 48). Head GEMMs keep full 3-product (error feeds
// output directly). 128x128 tile, BK=32, single-buffer (R9 structure).
// gemmB applies BN+relu+split inline in A-staging (R12). Storage swizzle
// sw(row)=(row&3)^((row>>2)&3) on 16B k-groups (bank-spread, staging linear).
// XCD-pair block swizzle on main GEMMs. stats zeroing folded into k_agg
// block 0 (-3 dispatches). Integer inputs arrive as int32.
// Ledger: dbuf +-0 (R8), bank-swz -12 (R9), sort/wide-tile regressions
// reverted (R10/R11), BN-fusion -56 (R12).
// ---------------------------------------------------------------------------

typedef __attribute__((ext_vector_type(8))) short short8;   // 8 bf16 for MFMA
typedef __attribute__((ext_vector_type(4))) float f32x4;
typedef __attribute__((ext_vector_type(4))) unsigned short us4;
typedef __attribute__((ext_vector_type(8))) unsigned short us8;

__device__ __forceinline__ unsigned short f2bf(float f) {
  unsigned int b = __float_as_uint(f);
  unsigned int r = 0x7FFFu + ((b >> 16) & 1u);   // round-to-nearest-even
  return (unsigned short)((b + r) >> 16);
}
__device__ __forceinline__ float bf2f(unsigned short u) {
  return __uint_as_float(((unsigned int)u) << 16);
}

// bank-spread row swizzle value (4-group domain)
__device__ __forceinline__ int swv(int row) {
  return (row & 3) ^ ((row >> 2) & 3);
}

// global->LDS 16B async copy; LDS dest is wave-uniform base (HW adds lane*16)
typedef const __attribute__((address_space(1))) unsigned int* gas1;
typedef __attribute__((address_space(3))) unsigned int* las3;
__device__ __forceinline__ void gload16(const void* g, void* l) {
  __builtin_amdgcn_global_load_lds((gas1)g, (las3)l, 16, 0, 0);
}

// swizzled flat index of element (row, k), row length K:
// 16B groups (8 us) XORed within each 32-elem block: g' = g ^ swv(row)
__device__ __forceinline__ size_t swz4_idx(int row, int k, int K) {
  int g = k >> 3;
  return (size_t)row * K + ((g >> 2) << 5) + ((((g & 3) ^ swv(row)) << 3)) + (k & 7);
}

// ---------------- CSR build + graph bounds (fused) ----------------
__global__ void k_histbounds(const int* __restrict__ ei, int* __restrict__ deg, int E,
                             int eb, const int* __restrict__ batch,
                             int* __restrict__ gs, int* __restrict__ ge, int N) {
  int b = blockIdx.x;
  if (b < eb) {
    int e = b * 256 + threadIdx.x;
    if (e < E) atomicAdd(&deg[ei[E + e]], 1);
  } else {
    int i = (b - eb) * 256 + threadIdx.x;
    if (i < N) {
      int bb = batch[i];
      if (i == 0 || batch[i - 1] != bb) gs[bb] = i;
      if (i == N - 1 || batch[i + 1] != bb) ge[bb] = i + 1;
    }
  }
}

// phase 1: per-block (1024 elems) inclusive scan + block sum
__global__ __launch_bounds__(1024) void k_scan1(const int* __restrict__ deg,
                                                int* __restrict__ partial,
                                                int* __restrict__ bsum, int N) {
  __shared__ int sd[1024];
  int tid = threadIdx.x;
  int i = blockIdx.x * 1024 + tid;
  int v = (i < N) ? deg[i] : 0;
  sd[tid] = v;
  __syncthreads();
  for (int off = 1; off < 1024; off <<= 1) {
    int t = (tid >= off) ? sd[tid - off] : 0;
    __syncthreads();
    sd[tid] += t;
    __syncthreads();
  }
  if (i < N) partial[i] = sd[tid];
  if (tid == 1023) bsum[blockIdx.x] = sd[1023];
}

// phase 2: exclusive scan of <=64 block sums in one wave
__global__ void k_scan2(int* __restrict__ bsum, int nb) {
  int l = threadIdx.x;
  int orig = (l < nb) ? bsum[l] : 0;
  int v = orig;
  for (int off = 1; off < 64; off <<= 1) {
    int t = __shfl_up(v, off);
    if (l >= off) v += t;
  }
  if (l < nb) bsum[l] = v - orig;
}

// phase 3: rowptr / cursor
__global__ void k_scan3(const int* __restrict__ deg, const int* __restrict__ partial,
                        const int* __restrict__ bsum, int* __restrict__ rowptr,
                        int* __restrict__ cursor, int N) {
  int i = blockIdx.x * 256 + threadIdx.x;
  if (i >= N) return;
  int incl = partial[i] + bsum[i >> 10];
  rowptr[i + 1] = incl;
  cursor[i] = incl - deg[i];
  if (i == 0) rowptr[0] = 0;
}

__global__ void k_fill(const int* __restrict__ ei, int* __restrict__ cursor,
                       int* __restrict__ adj, int E) {
  int e = blockIdx.x * 256 + threadIdx.x;
  if (e >= E) return;
  int s = ei[e];
  int d = ei[E + e];
  int pos = atomicAdd(&cursor[d], 1);
  adj[pos] = s;
}

// ---- ALL weights: transpose + split + swizzle in ONE kernel ----
__global__ void k_prep_all(const float* __restrict__ w1a, const float* __restrict__ w1b,
                           const float* __restrict__ w2a, const float* __restrict__ w2b,
                           const float* __restrict__ w3a, const float* __restrict__ w3b,
                           const float* __restrict__ wh1, const float* __restrict__ wh2,
                           unsigned short* __restrict__ Hi, unsigned short* __restrict__ Lo) {
  int idx = blockIdx.x * 256 + threadIdx.x;   // [0, 884736)
  const float* W; int K, Nout, lo_;
  if (idx < 32768)       { W = w1a; K = 128; Nout = 256; lo_ = 0; }
  else if (idx < 98304)  { W = w1b; K = 256; Nout = 256; lo_ = 32768; }
  else if (idx < 163840) { W = w2a; K = 256; Nout = 256; lo_ = 98304; }
  else if (idx < 229376) { W = w2b; K = 256; Nout = 256; lo_ = 163840; }
  else if (idx < 294912) { W = w3a; K = 256; Nout = 256; lo_ = 229376; }
  else if (idx < 360448) { W = w3b; K = 256; Nout = 256; lo_ = 294912; }
  else if (idx < 491520) { W = wh1; K = 256; Nout = 512; lo_ = 360448; }
  else                   { W = wh2; K = 512; Nout = 768; lo_ = 491520; }
  int li = idx - lo_;
  int n = li % Nout, k = li / Nout;
  float w = W[k * Nout + n];
  unsigned short h = f2bf(w);
  size_t oi = (size_t)lo_ + swz4_idx(n, k, K);
  Hi[oi] = h;
  Lo[oi] = f2bf(w - bf2f(h));   // only heads read Lo, but writing is cheap
}

// -------- aggregation: h = X[i] + sum X[adj[e]]; write split+swizzled --------
// Block 0 also zeroes stats[] (consumed by the gemmA that follows serially).
template <int C>
__global__ __launch_bounds__(256) void k_agg(const float* __restrict__ X,
                                             unsigned short* __restrict__ HHi,
                                             unsigned short* __restrict__ HLo,
                                             const int* __restrict__ rowptr,
                                             const int* __restrict__ adj, int N,
                                             float* __restrict__ statsZ) {
  if (blockIdx.x == 0) {
    statsZ[threadIdx.x] = 0.f;
    statsZ[256 + threadIdx.x] = 0.f;
  }
  int node = blockIdx.x * 4 + (threadIdx.x >> 6);
  if (node >= N) return;
  int lane = threadIdx.x & 63;
  int e0 = rowptr[node], e1 = rowptr[node + 1];
  if constexpr (C == 256) {
    float4 acc = ((const float4*)(X + (size_t)node * C))[lane];
    int e = e0;
    for (; e + 4 <= e1; e += 4) {
      int s0 = adj[e], s1 = adj[e + 1], s2 = adj[e + 2], s3 = adj[e + 3];
      float4 v0 = ((const float4*)(X + (size_t)s0 * C))[lane];
      float4 v1 = ((const float4*)(X + (size_t)s1 * C))[lane];
      float4 v2 = ((const float4*)(X + (size_t)s2 * C))[lane];
      float4 v3 = ((const float4*)(X + (size_t)s3 * C))[lane];
      acc.x += (v0.x + v1.x) + (v2.x + v3.x);
      acc.y += (v0.y + v1.y) + (v2.y + v3.y);
      acc.z += (v0.z + v1.z) + (v2.z + v3.z);
      acc.w += (v0.w + v1.w) + (v2.w + v3.w);
    }
    for (; e < e1; ++e) {
      int s = adj[e];
      float4 v = ((const float4*)(X + (size_t)s * C))[lane];
      acc.x += v.x; acc.y += v.y; acc.z += v.z; acc.w += v.w;
    }
    float vv[4] = {acc.x, acc.y, acc.z, acc.w};
    us4 hv, lv;
#pragma unroll
    for (int j = 0; j < 4; ++j) {
      unsigned short h = f2bf(vv[j]);
      hv[j] = h;
      lv[j] = f2bf(vv[j] - bf2f(h));
    }
    size_t oi = (size_t)node * 256 + ((lane >> 3) << 5) +
                ((((lane >> 1) & 3) ^ swv(node)) << 3) + ((lane & 1) << 2);
    *(us4*)(HHi + oi) = hv;
    *(us4*)(HLo + oi) = lv;
  } else {  // C == 128
    float2 acc = ((const float2*)(X + (size_t)node * C))[lane];
    int e = e0;
    for (; e + 4 <= e1; e += 4) {
      int s0 = adj[e], s1 = adj[e + 1], s2 = adj[e + 2], s3 = adj[e + 3];
      float2 v0 = ((const float2*)(X + (size_t)s0 * C))[lane];
      float2 v1 = ((const float2*)(X + (size_t)s1 * C))[lane];
      float2 v2 = ((const float2*)(X + (size_t)s2 * C))[lane];
      float2 v3 = ((const float2*)(X + (size_t)s3 * C))[lane];
      acc.x += (v0.x + v1.x) + (v2.x + v3.x);
      acc.y += (v0.y + v1.y) + (v2.y + v3.y);
    }
    for (; e < e1; ++e) {
      int s = adj[e];
      float2 v = ((const float2*)(X + (size_t)s * C))[lane];
      acc.x += v.x; acc.y += v.y;
    }
    unsigned short hx = f2bf(acc.x), hy = f2bf(acc.y);
    ushort2 hv = {hx, hy};
    ushort2 lv = {f2bf(acc.x - bf2f(hx)), f2bf(acc.y - bf2f(hy))};
    size_t oi = (size_t)node * 128 + ((lane >> 4) << 5) +
                ((((lane >> 2) & 3) ^ swv(node)) << 3) + ((lane & 3) << 1);
    *(ushort2*)(HHi + oi) = hv;
    *(ushort2*)(HLo + oi) = lv;
  }
}

// ------------ MFMA GEMM: single-buffer BK=32, 128x128 tile -------------
// FULL=false: 2-product (aHi*wHi + aLo*wHi), wLo never staged, LDS 24KB.
// FULL=true (heads): 3-product as before, LDS 32KB.
// ASRC: 0 presplit gload16; 2 f32 z reg-staged with BN+relu+split (gemmB).
// EPI: 0 none, 1 relu, 2 tanh, 3 relu(tanh). STATS: fused BN sum/sumsq out.
// OSPLIT: write split+swizzled (relu). XSWZ: XCD-pair block swizzle.
template <int EPI, bool STATS, bool OSPLIT, bool XSWZ, int ASRC, bool FULL>
__global__ __launch_bounds__(256) void k_gemm(
    const unsigned short* __restrict__ AHi, const unsigned short* __restrict__ ALo,
    const float* __restrict__ Zf,
    int M, int K, int Nld, int mb, int per,
    const unsigned short* __restrict__ WHi, const unsigned short* __restrict__ WLo,
    const float* __restrict__ bias,
    const float* __restrict__ statsIn, const float* __restrict__ gvec,
    const float* __restrict__ bevec,
    float* __restrict__ Out,
    unsigned short* __restrict__ OHi, unsigned short* __restrict__ OLo,
    float* __restrict__ statsOut) {
  __shared__ unsigned short aHi[4096], aLo[4096], bHi[4096];
  __shared__ unsigned short bLo[FULL ? 4096 : 64];
  __shared__ float sBNsc[ASRC == 2 ? 256 : 1], sBNsh[ASRC == 2 ? 256 : 1];
  int bx, by;
  if constexpr (XSWZ) {
    int xcd = blockIdx.x & 7, slot = blockIdx.x >> 3;
    bx = xcd * per + (slot >> 1);
    by = slot & 1;
    if (bx >= mb) return;
  } else {
    bx = blockIdx.x;
    by = blockIdx.y;
  }
  const int tid = threadIdx.x;
  const int lane = tid & 63, w = tid >> 6;
  const int wm = w >> 1, wn = w & 1;
  const int m0 = bx * 128, n0 = by * 128;

  if constexpr (ASRC == 2) {
    // per-column scale/shift, exact op order of old k_finalize (bit-identical)
    float mu = statsIn[tid] / (float)M;
    float var = statsIn[256 + tid] / (float)M - mu * mu;
    float sc = gvec[tid] * rsqrtf(var + 1e-5f);
    sBNsc[tid] = sc;
    sBNsh[tid] = bevec[tid] - mu * sc;
    // first loop-iteration barrier publishes these before staging reads
  }

  f32x4 zero = {0.f, 0.f, 0.f, 0.f};
  f32x4 acc[4][4];
#pragma unroll
  for (int i = 0; i < 4; ++i)
#pragma unroll
    for (int j = 0; j < 4; ++j) acc[i][j] = zero;

  // gload16 staging map: wave w rows [32w,32w+32); issue q: rows 32w+16q+(lane>>2),
  // slot lane&3; LDS linear (lane*16 off wave-uniform base).
  const int rq = lane >> 2;
  const int k8s = lane & 3;

  for (int kb = 0; kb < K; kb += 32) {
    __syncthreads();
    if constexpr (ASRC == 2) {
      // A: reg-staged from f32 z, BN+relu+split, swizzled ds_write_b128
#pragma unroll
      for (int p = 0; p < 2; ++p) {
        int idx = tid + p * 256;            // 512 (row, 8-col-group) tasks
        int row = idx >> 2, gq = idx & 3;
        int ra = m0 + row; if (ra >= M) ra = M - 1;   // clamp (junk never stored)
        const float* zp = Zf + (size_t)ra * K + kb + gq * 8;
        float4 v0 = *(const float4*)zp;
        float4 v1 = *(const float4*)(zp + 4);
        float f[8] = {v0.x, v0.y, v0.z, v0.w, v1.x, v1.y, v1.z, v1.w};
        us8 hv, lv;
#pragma unroll
        for (int jj = 0; jj < 8; ++jj) {
          int kc = kb + gq * 8 + jj;
          float o = fmaxf(f[jj] * sBNsc[kc] + sBNsh[kc], 0.f);
          unsigned short h = f2bf(o);
          hv[jj] = h;
          lv[jj] = f2bf(o - bf2f(h));
        }
        int bo = row * 64 + ((gq ^ swv(row)) << 4);
        *(us8*)((char*)aHi + bo) = hv;
        *(us8*)((char*)aLo + bo) = lv;
      }
      // B via gload16 (pure copy; wHi only unless FULL)
#pragma unroll
      for (int q = 0; q < 2; ++q) {
        int rloc = (w << 5) + (q << 4) + rq;
        size_t gb = (size_t)(n0 + rloc) * K + kb + k8s * 8;
        unsigned bo = (w << 11) + (q << 10);
        gload16(WHi + gb, (char*)bHi + bo);
        if constexpr (FULL) gload16(WLo + gb, (char*)bLo + bo);
      }
    } else {
#pragma unroll
      for (int q = 0; q < 2; ++q) {
        int rloc = (w << 5) + (q << 4) + rq;
        int ra = m0 + rloc; if (ra >= M) ra = M - 1;   // clamp tail
        size_t ga = (size_t)ra * K + kb + k8s * 8;     // swizzles cancel -> linear
        size_t gb = (size_t)(n0 + rloc) * K + kb + k8s * 8;
        unsigned bo = (w << 11) + (q << 10);           // wave-uniform LDS base
        gload16(AHi + ga, (char*)aHi + bo);
        gload16(ALo + ga, (char*)aLo + bo);
        gload16(WHi + gb, (char*)bHi + bo);
        if constexpr (FULL) gload16(WLo + gb, (char*)bLo + bo);
      }
    }
    __syncthreads();   // drains vmcnt+lgkmcnt before s_barrier -> LDS ready

    const int j = lane >> 4;
    short8 bh[4], bl[4];
#pragma unroll
    for (int ni = 0; ni < 4; ++ni) {
      int r = wn * 64 + ni * 16 + (lane & 15);
      int bo = r * 64 + ((j ^ swv(r)) << 4);
      bh[ni] = *(const short8*)((const char*)bHi + bo);
      if constexpr (FULL) bl[ni] = *(const short8*)((const char*)bLo + bo);
    }
#pragma unroll
    for (int mi = 0; mi < 4; ++mi) {
      int r = wm * 64 + mi * 16 + (lane & 15);
      int bo = r * 64 + ((j ^ swv(r)) << 4);
      short8 ah = *(const short8*)((const char*)aHi + bo);
      short8 al = *(const short8*)((const char*)aLo + bo);
#pragma unroll
      for (int ni = 0; ni < 4; ++ni) {
        acc[mi][ni] = __builtin_amdgcn_mfma_f32_16x16x32_bf16(ah, bh[ni], acc[mi][ni], 0, 0, 0);
        if constexpr (FULL)
          acc[mi][ni] = __builtin_amdgcn_mfma_f32_16x16x32_bf16(ah, bl[ni], acc[mi][ni], 0, 0, 0);
        acc[mi][ni] = __builtin_amdgcn_mfma_f32_16x16x32_bf16(al, bh[ni], acc[mi][ni], 0, 0, 0);
      }
    }
  }

  // epilogue: C/D layout col = lane&15, row = (lane>>4)*4 + r   [m89-verified]
#pragma unroll
  for (int ni = 0; ni < 4; ++ni) {
    int col = n0 + wn * 64 + ni * 16 + (lane & 15);
    float bc = bias[col];
    float s = 0.f, q = 0.f;
#pragma unroll
    for (int mi = 0; mi < 4; ++mi) {
      int rbase = m0 + wm * 64 + mi * 16 + (lane >> 4) * 4;
#pragma unroll
      for (int r = 0; r < 4; ++r) {
        int row = rbase + r;
        if (row < M) {
          float o = acc[mi][ni][r] + bc;
          if (STATS) { s += o; q += o * o; }
          if (OSPLIT) {
            o = fmaxf(o, 0.f);   // relu (head1)
            unsigned short h = f2bf(o);
            size_t oi = swz4_idx(row, col, Nld);
            OHi[oi] = h;
            OLo[oi] = f2bf(o - bf2f(h));
          } else {
            if (EPI == 1) o = fmaxf(o, 0.f);
            else if (EPI == 2) o = tanhf(o);
            else if (EPI == 3) o = fmaxf(tanhf(o), 0.f);
            Out[(size_t)row * Nld + col] = o;
          }
        }
      }
    }
    if (STATS) {
      s += __shfl_xor(s, 16); s += __shfl_xor(s, 32);
      q += __shfl_xor(q, 16); q += __shfl_xor(q, 32);
      if ((lane >> 4) == 0) {
        atomicAdd(&statsOut[col], s);
        atomicAdd(&statsOut[256 + col], q);
      }
    }
  }
}

// ---------------- pooling ----------------
// 4 waves stride rows, float4 lanes, LDS reduce; write split+swizzled.
__global__ __launch_bounds__(256) void k_pool(const float* __restrict__ Hf,
                                              const int* __restrict__ gs,
                                              const int* __restrict__ ge,
                                              unsigned short* __restrict__ PHi,
                                              unsigned short* __restrict__ PLo) {
  __shared__ float4 red[4][64];
  int gi = blockIdx.x;
  int s = gs[gi], e = ge[gi];
  int w = threadIdx.x >> 6, lane = threadIdx.x & 63;
  float4 acc = {0.f, 0.f, 0.f, 0.f};
  for (int r = s + w; r < e; r += 4) {
    float4 v = ((const float4*)(Hf + (size_t)r * 256))[lane];
    acc.x += v.x; acc.y += v.y; acc.z += v.z; acc.w += v.w;
  }
  red[w][lane] = acc;
  __syncthreads();
  if (w == 0) {
    float4 a = red[0][lane], b = red[1][lane], c = red[2][lane], d = red[3][lane];
    float inv = 1.0f / fmaxf((float)(e - s), 1.0f);
    float vv[4] = {(a.x + b.x + c.x + d.x) * inv, (a.y + b.y + c.y + d.y) * inv,
                   (a.z + b.z + c.z + d.z) * inv, (a.w + b.w + c.w + d.w) * inv};
    us4 hv, lv;
#pragma unroll
    for (int j = 0; j < 4; ++j) {
      unsigned short h = f2bf(vv[j]);
      hv[j] = h;
      lv[j] = f2bf(vv[j] - bf2f(h));
    }
    size_t oi = (size_t)gi * 256 + ((lane >> 3) << 5) +
                ((((lane >> 1) & 3) ^ swv(gi)) << 3) + ((lane & 1) << 2);
    *(us4*)(PHi + oi) = hv;
    *(us4*)(PLo + oi) = lv;
  }
}

// ---------------------------------------------------------------------------
extern "C" void kernel_launch(void* const* d_in, const int* in_sizes, int n_in,
                              void* d_out, int out_size, void* d_ws, size_t ws_size,
                              hipStream_t stream) {
  const float* x      = (const float*)d_in[0];
  const int* ei       = (const int*)d_in[1];    // int32 from harness
  const int* bat      = (const int*)d_in[2];    // int32 from harness
  const float* w1a = (const float*)d_in[3];  const float* b1a = (const float*)d_in[4];
  const float* g1  = (const float*)d_in[5];  const float* be1 = (const float*)d_in[6];
  const float* w1b = (const float*)d_in[7];  const float* b1b = (const float*)d_in[8];
  const float* w2a = (const float*)d_in[9];  const float* b2a = (const float*)d_in[10];
  const float* g2  = (const float*)d_in[11]; const float* be2 = (const float*)d_in[12];
  const float* w2b = (const float*)d_in[13]; const float* b2b = (const float*)d_in[14];
  const float* w3a = (const float*)d_in[15]; const float* b3a = (const float*)d_in[16];
  const float* g3  = (const float*)d_in[17]; const float* be3 = (const float*)d_in[18];
  const float* w3b = (const float*)d_in[19]; const float* b3b = (const float*)d_in[20];
  const float* wh1 = (const float*)d_in[21]; const float* bh1 = (const float*)d_in[22];
  const float* wh2 = (const float*)d_in[23]; const float* bh2 = (const float*)d_in[24];
  float* out = (float*)d_out;

  const int N = in_sizes[0] / 128;   // 50000
  const int E = in_sizes[1] / 2;     // 800000
  const int G = 512;

  // ---- workspace: 3 rotating 51.2MB regions (act | splitHi | splitLo | z) ----
  char* ws = (char*)d_ws;
  size_t off = 0;
  auto alloc = [&](size_t bytes) {
    void* p = ws + off;
    off = (off + bytes + 255) & ~(size_t)255;
    return p;
  };
  char* reg0 = (char*)alloc((size_t)N * 256 * 4);
  char* reg1 = (char*)alloc((size_t)N * 256 * 4);
  char* reg2 = (char*)alloc((size_t)N * 256 * 4);
  int* adj     = (int*)alloc((size_t)E * 4);
  int* rowptr  = (int*)alloc((size_t)(N + 1) * 4);
  int* cursor  = (int*)alloc((size_t)N * 4);
  int* deg     = (int*)alloc((size_t)N * 4);
  int* partial = (int*)alloc((size_t)N * 4);
  int* bsum    = (int*)alloc(64 * 4);
  unsigned short* wHi = (unsigned short*)alloc(884736 * 2);
  unsigned short* wLo = (unsigned short*)alloc(884736 * 2);
  float* stats = (float*)alloc(512 * 4);
  int* gs      = (int*)alloc(G * 4);
  int* ge      = (int*)alloc(G * 4);
  unsigned short* poolHi = (unsigned short*)alloc((size_t)G * 256 * 2);
  unsigned short* poolLo = (unsigned short*)alloc((size_t)G * 256 * 2);
  unsigned short* thidHi = (unsigned short*)alloc((size_t)G * 512 * 2);
  unsigned short* thidLo = (unsigned short*)alloc((size_t)G * 512 * 2);

  // region views
  float* f0 = (float*)reg0; float* f1 = (float*)reg1; float* f2 = (float*)reg2;
  unsigned short* u0 = (unsigned short*)reg0;
  unsigned short* u1 = (unsigned short*)reg1;
  unsigned short* u2 = (unsigned short*)reg2;

  // transposed-weight element offsets (match k_prep_all segment table)
  const int o1a = 0, o1b = 32768, o2a = 98304, o2b = 163840, o3a = 229376, o3b = 294912;
  const int oh1 = 360448, oh2 = 491520;   // ends at 884736

  hipMemsetAsync(deg, 0, (size_t)N * 4, stream);
  hipMemsetAsync(gs, 0, (size_t)G * 4, stream);
  hipMemsetAsync(ge, 0, (size_t)G * 4, stream);

  int eb = (E + 255) / 256;
  int nbN = (N + 255) / 256;
  int nb1 = (N + 1023) >> 10;   // 49 (<=64 required by k_scan2)
  k_histbounds<<<eb + nbN, 256, 0, stream>>>(ei, deg, E, eb, bat, gs, ge, N);
  k_scan1<<<nb1, 1024, 0, stream>>>(deg, partial, bsum, N);
  k_scan2<<<1, 64, 0, stream>>>(bsum, nb1);
  k_scan3<<<nbN, 256, 0, stream>>>(deg, partial, bsum, rowptr, cursor, N);
  k_fill<<<eb, 256, 0, stream>>>(ei, cursor, adj, E);

  k_prep_all<<<3456, 256, 0, stream>>>(w1a, w1b, w2a, w2b, w3a, w3b, wh1, wh2, wHi, wLo);

  int nb4 = (N + 3) / 4;
  const int mb = (N + 127) / 128;        // 391
  const int per = (mb + 7) / 8;          // 49
  dim3 gg(per * 16);                     // XCD-pair swizzled flat grid

  // ---- layer 1: x -> split@{reg0,reg1} -> z@reg2 -> act@reg0 ----
  k_agg<128><<<nb4, 256, 0, stream>>>(x, u0, u1, rowptr, adj, N, stats);
  k_gemm<0, true, false, true, 0, false><<<gg, 256, 0, stream>>>(
      u0, u1, nullptr, N, 128, 256, mb, per, wHi + o1a, wLo + o1a, b1a,
      nullptr, nullptr, nullptr, f2, nullptr, nullptr, stats);
  k_gemm<1, false, false, true, 2, false><<<gg, 256, 0, stream>>>(
      nullptr, nullptr, f2, N, 256, 256, mb, per, wHi + o1b, wLo + o1b, b1b,
      stats, g1, be1, f0, nullptr, nullptr, nullptr);

  // ---- layer 2: act@reg0 -> split@{reg1,reg2} -> z@reg0 -> act@reg1 ----
  k_agg<256><<<nb4, 256, 0, stream>>>(f0, u1, u2, rowptr, adj, N, stats);
  k_gemm<0, true, false, true, 0, false><<<gg, 256, 0, stream>>>(
      u1, u2, nullptr, N, 256, 256, mb, per, wHi + o2a, wLo + o2a, b2a,
      nullptr, nullptr, nullptr, f0, nullptr, nullptr, stats);
  k_gemm<3, false, false, true, 2, false><<<gg, 256, 0, stream>>>(
      nullptr, nullptr, f0, N, 256, 256, mb, per, wHi + o2b, wLo + o2b, b2b,
      stats, g2, be2, f1, nullptr, nullptr, nullptr);

  // ---- layer 3: act@reg1 -> split@{reg2,reg0} -> z@reg1 -> act@reg2 ----
  k_agg<256><<<nb4, 256, 0, stream>>>(f1, u2, u0, rowptr, adj, N, stats);
  k_gemm<0, true, false, true, 0, false><<<gg, 256, 0, stream>>>(
      u2, u0, nullptr, N, 256, 256, mb, per, wHi + o3a, wLo + o3a, b3a,
      nullptr, nullptr, nullptr, f1, nullptr, nullptr, stats);
  k_gemm<2, false, false, true, 2, false><<<gg, 256, 0, stream>>>(
      nullptr, nullptr, f1, N, 256, 256, mb, per, wHi + o3b, wLo + o3b, b3b,
      stats, g3, be3, f2, nullptr, nullptr, nullptr);

  // ---- pool + MFMA heads (heads keep FULL 3-product split) ----
  k_pool<<<G, 256, 0, stream>>>(f2, gs, ge, poolHi, poolLo);
  dim3 gh1(4, 4);   // M=512/128, N=512/128
  k_gemm<1, false, true, false, 0, true><<<gh1, 256, 0, stream>>>(
      poolHi, poolLo, nullptr, G, 256, 512, 0, 0, wHi + oh1, wLo + oh1, bh1,
      nullptr, nullptr, nullptr, nullptr, thidHi, thidLo, nullptr);
  dim3 gh2(4, 6);   // M=512/128, N=768/128
  k_gemm<0, false, false, false, 0, true><<<gh2, 256, 0, stream>>>(
      thidHi, thidLo, nullptr, G, 512, 768, 0, 0, wHi + oh2, wLo + oh2, bh2,
      nullptr, nullptr, nullptr, out, nullptr, nullptr, nullptr);
}

// Round 14
// 675.009 us; speedup vs baseline: 1.3837x; 1.1781x over previous
//
#include <hip/hip_runtime.h>

// ---------------------------------------------------------------------------
// GIN GraphEncoder on MI355X.
// R14: BF16 GATHER -- inter-layer activations stored bf16 (gemmB epilogue),
// x converted once (k_xbf); k_agg/k_pool gather 2B/elem (halves the 819MB
// gather demand; 25.6MB window L3-resident). Accuracy rationale: R13 showed
// bf16-class weight rounding moved absmax by ZERO (comparison floor 2^-10);
// activation rounding is the same class + pool averages node noise ~10x.
// Main GEMMs: 2-product split (exact-a x bf16(W)), 128x128, BK=32,
// single-buffer, gload16 staging, bank-spread swizzle sw(row)=(row&3)^((row>>2)&3),
// XCD-pair block swizzle. gemmB fuses BN+relu (+tanh) + bf16-act write +
// split-A staging in one kernel. Heads keep full 3-product.
// Ledger: dbuf +-0, bank-swz -12, sort/wide-tile reverted, BN-fusion -56,
// 2-product -17. Integer inputs arrive as int32.
// ---------------------------------------------------------------------------

typedef __attribute__((ext_vector_type(8))) short short8;   // 8 bf16 for MFMA
typedef __attribute__((ext_vector_type(4))) float f32x4;
typedef __attribute__((ext_vector_type(4))) unsigned short us4;
typedef __attribute__((ext_vector_type(8))) unsigned short us8;

__device__ __forceinline__ unsigned short f2bf(float f) {
  unsigned int b = __float_as_uint(f);
  unsigned int r = 0x7FFFu + ((b >> 16) & 1u);   // round-to-nearest-even
  return (unsigned short)((b + r) >> 16);
}
__device__ __forceinline__ float bf2f(unsigned short u) {
  return __uint_as_float(((unsigned int)u) << 16);
}

// bank-spread row swizzle value (4-group domain)
__device__ __forceinline__ int swv(int row) {
  return (row & 3) ^ ((row >> 2) & 3);
}

// global->LDS 16B async copy; LDS dest is wave-uniform base (HW adds lane*16)
typedef const __attribute__((address_space(1))) unsigned int* gas1;
typedef __attribute__((address_space(3))) unsigned int* las3;
__device__ __forceinline__ void gload16(const void* g, void* l) {
  __builtin_amdgcn_global_load_lds((gas1)g, (las3)l, 16, 0, 0);
}

// swizzled flat index of element (row, k), row length K:
// 16B groups (8 us) XORed within each 32-elem block: g' = g ^ swv(row)
__device__ __forceinline__ size_t swz4_idx(int row, int k, int K) {
  int g = k >> 3;
  return (size_t)row * K + ((g >> 2) << 5) + ((((g & 3) ^ swv(row)) << 3)) + (k & 7);
}

// ---------------- CSR build + graph bounds (fused) ----------------
__global__ void k_histbounds(const int* __restrict__ ei, int* __restrict__ deg, int E,
                             int eb, const int* __restrict__ batch,
                             int* __restrict__ gs, int* __restrict__ ge, int N) {
  int b = blockIdx.x;
  if (b < eb) {
    int e = b * 256 + threadIdx.x;
    if (e < E) atomicAdd(&deg[ei[E + e]], 1);
  } else {
    int i = (b - eb) * 256 + threadIdx.x;
    if (i < N) {
      int bb = batch[i];
      if (i == 0 || batch[i - 1] != bb) gs[bb] = i;
      if (i == N - 1 || batch[i + 1] != bb) ge[bb] = i + 1;
    }
  }
}

// phase 1: per-block (1024 elems) inclusive scan + block sum
__global__ __launch_bounds__(1024) void k_scan1(const int* __restrict__ deg,
                                                int* __restrict__ partial,
                                                int* __restrict__ bsum, int N) {
  __shared__ int sd[1024];
  int tid = threadIdx.x;
  int i = blockIdx.x * 1024 + tid;
  int v = (i < N) ? deg[i] : 0;
  sd[tid] = v;
  __syncthreads();
  for (int off = 1; off < 1024; off <<= 1) {
    int t = (tid >= off) ? sd[tid - off] : 0;
    __syncthreads();
    sd[tid] += t;
    __syncthreads();
  }
  if (i < N) partial[i] = sd[tid];
  if (tid == 1023) bsum[blockIdx.x] = sd[1023];
}

// phase 2: exclusive scan of <=64 block sums in one wave
__global__ void k_scan2(int* __restrict__ bsum, int nb) {
  int l = threadIdx.x;
  int orig = (l < nb) ? bsum[l] : 0;
  int v = orig;
  for (int off = 1; off < 64; off <<= 1) {
    int t = __shfl_up(v, off);
    if (l >= off) v += t;
  }
  if (l < nb) bsum[l] = v - orig;
}

// phase 3: rowptr / cursor
__global__ void k_scan3(const int* __restrict__ deg, const int* __restrict__ partial,
                        const int* __restrict__ bsum, int* __restrict__ rowptr,
                        int* __restrict__ cursor, int N) {
  int i = blockIdx.x * 256 + threadIdx.x;
  if (i >= N) return;
  int incl = partial[i] + bsum[i >> 10];
  rowptr[i + 1] = incl;
  cursor[i] = incl - deg[i];
  if (i == 0) rowptr[0] = 0;
}

__global__ void k_fill(const int* __restrict__ ei, int* __restrict__ cursor,
                       int* __restrict__ adj, int E) {
  int e = blockIdx.x * 256 + threadIdx.x;
  if (e >= E) return;
  int s = ei[e];
  int d = ei[E + e];
  int pos = atomicAdd(&cursor[d], 1);
  adj[pos] = s;
}

// ---- x f32 -> bf16 (one-time; feeds layer-1 gather) ----
__global__ void k_xbf(const float* __restrict__ X, unsigned short* __restrict__ Xb,
                      int total) {
  int t = blockIdx.x * 256 + threadIdx.x;   // one 8-elem group
  if (t * 8 >= total) return;
  const float4 v0 = *(const float4*)(X + t * 8);
  const float4 v1 = *(const float4*)(X + t * 8 + 4);
  us8 o;
  o[0] = f2bf(v0.x); o[1] = f2bf(v0.y); o[2] = f2bf(v0.z); o[3] = f2bf(v0.w);
  o[4] = f2bf(v1.x); o[5] = f2bf(v1.y); o[6] = f2bf(v1.z); o[7] = f2bf(v1.w);
  *(us8*)(Xb + t * 8) = o;
}

// ---- ALL weights: transpose + split + swizzle in ONE kernel ----
__global__ void k_prep_all(const float* __restrict__ w1a, const float* __restrict__ w1b,
                           const float* __restrict__ w2a, const float* __restrict__ w2b,
                           const float* __restrict__ w3a, const float* __restrict__ w3b,
                           const float* __restrict__ wh1, const float* __restrict__ wh2,
                           unsigned short* __restrict__ Hi, unsigned short* __restrict__ Lo) {
  int idx = blockIdx.x * 256 + threadIdx.x;   // [0, 884736)
  const float* W; int K, Nout, lo_;
  if (idx < 32768)       { W = w1a; K = 128; Nout = 256; lo_ = 0; }
  else if (idx < 98304)  { W = w1b; K = 256; Nout = 256; lo_ = 32768; }
  else if (idx < 163840) { W = w2a; K = 256; Nout = 256; lo_ = 98304; }
  else if (idx < 229376) { W = w2b; K = 256; Nout = 256; lo_ = 163840; }
  else if (idx < 294912) { W = w3a; K = 256; Nout = 256; lo_ = 229376; }
  else if (idx < 360448) { W = w3b; K = 256; Nout = 256; lo_ = 294912; }
  else if (idx < 491520) { W = wh1; K = 256; Nout = 512; lo_ = 360448; }
  else                   { W = wh2; K = 512; Nout = 768; lo_ = 491520; }
  int li = idx - lo_;
  int n = li % Nout, k = li / Nout;
  float w = W[k * Nout + n];
  unsigned short h = f2bf(w);
  size_t oi = (size_t)lo_ + swz4_idx(n, k, K);
  Hi[oi] = h;
  Lo[oi] = f2bf(w - bf2f(h));   // only heads read Lo
}

// -------- aggregation: h = Xb[i] + sum Xb[adj[e]] (bf16 gather, f32 acc) ----
// Writes split+swizzled h. Block 0 zeroes stats[] for the following gemmA.
template <int C>
__global__ __launch_bounds__(256) void k_agg(const unsigned short* __restrict__ Xb,
                                             unsigned short* __restrict__ HHi,
                                             unsigned short* __restrict__ HLo,
                                             const int* __restrict__ rowptr,
                                             const int* __restrict__ adj, int N,
                                             float* __restrict__ statsZ) {
  if (blockIdx.x == 0) {
    statsZ[threadIdx.x] = 0.f;
    statsZ[256 + threadIdx.x] = 0.f;
  }
  int node = blockIdx.x * 4 + (threadIdx.x >> 6);
  if (node >= N) return;
  int lane = threadIdx.x & 63;
  int e0 = rowptr[node], e1 = rowptr[node + 1];
  if constexpr (C == 256) {
    us4 ov = *(const us4*)(Xb + (size_t)node * C + lane * 4);
    float a0 = bf2f(ov[0]), a1 = bf2f(ov[1]), a2 = bf2f(ov[2]), a3 = bf2f(ov[3]);
    int e = e0;
    for (; e + 4 <= e1; e += 4) {
      int s0 = adj[e], s1 = adj[e + 1], s2 = adj[e + 2], s3 = adj[e + 3];
      us4 v0 = *(const us4*)(Xb + (size_t)s0 * C + lane * 4);
      us4 v1 = *(const us4*)(Xb + (size_t)s1 * C + lane * 4);
      us4 v2 = *(const us4*)(Xb + (size_t)s2 * C + lane * 4);
      us4 v3 = *(const us4*)(Xb + (size_t)s3 * C + lane * 4);
      a0 += (bf2f(v0[0]) + bf2f(v1[0])) + (bf2f(v2[0]) + bf2f(v3[0]));
      a1 += (bf2f(v0[1]) + bf2f(v1[1])) + (bf2f(v2[1]) + bf2f(v3[1]));
      a2 += (bf2f(v0[2]) + bf2f(v1[2])) + (bf2f(v2[2]) + bf2f(v3[2]));
      a3 += (bf2f(v0[3]) + bf2f(v1[3])) + (bf2f(v2[3]) + bf2f(v3[3]));
    }
    for (; e < e1; ++e) {
      us4 v = *(const us4*)(Xb + (size_t)adj[e] * C + lane * 4);
      a0 += bf2f(v[0]); a1 += bf2f(v[1]); a2 += bf2f(v[2]); a3 += bf2f(v[3]);
    }
    float vv[4] = {a0, a1, a2, a3};
    us4 hv, lv;
#pragma unroll
    for (int j = 0; j < 4; ++j) {
      unsigned short h = f2bf(vv[j]);
      hv[j] = h;
      lv[j] = f2bf(vv[j] - bf2f(h));
    }
    size_t oi = (size_t)node * 256 + ((lane >> 3) << 5) +
                ((((lane >> 1) & 3) ^ swv(node)) << 3) + ((lane & 1) << 2);
    *(us4*)(HHi + oi) = hv;
    *(us4*)(HLo + oi) = lv;
  } else {  // C == 128
    ushort2 ov = *(const ushort2*)(Xb + (size_t)node * C + lane * 2);
    float a0 = bf2f(ov.x), a1 = bf2f(ov.y);
    int e = e0;
    for (; e + 4 <= e1; e += 4) {
      int s0 = adj[e], s1 = adj[e + 1], s2 = adj[e + 2], s3 = adj[e + 3];
      ushort2 v0 = *(const ushort2*)(Xb + (size_t)s0 * C + lane * 2);
      ushort2 v1 = *(const ushort2*)(Xb + (size_t)s1 * C + lane * 2);
      ushort2 v2 = *(const ushort2*)(Xb + (size_t)s2 * C + lane * 2);
      ushort2 v3 = *(const ushort2*)(Xb + (size_t)s3 * C + lane * 2);
      a0 += (bf2f(v0.x) + bf2f(v1.x)) + (bf2f(v2.x) + bf2f(v3.x));
      a1 += (bf2f(v0.y) + bf2f(v1.y)) + (bf2f(v2.y) + bf2f(v3.y));
    }
    for (; e < e1; ++e) {
      ushort2 v = *(const ushort2*)(Xb + (size_t)adj[e] * C + lane * 2);
      a0 += bf2f(v.x); a1 += bf2f(v.y);
    }
    unsigned short hx = f2bf(a0), hy = f2bf(a1);
    ushort2 hv = {hx, hy};
    ushort2 lv = {f2bf(a0 - bf2f(hx)), f2bf(a1 - bf2f(hy))};
    size_t oi = (size_t)node * 128 + ((lane >> 4) << 5) +
                ((((lane >> 2) & 3) ^ swv(node)) << 3) + ((lane & 3) << 1);
    *(ushort2*)(HHi + oi) = hv;
    *(ushort2*)(HLo + oi) = lv;
  }
}

// ------------ MFMA GEMM: single-buffer BK=32, 128x128 tile -------------
// FULL=false: 2-product (exact-a x bf16(W)), wLo not staged, LDS 24KB.
// FULL=true (heads): 3-product. ASRC: 0 presplit gload16; 2 f32 z reg-staged
// with BN+relu+split (gemmB). EPI: 0 none, 1 relu, 2 tanh, 3 relu(tanh).
// OBF16: write activation as bf16 (gemmB). OSPLIT: write split+swizzled
// (head1, with relu). STATS: fused BN sum/sumsq. XSWZ: XCD-pair swizzle.
template <int EPI, bool STATS, bool OSPLIT, bool XSWZ, int ASRC, bool FULL, bool OBF16>
__global__ __launch_bounds__(256) void k_gemm(
    const unsigned short* __restrict__ AHi, const unsigned short* __restrict__ ALo,
    const float* __restrict__ Zf,
    int M, int K, int Nld, int mb, int per,
    const unsigned short* __restrict__ WHi, const unsigned short* __restrict__ WLo,
    const float* __restrict__ bias,
    const float* __restrict__ statsIn, const float* __restrict__ gvec,
    const float* __restrict__ bevec,
    float* __restrict__ Out, unsigned short* __restrict__ OutB,
    unsigned short* __restrict__ OHi, unsigned short* __restrict__ OLo,
    float* __restrict__ statsOut) {
  __shared__ unsigned short aHi[4096], aLo[4096], bHi[4096];
  __shared__ unsigned short bLo[FULL ? 4096 : 64];
  __shared__ float sBNsc[ASRC == 2 ? 256 : 1], sBNsh[ASRC == 2 ? 256 : 1];
  int bx, by;
  if constexpr (XSWZ) {
    int xcd = blockIdx.x & 7, slot = blockIdx.x >> 3;
    bx = xcd * per + (slot >> 1);
    by = slot & 1;
    if (bx >= mb) return;
  } else {
    bx = blockIdx.x;
    by = blockIdx.y;
  }
  const int tid = threadIdx.x;
  const int lane = tid & 63, w = tid >> 6;
  const int wm = w >> 1, wn = w & 1;
  const int m0 = bx * 128, n0 = by * 128;

  if constexpr (ASRC == 2) {
    // per-column scale/shift, exact op order of old k_finalize
    float mu = statsIn[tid] / (float)M;
    float var = statsIn[256 + tid] / (float)M - mu * mu;
    float sc = gvec[tid] * rsqrtf(var + 1e-5f);
    sBNsc[tid] = sc;
    sBNsh[tid] = bevec[tid] - mu * sc;
  }

  f32x4 zero = {0.f, 0.f, 0.f, 0.f};
  f32x4 acc[4][4];
#pragma unroll
  for (int i = 0; i < 4; ++i)
#pragma unroll
    for (int j = 0; j < 4; ++j) acc[i][j] = zero;

  const int rq = lane >> 2;
  const int k8s = lane & 3;

  for (int kb = 0; kb < K; kb += 32) {
    __syncthreads();
    if constexpr (ASRC == 2) {
      // A: reg-staged from f32 z, BN+relu+split, swizzled ds_write_b128
#pragma unroll
      for (int p = 0; p < 2; ++p) {
        int idx = tid + p * 256;
        int row = idx >> 2, gq = idx & 3;
        int ra = m0 + row; if (ra >= M) ra = M - 1;
        const float* zp = Zf + (size_t)ra * K + kb + gq * 8;
        float4 v0 = *(const float4*)zp;
        float4 v1 = *(const float4*)(zp + 4);
        float f[8] = {v0.x, v0.y, v0.z, v0.w, v1.x, v1.y, v1.z, v1.w};
        us8 hv, lv;
#pragma unroll
        for (int jj = 0; jj < 8; ++jj) {
          int kc = kb + gq * 8 + jj;
          float o = fmaxf(f[jj] * sBNsc[kc] + sBNsh[kc], 0.f);
          unsigned short h = f2bf(o);
          hv[jj] = h;
          lv[jj] = f2bf(o - bf2f(h));
        }
        int bo = row * 64 + ((gq ^ swv(row)) << 4);
        *(us8*)((char*)aHi + bo) = hv;
        *(us8*)((char*)aLo + bo) = lv;
      }
#pragma unroll
      for (int q = 0; q < 2; ++q) {
        int rloc = (w << 5) + (q << 4) + rq;
        size_t gb = (size_t)(n0 + rloc) * K + kb + k8s * 8;
        unsigned bo = (w << 11) + (q << 10);
        gload16(WHi + gb, (char*)bHi + bo);
        if constexpr (FULL) gload16(WLo + gb, (char*)bLo + bo);
      }
    } else {
#pragma unroll
      for (int q = 0; q < 2; ++q) {
        int rloc = (w << 5) + (q << 4) + rq;
        int ra = m0 + rloc; if (ra >= M) ra = M - 1;
        size_t ga = (size_t)ra * K + kb + k8s * 8;
        size_t gb = (size_t)(n0 + rloc) * K + kb + k8s * 8;
        unsigned bo = (w << 11) + (q << 10);
        gload16(AHi + ga, (char*)aHi + bo);
        gload16(ALo + ga, (char*)aLo + bo);
        gload16(WHi + gb, (char*)bHi + bo);
        if constexpr (FULL) gload16(WLo + gb, (char*)bLo + bo);
      }
    }
    __syncthreads();

    const int j = lane >> 4;
    short8 bh[4], bl[4];
#pragma unroll
    for (int ni = 0; ni < 4; ++ni) {
      int r = wn * 64 + ni * 16 + (lane & 15);
      int bo = r * 64 + ((j ^ swv(r)) << 4);
      bh[ni] = *(const short8*)((const char*)bHi + bo);
      if constexpr (FULL) bl[ni] = *(const short8*)((const char*)bLo + bo);
    }
#pragma unroll
    for (int mi = 0; mi < 4; ++mi) {
      int r = wm * 64 + mi * 16 + (lane & 15);
      int bo = r * 64 + ((j ^ swv(r)) << 4);
      short8 ah = *(const short8*)((const char*)aHi + bo);
      short8 al = *(const short8*)((const char*)aLo + bo);
#pragma unroll
      for (int ni = 0; ni < 4; ++ni) {
        acc[mi][ni] = __builtin_amdgcn_mfma_f32_16x16x32_bf16(ah, bh[ni], acc[mi][ni], 0, 0, 0);
        if constexpr (FULL)
          acc[mi][ni] = __builtin_amdgcn_mfma_f32_16x16x32_bf16(ah, bl[ni], acc[mi][ni], 0, 0, 0);
        acc[mi][ni] = __builtin_amdgcn_mfma_f32_16x16x32_bf16(al, bh[ni], acc[mi][ni], 0, 0, 0);
      }
    }
  }

  // epilogue: C/D layout col = lane&15, row = (lane>>4)*4 + r   [m89-verified]
#pragma unroll
  for (int ni = 0; ni < 4; ++ni) {
    int col = n0 + wn * 64 + ni * 16 + (lane & 15);
    float bc = bias[col];
    float s = 0.f, q = 0.f;
#pragma unroll
    for (int mi = 0; mi < 4; ++mi) {
      int rbase = m0 + wm * 64 + mi * 16 + (lane >> 4) * 4;
#pragma unroll
      for (int r = 0; r < 4; ++r) {
        int row = rbase + r;
        if (row < M) {
          float o = acc[mi][ni][r] + bc;
          if (STATS) { s += o; q += o * o; }
          if (OSPLIT) {
            o = fmaxf(o, 0.f);   // relu (head1)
            unsigned short h = f2bf(o);
            size_t oi = swz4_idx(row, col, Nld);
            OHi[oi] = h;
            OLo[oi] = f2bf(o - bf2f(h));
          } else {
            if (EPI == 1) o = fmaxf(o, 0.f);
            else if (EPI == 2) o = tanhf(o);
            else if (EPI == 3) o = fmaxf(tanhf(o), 0.f);
            if (OBF16) OutB[(size_t)row * Nld + col] = f2bf(o);
            else       Out[(size_t)row * Nld + col] = o;
          }
        }
      }
    }
    if (STATS) {
      s += __shfl_xor(s, 16); s += __shfl_xor(s, 32);
      q += __shfl_xor(q, 16); q += __shfl_xor(q, 32);
      if ((lane >> 4) == 0) {
        atomicAdd(&statsOut[col], s);
        atomicAdd(&statsOut[256 + col], q);
      }
    }
  }
}

// ---------------- pooling (bf16 input) ----------------
__global__ __launch_bounds__(256) void k_pool(const unsigned short* __restrict__ Hb,
                                              const int* __restrict__ gs,
                                              const int* __restrict__ ge,
                                              unsigned short* __restrict__ PHi,
                                              unsigned short* __restrict__ PLo) {
  __shared__ float4 red[4][64];
  int gi = blockIdx.x;
  int s = gs[gi], e = ge[gi];
  int w = threadIdx.x >> 6, lane = threadIdx.x & 63;
  float4 acc = {0.f, 0.f, 0.f, 0.f};
  for (int r = s + w; r < e; r += 4) {
    us4 v = *(const us4*)(Hb + (size_t)r * 256 + lane * 4);
    acc.x += bf2f(v[0]); acc.y += bf2f(v[1]);
    acc.z += bf2f(v[2]); acc.w += bf2f(v[3]);
  }
  red[w][lane] = acc;
  __syncthreads();
  if (w == 0) {
    float4 a = red[0][lane], b = red[1][lane], c = red[2][lane], d = red[3][lane];
    float inv = 1.0f / fmaxf((float)(e - s), 1.0f);
    float vv[4] = {(a.x + b.x + c.x + d.x) * inv, (a.y + b.y + c.y + d.y) * inv,
                   (a.z + b.z + c.z + d.z) * inv, (a.w + b.w + c.w + d.w) * inv};
    us4 hv, lv;
#pragma unroll
    for (int j = 0; j < 4; ++j) {
      unsigned short h = f2bf(vv[j]);
      hv[j] = h;
      lv[j] = f2bf(vv[j] - bf2f(h));
    }
    size_t oi = (size_t)gi * 256 + ((lane >> 3) << 5) +
                ((((lane >> 1) & 3) ^ swv(gi)) << 3) + ((lane & 1) << 2);
    *(us4*)(PHi + oi) = hv;
    *(us4*)(PLo + oi) = lv;
  }
}

// ---------------------------------------------------------------------------
extern "C" void kernel_launch(void* const* d_in, const int* in_sizes, int n_in,
                              void* d_out, int out_size, void* d_ws, size_t ws_size,
                              hipStream_t stream) {
  const float* x      = (const float*)d_in[0];
  const int* ei       = (const int*)d_in[1];    // int32 from harness
  const int* bat      = (const int*)d_in[2];    // int32 from harness
  const float* w1a = (const float*)d_in[3];  const float* b1a = (const float*)d_in[4];
  const float* g1  = (const float*)d_in[5];  const float* be1 = (const float*)d_in[6];
  const float* w1b = (const float*)d_in[7];  const float* b1b = (const float*)d_in[8];
  const float* w2a = (const float*)d_in[9];  const float* b2a = (const float*)d_in[10];
  const float* g2  = (const float*)d_in[11]; const float* be2 = (const float*)d_in[12];
  const float* w2b = (const float*)d_in[13]; const float* b2b = (const float*)d_in[14];
  const float* w3a = (const float*)d_in[15]; const float* b3a = (const float*)d_in[16];
  const float* g3  = (const float*)d_in[17]; const float* be3 = (const float*)d_in[18];
  const float* w3b = (const float*)d_in[19]; const float* b3b = (const float*)d_in[20];
  const float* wh1 = (const float*)d_in[21]; const float* bh1 = (const float*)d_in[22];
  const float* wh2 = (const float*)d_in[23]; const float* bh2 = (const float*)d_in[24];
  float* out = (float*)d_out;

  const int N = in_sizes[0] / 128;   // 50000
  const int E = in_sizes[1] / 2;     // 800000
  const int G = 512;

  // ---- workspace: 3 rotating 51.2MB regions + bf16 x ----
  char* ws = (char*)d_ws;
  size_t off = 0;
  auto alloc = [&](size_t bytes) {
    void* p = ws + off;
    off = (off + bytes + 255) & ~(size_t)255;
    return p;
  };
  char* reg0 = (char*)alloc((size_t)N * 256 * 4);
  char* reg1 = (char*)alloc((size_t)N * 256 * 4);
  char* reg2 = (char*)alloc((size_t)N * 256 * 4);
  unsigned short* xb = (unsigned short*)alloc((size_t)N * 128 * 2);
  int* adj     = (int*)alloc((size_t)E * 4);
  int* rowptr  = (int*)alloc((size_t)(N + 1) * 4);
  int* cursor  = (int*)alloc((size_t)N * 4);
  int* deg     = (int*)alloc((size_t)N * 4);
  int* partial = (int*)alloc((size_t)N * 4);
  int* bsum    = (int*)alloc(64 * 4);
  unsigned short* wHi = (unsigned short*)alloc(884736 * 2);
  unsigned short* wLo = (unsigned short*)alloc(884736 * 2);
  float* stats = (float*)alloc(512 * 4);
  int* gs      = (int*)alloc(G * 4);
  int* ge      = (int*)alloc(G * 4);
  unsigned short* poolHi = (unsigned short*)alloc((size_t)G * 256 * 2);
  unsigned short* poolLo = (unsigned short*)alloc((size_t)G * 256 * 2);
  unsigned short* thidHi = (unsigned short*)alloc((size_t)G * 512 * 2);
  unsigned short* thidLo = (unsigned short*)alloc((size_t)G * 512 * 2);

  // region views
  float* f0 = (float*)reg0; float* f1 = (float*)reg1; float* f2 = (float*)reg2;
  unsigned short* u0 = (unsigned short*)reg0;
  unsigned short* u1 = (unsigned short*)reg1;
  unsigned short* u2 = (unsigned short*)reg2;

  // transposed-weight element offsets (match k_prep_all segment table)
  const int o1a = 0, o1b = 32768, o2a = 98304, o2b = 163840, o3a = 229376, o3b = 294912;
  const int oh1 = 360448, oh2 = 491520;   // ends at 884736

  hipMemsetAsync(deg, 0, (size_t)N * 4, stream);
  hipMemsetAsync(gs, 0, (size_t)G * 4, stream);
  hipMemsetAsync(ge, 0, (size_t)G * 4, stream);

  int eb = (E + 255) / 256;
  int nbN = (N + 255) / 256;
  int nb1 = (N + 1023) >> 10;   // 49 (<=64 required by k_scan2)
  k_histbounds<<<eb + nbN, 256, 0, stream>>>(ei, deg, E, eb, bat, gs, ge, N);
  k_scan1<<<nb1, 1024, 0, stream>>>(deg, partial, bsum, N);
  k_scan2<<<1, 64, 0, stream>>>(bsum, nb1);
  k_scan3<<<nbN, 256, 0, stream>>>(deg, partial, bsum, rowptr, cursor, N);
  k_fill<<<eb, 256, 0, stream>>>(ei, cursor, adj, E);

  k_xbf<<<(N * 128 / 8 + 255) / 256, 256, 0, stream>>>(x, xb, N * 128);
  k_prep_all<<<3456, 256, 0, stream>>>(w1a, w1b, w2a, w2b, w3a, w3b, wh1, wh2, wHi, wLo);

  int nb4 = (N + 3) / 4;
  const int mb = (N + 127) / 128;        // 391
  const int per = (mb + 7) / 8;          // 49
  dim3 gg(per * 16);                     // XCD-pair swizzled flat grid

  // ---- layer 1: xb -> split@{reg0,reg1} -> z@reg2 -> actB@reg0 ----
  k_agg<128><<<nb4, 256, 0, stream>>>(xb, u0, u1, rowptr, adj, N, stats);
  k_gemm<0, true, false, true, 0, false, false><<<gg, 256, 0, stream>>>(
      u0, u1, nullptr, N, 128, 256, mb, per, wHi + o1a, wLo + o1a, b1a,
      nullptr, nullptr, nullptr, f2, nullptr, nullptr, nullptr, stats);
  k_gemm<1, false, false, true, 2, false, true><<<gg, 256, 0, stream>>>(
      nullptr, nullptr, f2, N, 256, 256, mb, per, wHi + o1b, wLo + o1b, b1b,
      stats, g1, be1, nullptr, u0, nullptr, nullptr, nullptr);

  // ---- layer 2: actB@u0 -> split@{reg1,reg2} -> z@reg0... wait z overwrites
  // actB@u0 only AFTER agg consumed it (serial stream) -> safe.
  k_agg<256><<<nb4, 256, 0, stream>>>(u0, u1, u2, rowptr, adj, N, stats);
  k_gemm<0, true, false, true, 0, false, false><<<gg, 256, 0, stream>>>(
      u1, u2, nullptr, N, 256, 256, mb, per, wHi + o2a, wLo + o2a, b2a,
      nullptr, nullptr, nullptr, f0, nullptr, nullptr, nullptr, stats);
  k_gemm<3, false, false, true, 2, false, true><<<gg, 256, 0, stream>>>(
      nullptr, nullptr, f0, N, 256, 256, mb, per, wHi + o2b, wLo + o2b, b2b,
      stats, g2, be2, nullptr, u1, nullptr, nullptr, nullptr);

  // ---- layer 3: actB@u1 -> split@{reg2,reg0} -> z@reg1 -> actB@u2 ----
  k_agg<256><<<nb4, 256, 0, stream>>>(u1, u2, u0, rowptr, adj, N, stats);
  k_gemm<0, true, false, true, 0, false, false><<<gg, 256, 0, stream>>>(
      u2, u0, nullptr, N, 256, 256, mb, per, wHi + o3a, wLo + o3a, b3a,
      nullptr, nullptr, nullptr, f1, nullptr, nullptr, nullptr, stats);
  k_gemm<2, false, false, true, 2, false, true><<<gg, 256, 0, stream>>>(
      nullptr, nullptr, f1, N, 256, 256, mb, per, wHi + o3b, wLo + o3b, b3b,
      stats, g3, be3, nullptr, u2, nullptr, nullptr, nullptr);

  // ---- pool + MFMA heads (heads keep FULL 3-product split) ----
  k_pool<<<G, 256, 0, stream>>>(u2, gs, ge, poolHi, poolLo);
  dim3 gh1(4, 4);   // M=512/128, N=512/128
  k_gemm<1, false, true, false, 0, true, false><<<gh1, 256, 0, stream>>>(
      poolHi, poolLo, nullptr, G, 256, 512, 0, 0, wHi + oh1, wLo + oh1, bh1,
      nullptr, nullptr, nullptr, nullptr, nullptr, thidHi, thidLo, nullptr);
  dim3 gh2(4, 6);   // M=512/128, N=768/128
  k_gemm<0, false, false, false, 0, true, false><<<gh2, 256, 0, stream>>>(
      thidHi, thidLo, nullptr, G, 512, 768, 0, 0, wHi + oh2, wLo + oh2, bh2,
      nullptr, nullptr, nullptr, out, nullptr, nullptr, nullptr, nullptr);
}

// Round 15
// 654.329 us; speedup vs baseline: 1.4275x; 1.0316x over previous
//
#include <hip/hip_runtime.h>

// ---------------------------------------------------------------------------
// GIN GraphEncoder on MI355X.
// R15: gemmB staging de-stalled -- (a) T14 async-STAGE: z f32 loads for tile
// k+1 issued AFTER the compute barrier (hidden under MFMA), consumed next
// stage phase; (b) truncation hi/lo split in BNP path (hi=bits>>16, lo=
// trunc(rem)) -- a=hi+lo exact to 2^-16 rel, ~35% less staging VALU.
// R14: bf16 gather (activations bf16; k_agg/k_pool 2B/elem).
// Main GEMMs: 2-product split (exact-a x bf16(W)), 128x128, BK=32,
// single-buffer, gload16 staging, bank-spread swizzle sw(row)=(row&3)^((row>>2)&3),
// XCD-pair block swizzle. gemmB fuses BN+relu(+tanh)+bf16-act write.
// Heads keep full 3-product. Integer inputs arrive as int32.
// Ledger: dbuf +-0, bank-swz -12, sort/wide-tile reverted, BN-fusion -56,
// 2-product -17, bf16-gather -120.
// ---------------------------------------------------------------------------

typedef __attribute__((ext_vector_type(8))) short short8;   // 8 bf16 for MFMA
typedef __attribute__((ext_vector_type(4))) float f32x4;
typedef __attribute__((ext_vector_type(4))) unsigned short us4;
typedef __attribute__((ext_vector_type(8))) unsigned short us8;

__device__ __forceinline__ unsigned short f2bf(float f) {
  unsigned int b = __float_as_uint(f);
  unsigned int r = 0x7FFFu + ((b >> 16) & 1u);   // round-to-nearest-even
  return (unsigned short)((b + r) >> 16);
}
__device__ __forceinline__ float bf2f(unsigned short u) {
  return __uint_as_float(((unsigned int)u) << 16);
}

// bank-spread row swizzle value (4-group domain)
__device__ __forceinline__ int swv(int row) {
  return (row & 3) ^ ((row >> 2) & 3);
}

// global->LDS 16B async copy; LDS dest is wave-uniform base (HW adds lane*16)
typedef const __attribute__((address_space(1))) unsigned int* gas1;
typedef __attribute__((address_space(3))) unsigned int* las3;
__device__ __forceinline__ void gload16(const void* g, void* l) {
  __builtin_amdgcn_global_load_lds((gas1)g, (las3)l, 16, 0, 0);
}

// swizzled flat index of element (row, k), row length K:
// 16B groups (8 us) XORed within each 32-elem block: g' = g ^ swv(row)
__device__ __forceinline__ size_t swz4_idx(int row, int k, int K) {
  int g = k >> 3;
  return (size_t)row * K + ((g >> 2) << 5) + ((((g & 3) ^ swv(row)) << 3)) + (k & 7);
}

// ---------------- CSR build + graph bounds (fused) ----------------
__global__ void k_histbounds(const int* __restrict__ ei, int* __restrict__ deg, int E,
                             int eb, const int* __restrict__ batch,
                             int* __restrict__ gs, int* __restrict__ ge, int N) {
  int b = blockIdx.x;
  if (b < eb) {
    int e = b * 256 + threadIdx.x;
    if (e < E) atomicAdd(&deg[ei[E + e]], 1);
  } else {
    int i = (b - eb) * 256 + threadIdx.x;
    if (i < N) {
      int bb = batch[i];
      if (i == 0 || batch[i - 1] != bb) gs[bb] = i;
      if (i == N - 1 || batch[i + 1] != bb) ge[bb] = i + 1;
    }
  }
}

// phase 1: per-block (1024 elems) inclusive scan + block sum
__global__ __launch_bounds__(1024) void k_scan1(const int* __restrict__ deg,
                                                int* __restrict__ partial,
                                                int* __restrict__ bsum, int N) {
  __shared__ int sd[1024];
  int tid = threadIdx.x;
  int i = blockIdx.x * 1024 + tid;
  int v = (i < N) ? deg[i] : 0;
  sd[tid] = v;
  __syncthreads();
  for (int off = 1; off < 1024; off <<= 1) {
    int t = (tid >= off) ? sd[tid - off] : 0;
    __syncthreads();
    sd[tid] += t;
    __syncthreads();
  }
  if (i < N) partial[i] = sd[tid];
  if (tid == 1023) bsum[blockIdx.x] = sd[1023];
}

// phase 2: exclusive scan of <=64 block sums in one wave
__global__ void k_scan2(int* __restrict__ bsum, int nb) {
  int l = threadIdx.x;
  int orig = (l < nb) ? bsum[l] : 0;
  int v = orig;
  for (int off = 1; off < 64; off <<= 1) {
    int t = __shfl_up(v, off);
    if (l >= off) v += t;
  }
  if (l < nb) bsum[l] = v - orig;
}

// phase 3: rowptr / cursor
__global__ void k_scan3(const int* __restrict__ deg, const int* __restrict__ partial,
                        const int* __restrict__ bsum, int* __restrict__ rowptr,
                        int* __restrict__ cursor, int N) {
  int i = blockIdx.x * 256 + threadIdx.x;
  if (i >= N) return;
  int incl = partial[i] + bsum[i >> 10];
  rowptr[i + 1] = incl;
  cursor[i] = incl - deg[i];
  if (i == 0) rowptr[0] = 0;
}

__global__ void k_fill(const int* __restrict__ ei, int* __restrict__ cursor,
                       int* __restrict__ adj, int E) {
  int e = blockIdx.x * 256 + threadIdx.x;
  if (e >= E) return;
  int s = ei[e];
  int d = ei[E + e];
  int pos = atomicAdd(&cursor[d], 1);
  adj[pos] = s;
}

// ---- x f32 -> bf16 (one-time; feeds layer-1 gather) ----
__global__ void k_xbf(const float* __restrict__ X, unsigned short* __restrict__ Xb,
                      int total) {
  int t = blockIdx.x * 256 + threadIdx.x;   // one 8-elem group
  if (t * 8 >= total) return;
  const float4 v0 = *(const float4*)(X + t * 8);
  const float4 v1 = *(const float4*)(X + t * 8 + 4);
  us8 o;
  o[0] = f2bf(v0.x); o[1] = f2bf(v0.y); o[2] = f2bf(v0.z); o[3] = f2bf(v0.w);
  o[4] = f2bf(v1.x); o[5] = f2bf(v1.y); o[6] = f2bf(v1.z); o[7] = f2bf(v1.w);
  *(us8*)(Xb + t * 8) = o;
}

// ---- ALL weights: transpose + split + swizzle in ONE kernel ----
__global__ void k_prep_all(const float* __restrict__ w1a, const float* __restrict__ w1b,
                           const float* __restrict__ w2a, const float* __restrict__ w2b,
                           const float* __restrict__ w3a, const float* __restrict__ w3b,
                           const float* __restrict__ wh1, const float* __restrict__ wh2,
                           unsigned short* __restrict__ Hi, unsigned short* __restrict__ Lo) {
  int idx = blockIdx.x * 256 + threadIdx.x;   // [0, 884736)
  const float* W; int K, Nout, lo_;
  if (idx < 32768)       { W = w1a; K = 128; Nout = 256; lo_ = 0; }
  else if (idx < 98304)  { W = w1b; K = 256; Nout = 256; lo_ = 32768; }
  else if (idx < 163840) { W = w2a; K = 256; Nout = 256; lo_ = 98304; }
  else if (idx < 229376) { W = w2b; K = 256; Nout = 256; lo_ = 163840; }
  else if (idx < 294912) { W = w3a; K = 256; Nout = 256; lo_ = 229376; }
  else if (idx < 360448) { W = w3b; K = 256; Nout = 256; lo_ = 294912; }
  else if (idx < 491520) { W = wh1; K = 256; Nout = 512; lo_ = 360448; }
  else                   { W = wh2; K = 512; Nout = 768; lo_ = 491520; }
  int li = idx - lo_;
  int n = li % Nout, k = li / Nout;
  float w = W[k * Nout + n];
  unsigned short h = f2bf(w);
  size_t oi = (size_t)lo_ + swz4_idx(n, k, K);
  Hi[oi] = h;
  Lo[oi] = f2bf(w - bf2f(h));   // only heads read Lo
}

// -------- aggregation: h = Xb[i] + sum Xb[adj[e]] (bf16 gather, f32 acc) ----
// Writes split+swizzled h. Block 0 zeroes stats[] for the following gemmA.
template <int C>
__global__ __launch_bounds__(256) void k_agg(const unsigned short* __restrict__ Xb,
                                             unsigned short* __restrict__ HHi,
                                             unsigned short* __restrict__ HLo,
                                             const int* __restrict__ rowptr,
                                             const int* __restrict__ adj, int N,
                                             float* __restrict__ statsZ) {
  if (blockIdx.x == 0) {
    statsZ[threadIdx.x] = 0.f;
    statsZ[256 + threadIdx.x] = 0.f;
  }
  int node = blockIdx.x * 4 + (threadIdx.x >> 6);
  if (node >= N) return;
  int lane = threadIdx.x & 63;
  int e0 = rowptr[node], e1 = rowptr[node + 1];
  if constexpr (C == 256) {
    us4 ov = *(const us4*)(Xb + (size_t)node * C + lane * 4);
    float a0 = bf2f(ov[0]), a1 = bf2f(ov[1]), a2 = bf2f(ov[2]), a3 = bf2f(ov[3]);
    int e = e0;
    for (; e + 4 <= e1; e += 4) {
      int s0 = adj[e], s1 = adj[e + 1], s2 = adj[e + 2], s3 = adj[e + 3];
      us4 v0 = *(const us4*)(Xb + (size_t)s0 * C + lane * 4);
      us4 v1 = *(const us4*)(Xb + (size_t)s1 * C + lane * 4);
      us4 v2 = *(const us4*)(Xb + (size_t)s2 * C + lane * 4);
      us4 v3 = *(const us4*)(Xb + (size_t)s3 * C + lane * 4);
      a0 += (bf2f(v0[0]) + bf2f(v1[0])) + (bf2f(v2[0]) + bf2f(v3[0]));
      a1 += (bf2f(v0[1]) + bf2f(v1[1])) + (bf2f(v2[1]) + bf2f(v3[1]));
      a2 += (bf2f(v0[2]) + bf2f(v1[2])) + (bf2f(v2[2]) + bf2f(v3[2]));
      a3 += (bf2f(v0[3]) + bf2f(v1[3])) + (bf2f(v2[3]) + bf2f(v3[3]));
    }
    for (; e < e1; ++e) {
      us4 v = *(const us4*)(Xb + (size_t)adj[e] * C + lane * 4);
      a0 += bf2f(v[0]); a1 += bf2f(v[1]); a2 += bf2f(v[2]); a3 += bf2f(v[3]);
    }
    float vv[4] = {a0, a1, a2, a3};
    us4 hv, lv;
#pragma unroll
    for (int j = 0; j < 4; ++j) {
      unsigned short h = f2bf(vv[j]);
      hv[j] = h;
      lv[j] = f2bf(vv[j] - bf2f(h));
    }
    size_t oi = (size_t)node * 256 + ((lane >> 3) << 5) +
                ((((lane >> 1) & 3) ^ swv(node)) << 3) + ((lane & 1) << 2);
    *(us4*)(HHi + oi) = hv;
    *(us4*)(HLo + oi) = lv;
  } else {  // C == 128
    ushort2 ov = *(const ushort2*)(Xb + (size_t)node * C + lane * 2);
    float a0 = bf2f(ov.x), a1 = bf2f(ov.y);
    int e = e0;
    for (; e + 4 <= e1; e += 4) {
      int s0 = adj[e], s1 = adj[e + 1], s2 = adj[e + 2], s3 = adj[e + 3];
      ushort2 v0 = *(const ushort2*)(Xb + (size_t)s0 * C + lane * 2);
      ushort2 v1 = *(const ushort2*)(Xb + (size_t)s1 * C + lane * 2);
      ushort2 v2 = *(const ushort2*)(Xb + (size_t)s2 * C + lane * 2);
      ushort2 v3 = *(const ushort2*)(Xb + (size_t)s3 * C + lane * 2);
      a0 += (bf2f(v0.x) + bf2f(v1.x)) + (bf2f(v2.x) + bf2f(v3.x));
      a1 += (bf2f(v0.y) + bf2f(v1.y)) + (bf2f(v2.y) + bf2f(v3.y));
    }
    for (; e < e1; ++e) {
      ushort2 v = *(const ushort2*)(Xb + (size_t)adj[e] * C + lane * 2);
      a0 += bf2f(v.x); a1 += bf2f(v.y);
    }
    unsigned short hx = f2bf(a0), hy = f2bf(a1);
    ushort2 hv = {hx, hy};
    ushort2 lv = {f2bf(a0 - bf2f(hx)), f2bf(a1 - bf2f(hy))};
    size_t oi = (size_t)node * 128 + ((lane >> 4) << 5) +
                ((((lane >> 2) & 3) ^ swv(node)) << 3) + ((lane & 3) << 1);
    *(ushort2*)(HHi + oi) = hv;
    *(ushort2*)(HLo + oi) = lv;
  }
}

// ------------ MFMA GEMM: single-buffer BK=32, 128x128 tile -------------
// FULL=false: 2-product (exact-a x bf16(W)), wLo not staged, LDS 24KB.
// FULL=true (heads): 3-product. ASRC: 0 presplit gload16; 2 f32 z reg-staged
// with BN+relu+TRUNC-split, z loads for k+1 prefetched under MFMA (T14).
// EPI: 0 none, 1 relu, 2 tanh, 3 relu(tanh). OBF16: bf16 act write (gemmB).
// OSPLIT: split+swizzled out (head1, relu). STATS: fused BN sum/sumsq.
// XSWZ: XCD-pair swizzle.
template <int EPI, bool STATS, bool OSPLIT, bool XSWZ, int ASRC, bool FULL, bool OBF16>
__global__ __launch_bounds__(256) void k_gemm(
    const unsigned short* __restrict__ AHi, const unsigned short* __restrict__ ALo,
    const float* __restrict__ Zf,
    int M, int K, int Nld, int mb, int per,
    const unsigned short* __restrict__ WHi, const unsigned short* __restrict__ WLo,
    const float* __restrict__ bias,
    const float* __restrict__ statsIn, const float* __restrict__ gvec,
    const float* __restrict__ bevec,
    float* __restrict__ Out, unsigned short* __restrict__ OutB,
    unsigned short* __restrict__ OHi, unsigned short* __restrict__ OLo,
    float* __restrict__ statsOut) {
  __shared__ unsigned short aHi[4096], aLo[4096], bHi[4096];
  __shared__ unsigned short bLo[FULL ? 4096 : 64];
  __shared__ float sBNsc[ASRC == 2 ? 256 : 1], sBNsh[ASRC == 2 ? 256 : 1];
  int bx, by;
  if constexpr (XSWZ) {
    int xcd = blockIdx.x & 7, slot = blockIdx.x >> 3;
    bx = xcd * per + (slot >> 1);
    by = slot & 1;
    if (bx >= mb) return;
  } else {
    bx = blockIdx.x;
    by = blockIdx.y;
  }
  const int tid = threadIdx.x;
  const int lane = tid & 63, w = tid >> 6;
  const int wm = w >> 1, wn = w & 1;
  const int m0 = bx * 128, n0 = by * 128;

  if constexpr (ASRC == 2) {
    // per-column scale/shift, exact op order of old k_finalize
    float mu = statsIn[tid] / (float)M;
    float var = statsIn[256 + tid] / (float)M - mu * mu;
    float sc = gvec[tid] * rsqrtf(var + 1e-5f);
    sBNsc[tid] = sc;
    sBNsh[tid] = bevec[tid] - mu * sc;
  }

  f32x4 zero = {0.f, 0.f, 0.f, 0.f};
  f32x4 acc[4][4];
#pragma unroll
  for (int i = 0; i < 4; ++i)
#pragma unroll
    for (int j = 0; j < 4; ++j) acc[i][j] = zero;

  const int rq = lane >> 2;
  const int k8s = lane & 3;

  // T14 prefetch regs for ASRC==2 (z rows; addresses fixed except kb)
  float4 zr0, zr1, zr2, zr3;
  const float* zbase0 = nullptr;
  const float* zbase1 = nullptr;
  if constexpr (ASRC == 2) {
    int row0 = tid >> 2, gq0 = tid & 3;
    int ra0 = m0 + row0; if (ra0 >= M) ra0 = M - 1;
    zbase0 = Zf + (size_t)ra0 * K + gq0 * 8;
    int idx1 = tid + 256;
    int row1 = idx1 >> 2, gq1 = idx1 & 3;
    int ra1 = m0 + row1; if (ra1 >= M) ra1 = M - 1;
    zbase1 = Zf + (size_t)ra1 * K + gq1 * 8;
    zr0 = *(const float4*)(zbase0);
    zr1 = *(const float4*)(zbase0 + 4);
    zr2 = *(const float4*)(zbase1);
    zr3 = *(const float4*)(zbase1 + 4);
  }

  for (int kb = 0; kb < K; kb += 32) {
    __syncthreads();
    if constexpr (ASRC == 2) {
      // consume prefetched z regs: BN+relu+TRUNC-split -> swizzled ds_write
#pragma unroll
      for (int p = 0; p < 2; ++p) {
        int idx = tid + p * 256;
        int row = idx >> 2, gq = idx & 3;
        float f[8];
        if (p == 0) {
          f[0] = zr0.x; f[1] = zr0.y; f[2] = zr0.z; f[3] = zr0.w;
          f[4] = zr1.x; f[5] = zr1.y; f[6] = zr1.z; f[7] = zr1.w;
        } else {
          f[0] = zr2.x; f[1] = zr2.y; f[2] = zr2.z; f[3] = zr2.w;
          f[4] = zr3.x; f[5] = zr3.y; f[6] = zr3.z; f[7] = zr3.w;
        }
        us8 hv, lv;
#pragma unroll
        for (int jj = 0; jj < 8; ++jj) {
          int kc = kb + gq * 8 + jj;
          float o = fmaxf(f[jj] * sBNsc[kc] + sBNsh[kc], 0.f);
          unsigned short h = (unsigned short)(__float_as_uint(o) >> 16);  // trunc
          hv[jj] = h;
          float rem = o - bf2f(h);
          lv[jj] = (unsigned short)(__float_as_uint(rem) >> 16);          // trunc
        }
        int bo = row * 64 + ((gq ^ swv(row)) << 4);
        *(us8*)((char*)aHi + bo) = hv;
        *(us8*)((char*)aLo + bo) = lv;
      }
#pragma unroll
      for (int q = 0; q < 2; ++q) {
        int rloc = (w << 5) + (q << 4) + rq;
        size_t gb = (size_t)(n0 + rloc) * K + kb + k8s * 8;
        unsigned bo = (w << 11) + (q << 10);
        gload16(WHi + gb, (char*)bHi + bo);
        if constexpr (FULL) gload16(WLo + gb, (char*)bLo + bo);
      }
    } else {
#pragma unroll
      for (int q = 0; q < 2; ++q) {
        int rloc = (w << 5) + (q << 4) + rq;
        int ra = m0 + rloc; if (ra >= M) ra = M - 1;
        size_t ga = (size_t)ra * K + kb + k8s * 8;
        size_t gb = (size_t)(n0 + rloc) * K + kb + k8s * 8;
        unsigned bo = (w << 11) + (q << 10);
        gload16(AHi + ga, (char*)aHi + bo);
        gload16(ALo + ga, (char*)aLo + bo);
        gload16(WHi + gb, (char*)bHi + bo);
        if constexpr (FULL) gload16(WLo + gb, (char*)bLo + bo);
      }
    }
    __syncthreads();

    // T14: issue next tile's z loads here -- they complete under the MFMAs
    if constexpr (ASRC == 2) {
      if (kb + 32 < K) {
        zr0 = *(const float4*)(zbase0 + kb + 32);
        zr1 = *(const float4*)(zbase0 + kb + 36);
        zr2 = *(const float4*)(zbase1 + kb + 32);
        zr3 = *(const float4*)(zbase1 + kb + 36);
      }
    }

    const int j = lane >> 4;
    short8 bh[4], bl[4];
#pragma unroll
    for (int ni = 0; ni < 4; ++ni) {
      int r = wn * 64 + ni * 16 + (lane & 15);
      int bo = r * 64 + ((j ^ swv(r)) << 4);
      bh[ni] = *(const short8*)((const char*)bHi + bo);
      if constexpr (FULL) bl[ni] = *(const short8*)((const char*)bLo + bo);
    }
#pragma unroll
    for (int mi = 0; mi < 4; ++mi) {
      int r = wm * 64 + mi * 16 + (lane & 15);
      int bo = r * 64 + ((j ^ swv(r)) << 4);
      short8 ah = *(const short8*)((const char*)aHi + bo);
      short8 al = *(const short8*)((const char*)aLo + bo);
#pragma unroll
      for (int ni = 0; ni < 4; ++ni) {
        acc[mi][ni] = __builtin_amdgcn_mfma_f32_16x16x32_bf16(ah, bh[ni], acc[mi][ni], 0, 0, 0);
        if constexpr (FULL)
          acc[mi][ni] = __builtin_amdgcn_mfma_f32_16x16x32_bf16(ah, bl[ni], acc[mi][ni], 0, 0, 0);
        acc[mi][ni] = __builtin_amdgcn_mfma_f32_16x16x32_bf16(al, bh[ni], acc[mi][ni], 0, 0, 0);
      }
    }
  }

  // epilogue: C/D layout col = lane&15, row = (lane>>4)*4 + r   [m89-verified]
#pragma unroll
  for (int ni = 0; ni < 4; ++ni) {
    int col = n0 + wn * 64 + ni * 16 + (lane & 15);
    float bc = bias[col];
    float s = 0.f, q = 0.f;
#pragma unroll
    for (int mi = 0; mi < 4; ++mi) {
      int rbase = m0 + wm * 64 + mi * 16 + (lane >> 4) * 4;
#pragma unroll
      for (int r = 0; r < 4; ++r) {
        int row = rbase + r;
        if (row < M) {
          float o = acc[mi][ni][r] + bc;
          if (STATS) { s += o; q += o * o; }
          if (OSPLIT) {
            o = fmaxf(o, 0.f);   // relu (head1)
            unsigned short h = f2bf(o);
            size_t oi = swz4_idx(row, col, Nld);
            OHi[oi] = h;
            OLo[oi] = f2bf(o - bf2f(h));
          } else {
            if (EPI == 1) o = fmaxf(o, 0.f);
            else if (EPI == 2) o = tanhf(o);
            else if (EPI == 3) o = fmaxf(tanhf(o), 0.f);
            if (OBF16) OutB[(size_t)row * Nld + col] = f2bf(o);
            else       Out[(size_t)row * Nld + col] = o;
          }
        }
      }
    }
    if (STATS) {
      s += __shfl_xor(s, 16); s += __shfl_xor(s, 32);
      q += __shfl_xor(q, 16); q += __shfl_xor(q, 32);
      if ((lane >> 4) == 0) {
        atomicAdd(&statsOut[col], s);
        atomicAdd(&statsOut[256 + col], q);
      }
    }
  }
}

// ---------------- pooling (bf16 input) ----------------
__global__ __launch_bounds__(256) void k_pool(const unsigned short* __restrict__ Hb,
                                              const int* __restrict__ gs,
                                              const int* __restrict__ ge,
                                              unsigned short* __restrict__ PHi,
                                              unsigned short* __restrict__ PLo) {
  __shared__ float4 red[4][64];
  int gi = blockIdx.x;
  int s = gs[gi], e = ge[gi];
  int w = threadIdx.x >> 6, lane = threadIdx.x & 63;
  float4 acc = {0.f, 0.f, 0.f, 0.f};
  for (int r = s + w; r < e; r += 4) {
    us4 v = *(const us4*)(Hb + (size_t)r * 256 + lane * 4);
    acc.x += bf2f(v[0]); acc.y += bf2f(v[1]);
    acc.z += bf2f(v[2]); acc.w += bf2f(v[3]);
  }
  red[w][lane] = acc;
  __syncthreads();
  if (w == 0) {
    float4 a = red[0][lane], b = red[1][lane], c = red[2][lane], d = red[3][lane];
    float inv = 1.0f / fmaxf((float)(e - s), 1.0f);
    float vv[4] = {(a.x + b.x + c.x + d.x) * inv, (a.y + b.y + c.y + d.y) * inv,
                   (a.z + b.z + c.z + d.z) * inv, (a.w + b.w + c.w + d.w) * inv};
    us4 hv, lv;
#pragma unroll
    for (int j = 0; j < 4; ++j) {
      unsigned short h = f2bf(vv[j]);
      hv[j] = h;
      lv[j] = f2bf(vv[j] - bf2f(h));
    }
    size_t oi = (size_t)gi * 256 + ((lane >> 3) << 5) +
                ((((lane >> 1) & 3) ^ swv(gi)) << 3) + ((lane & 1) << 2);
    *(us4*)(PHi + oi) = hv;
    *(us4*)(PLo + oi) = lv;
  }
}

// ---------------------------------------------------------------------------
extern "C" void kernel_launch(void* const* d_in, const int* in_sizes, int n_in,
                              void* d_out, int out_size, void* d_ws, size_t ws_size,
                              hipStream_t stream) {
  const float* x      = (const float*)d_in[0];
  const int* ei       = (const int*)d_in[1];    // int32 from harness
  const int* bat      = (const int*)d_in[2];    // int32 from harness
  const float* w1a = (const float*)d_in[3];  const float* b1a = (const float*)d_in[4];
  const float* g1  = (const float*)d_in[5];  const float* be1 = (const float*)d_in[6];
  const float* w1b = (const float*)d_in[7];  const float* b1b = (const float*)d_in[8];
  const float* w2a = (const float*)d_in[9];  const float* b2a = (const float*)d_in[10];
  const float* g2  = (const float*)d_in[11]; const float* be2 = (const float*)d_in[12];
  const float* w2b = (const float*)d_in[13]; const float* b2b = (const float*)d_in[14];
  const float* w3a = (const float*)d_in[15]; const float* b3a = (const float*)d_in[16];
  const float* g3  = (const float*)d_in[17]; const float* be3 = (const float*)d_in[18];
  const float* w3b = (const float*)d_in[19]; const float* b3b = (const float*)d_in[20];
  const float* wh1 = (const float*)d_in[21]; const float* bh1 = (const float*)d_in[22];
  const float* wh2 = (const float*)d_in[23]; const float* bh2 = (const float*)d_in[24];
  float* out = (float*)d_out;

  const int N = in_sizes[0] / 128;   // 50000
  const int E = in_sizes[1] / 2;     // 800000
  const int G = 512;

  // ---- workspace: 3 rotating 51.2MB regions + bf16 x ----
  char* ws = (char*)d_ws;
  size_t off = 0;
  auto alloc = [&](size_t bytes) {
    void* p = ws + off;
    off = (off + bytes + 255) & ~(size_t)255;
    return p;
  };
  char* reg0 = (char*)alloc((size_t)N * 256 * 4);
  char* reg1 = (char*)alloc((size_t)N * 256 * 4);
  char* reg2 = (char*)alloc((size_t)N * 256 * 4);
  unsigned short* xb = (unsigned short*)alloc((size_t)N * 128 * 2);
  int* adj     = (int*)alloc((size_t)E * 4);
  int* rowptr  = (int*)alloc((size_t)(N + 1) * 4);
  int* cursor  = (int*)alloc((size_t)N * 4);
  int* deg     = (int*)alloc((size_t)N * 4);
  int* partial = (int*)alloc((size_t)N * 4);
  int* bsum    = (int*)alloc(64 * 4);
  unsigned short* wHi = (unsigned short*)alloc(884736 * 2);
  unsigned short* wLo = (unsigned short*)alloc(884736 * 2);
  float* stats = (float*)alloc(512 * 4);
  int* gs      = (int*)alloc(G * 4);
  int* ge      = (int*)alloc(G * 4);
  unsigned short* poolHi = (unsigned short*)alloc((size_t)G * 256 * 2);
  unsigned short* poolLo = (unsigned short*)alloc((size_t)G * 256 * 2);
  unsigned short* thidHi = (unsigned short*)alloc((size_t)G * 512 * 2);
  unsigned short* thidLo = (unsigned short*)alloc((size_t)G * 512 * 2);

  // region views
  float* f0 = (float*)reg0; float* f1 = (float*)reg1; float* f2 = (float*)reg2;
  unsigned short* u0 = (unsigned short*)reg0;
  unsigned short* u1 = (unsigned short*)reg1;
  unsigned short* u2 = (unsigned short*)reg2;

  // transposed-weight element offsets (match k_prep_all segment table)
  const int o1a = 0, o1b = 32768, o2a = 98304, o2b = 163840, o3a = 229376, o3b = 294912;
  const int oh1 = 360448, oh2 = 491520;   // ends at 884736

  hipMemsetAsync(deg, 0, (size_t)N * 4, stream);
  hipMemsetAsync(gs, 0, (size_t)G * 4, stream);
  hipMemsetAsync(ge, 0, (size_t)G * 4, stream);

  int eb = (E + 255) / 256;
  int nbN = (N + 255) / 256;
  int nb1 = (N + 1023) >> 10;   // 49 (<=64 required by k_scan2)
  k_histbounds<<<eb + nbN, 256, 0, stream>>>(ei, deg, E, eb, bat, gs, ge, N);
  k_scan1<<<nb1, 1024, 0, stream>>>(deg, partial, bsum, N);
  k_scan2<<<1, 64, 0, stream>>>(bsum, nb1);
  k_scan3<<<nbN, 256, 0, stream>>>(deg, partial, bsum, rowptr, cursor, N);
  k_fill<<<eb, 256, 0, stream>>>(ei, cursor, adj, E);

  k_xbf<<<(N * 128 / 8 + 255) / 256, 256, 0, stream>>>(x, xb, N * 128);
  k_prep_all<<<3456, 256, 0, stream>>>(w1a, w1b, w2a, w2b, w3a, w3b, wh1, wh2, wHi, wLo);

  int nb4 = (N + 3) / 4;
  const int mb = (N + 127) / 128;        // 391
  const int per = (mb + 7) / 8;          // 49
  dim3 gg(per * 16);                     // XCD-pair swizzled flat grid

  // ---- layer 1: xb -> split@{reg0,reg1} -> z@reg2 -> actB@u0 ----
  k_agg<128><<<nb4, 256, 0, stream>>>(xb, u0, u1, rowptr, adj, N, stats);
  k_gemm<0, true, false, true, 0, false, false><<<gg, 256, 0, stream>>>(
      u0, u1, nullptr, N, 128, 256, mb, per, wHi + o1a, wLo + o1a, b1a,
      nullptr, nullptr, nullptr, f2, nullptr, nullptr, nullptr, stats);
  k_gemm<1, false, false, true, 2, false, true><<<gg, 256, 0, stream>>>(
      nullptr, nullptr, f2, N, 256, 256, mb, per, wHi + o1b, wLo + o1b, b1b,
      stats, g1, be1, nullptr, u0, nullptr, nullptr, nullptr);

  // ---- layer 2: actB@u0 -> split@{reg1,reg2} -> z@reg0 -> actB@u1 ----
  k_agg<256><<<nb4, 256, 0, stream>>>(u0, u1, u2, rowptr, adj, N, stats);
  k_gemm<0, true, false, true, 0, false, false><<<gg, 256, 0, stream>>>(
      u1, u2, nullptr, N, 256, 256, mb, per, wHi + o2a, wLo + o2a, b2a,
      nullptr, nullptr, nullptr, f0, nullptr, nullptr, nullptr, stats);
  k_gemm<3, false, false, true, 2, false, true><<<gg, 256, 0, stream>>>(
      nullptr, nullptr, f0, N, 256, 256, mb, per, wHi + o2b, wLo + o2b, b2b,
      stats, g2, be2, nullptr, u1, nullptr, nullptr, nullptr);

  // ---- layer 3: actB@u1 -> split@{reg2,reg0} -> z@reg1 -> actB@u2 ----
  k_agg<256><<<nb4, 256, 0, stream>>>(u1, u2, u0, rowptr, adj, N, stats);
  k_gemm<0, true, false, true, 0, false, false><<<gg, 256, 0, stream>>>(
      u2, u0, nullptr, N, 256, 256, mb, per, wHi + o3a, wLo + o3a, b3a,
      nullptr, nullptr, nullptr, f1, nullptr, nullptr, nullptr, stats);
  k_gemm<2, false, false, true, 2, false, true><<<gg, 256, 0, stream>>>(
      nullptr, nullptr, f1, N, 256, 256, mb, per, wHi + o3b, wLo + o3b, b3b,
      stats, g3, be3, nullptr, u2, nullptr, nullptr, nullptr);

  // ---- pool + MFMA heads (heads keep FULL 3-product split) ----
  k_pool<<<G, 256, 0, stream>>>(u2, gs, ge, poolHi, poolLo);
  dim3 gh1(4, 4);   // M=512/128, N=512/128
  k_gemm<1, false, true, false, 0, true, false><<<gh1, 256, 0, stream>>>(
      poolHi, poolLo, nullptr, G, 256, 512, 0, 0, wHi + oh1, wLo + oh1, bh1,
      nullptr, nullptr, nullptr, nullptr, nullptr, thidHi, thidLo, nullptr);
  dim3 gh2(4, 6);   // M=512/128, N=768/128
  k_gemm<0, false, false, false, 0, true, false><<<gh2, 256, 0, stream>>>(
      thidHi, thidLo, nullptr, G, 512, 768, 0, 0, wHi + oh2, wLo + oh2, bh2,
      nullptr, nullptr, nullptr, out, nullptr, nullptr, nullptr, nullptr);
}

// Round 16
// 617.089 us; speedup vs baseline: 1.5136x; 1.0603x over previous
//
#include <hip/hip_runtime.h>

// ---------------------------------------------------------------------------
// GIN GraphEncoder on MI355X.
// R16: 64x128 GEMM tile (was 128x128) -- grid 784 -> 1568 blocks (3 -> 6.1
// blocks/CU): R15 counters showed nothing saturated (Mfma 7%, VALU 26%, occ
// 18%) = TLP-starved latency stalls. LDS 16KB, acc[2][4], same staging/
// compute pattern otherwise.
// R15: T14 async z-prefetch + trunc hi/lo split in gemmB staging.
// R14: bf16 gather (activations bf16; k_agg/k_pool 2B/elem).
// Main GEMMs: 2-product split (exact-a x bf16(W)), BK=32, single-buffer,
// gload16 staging, bank-spread swizzle sw(row)=(row&3)^((row>>2)&3),
// XCD-pair block swizzle. gemmB fuses BN+relu(+tanh)+bf16-act write.
// Heads keep full 3-product. Integer inputs arrive as int32.
// Ledger: dbuf +-0, bank-swz -12, sort/wide-tile reverted, BN-fusion -56,
// 2-product -17, bf16-gather -120, T14+trunc -21.
// ---------------------------------------------------------------------------

typedef __attribute__((ext_vector_type(8))) short short8;   // 8 bf16 for MFMA
typedef __attribute__((ext_vector_type(4))) float f32x4;
typedef __attribute__((ext_vector_type(4))) unsigned short us4;
typedef __attribute__((ext_vector_type(8))) unsigned short us8;

__device__ __forceinline__ unsigned short f2bf(float f) {
  unsigned int b = __float_as_uint(f);
  unsigned int r = 0x7FFFu + ((b >> 16) & 1u);   // round-to-nearest-even
  return (unsigned short)((b + r) >> 16);
}
__device__ __forceinline__ float bf2f(unsigned short u) {
  return __uint_as_float(((unsigned int)u) << 16);
}

// bank-spread row swizzle value (4-group domain)
__device__ __forceinline__ int swv(int row) {
  return (row & 3) ^ ((row >> 2) & 3);
}

// global->LDS 16B async copy; LDS dest is wave-uniform base (HW adds lane*16)
typedef const __attribute__((address_space(1))) unsigned int* gas1;
typedef __attribute__((address_space(3))) unsigned int* las3;
__device__ __forceinline__ void gload16(const void* g, void* l) {
  __builtin_amdgcn_global_load_lds((gas1)g, (las3)l, 16, 0, 0);
}

// swizzled flat index of element (row, k), row length K:
// 16B groups (8 us) XORed within each 32-elem block: g' = g ^ swv(row)
__device__ __forceinline__ size_t swz4_idx(int row, int k, int K) {
  int g = k >> 3;
  return (size_t)row * K + ((g >> 2) << 5) + ((((g & 3) ^ swv(row)) << 3)) + (k & 7);
}

// ---------------- CSR build + graph bounds (fused) ----------------
__global__ void k_histbounds(const int* __restrict__ ei, int* __restrict__ deg, int E,
                             int eb, const int* __restrict__ batch,
                             int* __restrict__ gs, int* __restrict__ ge, int N) {
  int b = blockIdx.x;
  if (b < eb) {
    int e = b * 256 + threadIdx.x;
    if (e < E) atomicAdd(&deg[ei[E + e]], 1);
  } else {
    int i = (b - eb) * 256 + threadIdx.x;
    if (i < N) {
      int bb = batch[i];
      if (i == 0 || batch[i - 1] != bb) gs[bb] = i;
      if (i == N - 1 || batch[i + 1] != bb) ge[bb] = i + 1;
    }
  }
}

// phase 1: per-block (1024 elems) inclusive scan + block sum
__global__ __launch_bounds__(1024) void k_scan1(const int* __restrict__ deg,
                                                int* __restrict__ partial,
                                                int* __restrict__ bsum, int N) {
  __shared__ int sd[1024];
  int tid = threadIdx.x;
  int i = blockIdx.x * 1024 + tid;
  int v = (i < N) ? deg[i] : 0;
  sd[tid] = v;
  __syncthreads();
  for (int off = 1; off < 1024; off <<= 1) {
    int t = (tid >= off) ? sd[tid - off] : 0;
    __syncthreads();
    sd[tid] += t;
    __syncthreads();
  }
  if (i < N) partial[i] = sd[tid];
  if (tid == 1023) bsum[blockIdx.x] = sd[1023];
}

// phase 2: exclusive scan of <=64 block sums in one wave
__global__ void k_scan2(int* __restrict__ bsum, int nb) {
  int l = threadIdx.x;
  int orig = (l < nb) ? bsum[l] : 0;
  int v = orig;
  for (int off = 1; off < 64; off <<= 1) {
    int t = __shfl_up(v, off);
    if (l >= off) v += t;
  }
  if (l < nb) bsum[l] = v - orig;
}

// phase 3: rowptr / cursor
__global__ void k_scan3(const int* __restrict__ deg, const int* __restrict__ partial,
                        const int* __restrict__ bsum, int* __restrict__ rowptr,
                        int* __restrict__ cursor, int N) {
  int i = blockIdx.x * 256 + threadIdx.x;
  if (i >= N) return;
  int incl = partial[i] + bsum[i >> 10];
  rowptr[i + 1] = incl;
  cursor[i] = incl - deg[i];
  if (i == 0) rowptr[0] = 0;
}

__global__ void k_fill(const int* __restrict__ ei, int* __restrict__ cursor,
                       int* __restrict__ adj, int E) {
  int e = blockIdx.x * 256 + threadIdx.x;
  if (e >= E) return;
  int s = ei[e];
  int d = ei[E + e];
  int pos = atomicAdd(&cursor[d], 1);
  adj[pos] = s;
}

// ---- x f32 -> bf16 (one-time; feeds layer-1 gather) ----
__global__ void k_xbf(const float* __restrict__ X, unsigned short* __restrict__ Xb,
                      int total) {
  int t = blockIdx.x * 256 + threadIdx.x;   // one 8-elem group
  if (t * 8 >= total) return;
  const float4 v0 = *(const float4*)(X + t * 8);
  const float4 v1 = *(const float4*)(X + t * 8 + 4);
  us8 o;
  o[0] = f2bf(v0.x); o[1] = f2bf(v0.y); o[2] = f2bf(v0.z); o[3] = f2bf(v0.w);
  o[4] = f2bf(v1.x); o[5] = f2bf(v1.y); o[6] = f2bf(v1.z); o[7] = f2bf(v1.w);
  *(us8*)(Xb + t * 8) = o;
}

// ---- ALL weights: transpose + split + swizzle in ONE kernel ----
__global__ void k_prep_all(const float* __restrict__ w1a, const float* __restrict__ w1b,
                           const float* __restrict__ w2a, const float* __restrict__ w2b,
                           const float* __restrict__ w3a, const float* __restrict__ w3b,
                           const float* __restrict__ wh1, const float* __restrict__ wh2,
                           unsigned short* __restrict__ Hi, unsigned short* __restrict__ Lo) {
  int idx = blockIdx.x * 256 + threadIdx.x;   // [0, 884736)
  const float* W; int K, Nout, lo_;
  if (idx < 32768)       { W = w1a; K = 128; Nout = 256; lo_ = 0; }
  else if (idx < 98304)  { W = w1b; K = 256; Nout = 256; lo_ = 32768; }
  else if (idx < 163840) { W = w2a; K = 256; Nout = 256; lo_ = 98304; }
  else if (idx < 229376) { W = w2b; K = 256; Nout = 256; lo_ = 163840; }
  else if (idx < 294912) { W = w3a; K = 256; Nout = 256; lo_ = 229376; }
  else if (idx < 360448) { W = w3b; K = 256; Nout = 256; lo_ = 294912; }
  else if (idx < 491520) { W = wh1; K = 256; Nout = 512; lo_ = 360448; }
  else                   { W = wh2; K = 512; Nout = 768; lo_ = 491520; }
  int li = idx - lo_;
  int n = li % Nout, k = li / Nout;
  float w = W[k * Nout + n];
  unsigned short h = f2bf(w);
  size_t oi = (size_t)lo_ + swz4_idx(n, k, K);
  Hi[oi] = h;
  Lo[oi] = f2bf(w - bf2f(h));   // only heads read Lo
}

// -------- aggregation: h = Xb[i] + sum Xb[adj[e]] (bf16 gather, f32 acc) ----
// Writes split+swizzled h. Block 0 zeroes stats[] for the following gemmA.
template <int C>
__global__ __launch_bounds__(256) void k_agg(const unsigned short* __restrict__ Xb,
                                             unsigned short* __restrict__ HHi,
                                             unsigned short* __restrict__ HLo,
                                             const int* __restrict__ rowptr,
                                             const int* __restrict__ adj, int N,
                                             float* __restrict__ statsZ) {
  if (blockIdx.x == 0) {
    statsZ[threadIdx.x] = 0.f;
    statsZ[256 + threadIdx.x] = 0.f;
  }
  int node = blockIdx.x * 4 + (threadIdx.x >> 6);
  if (node >= N) return;
  int lane = threadIdx.x & 63;
  int e0 = rowptr[node], e1 = rowptr[node + 1];
  if constexpr (C == 256) {
    us4 ov = *(const us4*)(Xb + (size_t)node * C + lane * 4);
    float a0 = bf2f(ov[0]), a1 = bf2f(ov[1]), a2 = bf2f(ov[2]), a3 = bf2f(ov[3]);
    int e = e0;
    for (; e + 4 <= e1; e += 4) {
      int s0 = adj[e], s1 = adj[e + 1], s2 = adj[e + 2], s3 = adj[e + 3];
      us4 v0 = *(const us4*)(Xb + (size_t)s0 * C + lane * 4);
      us4 v1 = *(const us4*)(Xb + (size_t)s1 * C + lane * 4);
      us4 v2 = *(const us4*)(Xb + (size_t)s2 * C + lane * 4);
      us4 v3 = *(const us4*)(Xb + (size_t)s3 * C + lane * 4);
      a0 += (bf2f(v0[0]) + bf2f(v1[0])) + (bf2f(v2[0]) + bf2f(v3[0]));
      a1 += (bf2f(v0[1]) + bf2f(v1[1])) + (bf2f(v2[1]) + bf2f(v3[1]));
      a2 += (bf2f(v0[2]) + bf2f(v1[2])) + (bf2f(v2[2]) + bf2f(v3[2]));
      a3 += (bf2f(v0[3]) + bf2f(v1[3])) + (bf2f(v2[3]) + bf2f(v3[3]));
    }
    for (; e < e1; ++e) {
      us4 v = *(const us4*)(Xb + (size_t)adj[e] * C + lane * 4);
      a0 += bf2f(v[0]); a1 += bf2f(v[1]); a2 += bf2f(v[2]); a3 += bf2f(v[3]);
    }
    float vv[4] = {a0, a1, a2, a3};
    us4 hv, lv;
#pragma unroll
    for (int j = 0; j < 4; ++j) {
      unsigned short h = f2bf(vv[j]);
      hv[j] = h;
      lv[j] = f2bf(vv[j] - bf2f(h));
    }
    size_t oi = (size_t)node * 256 + ((lane >> 3) << 5) +
                ((((lane >> 1) & 3) ^ swv(node)) << 3) + ((lane & 1) << 2);
    *(us4*)(HHi + oi) = hv;
    *(us4*)(HLo + oi) = lv;
  } else {  // C == 128
    ushort2 ov = *(const ushort2*)(Xb + (size_t)node * C + lane * 2);
    float a0 = bf2f(ov.x), a1 = bf2f(ov.y);
    int e = e0;
    for (; e + 4 <= e1; e += 4) {
      int s0 = adj[e], s1 = adj[e + 1], s2 = adj[e + 2], s3 = adj[e + 3];
      ushort2 v0 = *(const ushort2*)(Xb + (size_t)s0 * C + lane * 2);
      ushort2 v1 = *(const ushort2*)(Xb + (size_t)s1 * C + lane * 2);
      ushort2 v2 = *(const ushort2*)(Xb + (size_t)s2 * C + lane * 2);
      ushort2 v3 = *(const ushort2*)(Xb + (size_t)s3 * C + lane * 2);
      a0 += (bf2f(v0.x) + bf2f(v1.x)) + (bf2f(v2.x) + bf2f(v3.x));
      a1 += (bf2f(v0.y) + bf2f(v1.y)) + (bf2f(v2.y) + bf2f(v3.y));
    }
    for (; e < e1; ++e) {
      ushort2 v = *(const ushort2*)(Xb + (size_t)adj[e] * C + lane * 2);
      a0 += bf2f(v.x); a1 += bf2f(v.y);
    }
    unsigned short hx = f2bf(a0), hy = f2bf(a1);
    ushort2 hv = {hx, hy};
    ushort2 lv = {f2bf(a0 - bf2f(hx)), f2bf(a1 - bf2f(hy))};
    size_t oi = (size_t)node * 128 + ((lane >> 4) << 5) +
                ((((lane >> 2) & 3) ^ swv(node)) << 3) + ((lane & 3) << 1);
    *(ushort2*)(HHi + oi) = hv;
    *(ushort2*)(HLo + oi) = lv;
  }
}

// ------------ MFMA GEMM: 64x128 tile, BK=32, single-buffer, 16KB LDS --------
// 4 waves: wm=w>>1 (32-row half), wn=w&1 (64-col half); acc[2][4].
// FULL=false: 2-product (exact-a x bf16(W)), wLo not staged.
// FULL=true (heads): 3-product. ASRC: 0 presplit gload16; 2 f32 z reg-staged
// with BN+relu+TRUNC-split, z loads for k+1 prefetched under MFMA (T14).
// EPI: 0 none, 1 relu, 2 tanh, 3 relu(tanh). OBF16: bf16 act write (gemmB).
// OSPLIT: split+swizzled out (head1, relu). STATS: fused BN sum/sumsq.
// XSWZ: XCD-pair swizzle.
template <int EPI, bool STATS, bool OSPLIT, bool XSWZ, int ASRC, bool FULL, bool OBF16>
__global__ __launch_bounds__(256) void k_gemm(
    const unsigned short* __restrict__ AHi, const unsigned short* __restrict__ ALo,
    const float* __restrict__ Zf,
    int M, int K, int Nld, int mb, int per,
    const unsigned short* __restrict__ WHi, const unsigned short* __restrict__ WLo,
    const float* __restrict__ bias,
    const float* __restrict__ statsIn, const float* __restrict__ gvec,
    const float* __restrict__ bevec,
    float* __restrict__ Out, unsigned short* __restrict__ OutB,
    unsigned short* __restrict__ OHi, unsigned short* __restrict__ OLo,
    float* __restrict__ statsOut) {
  __shared__ unsigned short aHi[2048], aLo[2048], bHi[4096];   // 4+4+8 KB
  __shared__ unsigned short bLo[FULL ? 4096 : 64];
  __shared__ float sBNsc[ASRC == 2 ? 256 : 1], sBNsh[ASRC == 2 ? 256 : 1];
  int bx, by;
  if constexpr (XSWZ) {
    int xcd = blockIdx.x & 7, slot = blockIdx.x >> 3;
    bx = xcd * per + (slot >> 1);
    by = slot & 1;
    if (bx >= mb) return;
  } else {
    bx = blockIdx.x;
    by = blockIdx.y;
  }
  const int tid = threadIdx.x;
  const int lane = tid & 63, w = tid >> 6;
  const int wm = w >> 1, wn = w & 1;
  const int m0 = bx * 64, n0 = by * 128;

  if constexpr (ASRC == 2) {
    // per-column scale/shift, exact op order of old k_finalize
    float mu = statsIn[tid] / (float)M;
    float var = statsIn[256 + tid] / (float)M - mu * mu;
    float sc = gvec[tid] * rsqrtf(var + 1e-5f);
    sBNsc[tid] = sc;
    sBNsh[tid] = bevec[tid] - mu * sc;
  }

  f32x4 zero = {0.f, 0.f, 0.f, 0.f};
  f32x4 acc[2][4];
#pragma unroll
  for (int i = 0; i < 2; ++i)
#pragma unroll
    for (int j = 0; j < 4; ++j) acc[i][j] = zero;

  const int rq = lane >> 2;     // 0..15
  const int k8s = lane & 3;     // 16B slot

  // T14 prefetch regs for ASRC==2 (one z row-group per thread: 8 f32)
  float4 zr0, zr1;
  const float* zbase0 = nullptr;
  if constexpr (ASRC == 2) {
    int row0 = tid >> 2, gq0 = tid & 3;          // row0 0..63
    int ra0 = m0 + row0; if (ra0 >= M) ra0 = M - 1;
    zbase0 = Zf + (size_t)ra0 * K + gq0 * 8;
    zr0 = *(const float4*)(zbase0);
    zr1 = *(const float4*)(zbase0 + 4);
  }

  for (int kb = 0; kb < K; kb += 32) {
    __syncthreads();
    if constexpr (ASRC == 2) {
      // consume prefetched z regs: BN+relu+TRUNC-split -> swizzled ds_write
      int row = tid >> 2, gq = tid & 3;
      float f[8] = {zr0.x, zr0.y, zr0.z, zr0.w, zr1.x, zr1.y, zr1.z, zr1.w};
      us8 hv, lv;
#pragma unroll
      for (int jj = 0; jj < 8; ++jj) {
        int kc = kb + gq * 8 + jj;
        float o = fmaxf(f[jj] * sBNsc[kc] + sBNsh[kc], 0.f);
        unsigned short h = (unsigned short)(__float_as_uint(o) >> 16);  // trunc
        hv[jj] = h;
        float rem = o - bf2f(h);
        lv[jj] = (unsigned short)(__float_as_uint(rem) >> 16);          // trunc
      }
      int bo = row * 64 + ((gq ^ swv(row)) << 4);
      *(us8*)((char*)aHi + bo) = hv;
      *(us8*)((char*)aLo + bo) = lv;
      // B via gload16 (2 rounds)
#pragma unroll
      for (int q = 0; q < 2; ++q) {
        int rloc = (w << 5) + (q << 4) + rq;
        size_t gb = (size_t)(n0 + rloc) * K + kb + k8s * 8;
        unsigned bo2 = (w << 11) + (q << 10);
        gload16(WHi + gb, (char*)bHi + bo2);
        if constexpr (FULL) gload16(WLo + gb, (char*)bLo + bo2);
      }
    } else {
      // A: 64 rows, wave w covers rows [16w,16w+16) -- one round each hi/lo
      int raA = m0 + (w << 4) + rq; if (raA >= M) raA = M - 1;
      size_t ga = (size_t)raA * K + kb + k8s * 8;   // swizzles cancel -> linear
      gload16(AHi + ga, (char*)aHi + (w << 10));
      gload16(ALo + ga, (char*)aLo + (w << 10));
      // B: 128 rows -- two rounds
#pragma unroll
      for (int q = 0; q < 2; ++q) {
        int rloc = (w << 5) + (q << 4) + rq;
        size_t gb = (size_t)(n0 + rloc) * K + kb + k8s * 8;
        unsigned bo2 = (w << 11) + (q << 10);
        gload16(WHi + gb, (char*)bHi + bo2);
        if constexpr (FULL) gload16(WLo + gb, (char*)bLo + bo2);
      }
    }
    __syncthreads();

    // T14: issue next tile's z loads here -- they complete under the MFMAs
    if constexpr (ASRC == 2) {
      if (kb + 32 < K) {
        zr0 = *(const float4*)(zbase0 + kb + 32);
        zr1 = *(const float4*)(zbase0 + kb + 36);
      }
    }

    const int j = lane >> 4;
    short8 bh[4], bl[4];
#pragma unroll
    for (int ni = 0; ni < 4; ++ni) {
      int r = wn * 64 + ni * 16 + (lane & 15);
      int bo = r * 64 + ((j ^ swv(r)) << 4);
      bh[ni] = *(const short8*)((const char*)bHi + bo);
      if constexpr (FULL) bl[ni] = *(const short8*)((const char*)bLo + bo);
    }
#pragma unroll
    for (int mi = 0; mi < 2; ++mi) {
      int r = wm * 32 + mi * 16 + (lane & 15);
      int bo = r * 64 + ((j ^ swv(r)) << 4);
      short8 ah = *(const short8*)((const char*)aHi + bo);
      short8 al = *(const short8*)((const char*)aLo + bo);
#pragma unroll
      for (int ni = 0; ni < 4; ++ni) {
        acc[mi][ni] = __builtin_amdgcn_mfma_f32_16x16x32_bf16(ah, bh[ni], acc[mi][ni], 0, 0, 0);
        if constexpr (FULL)
          acc[mi][ni] = __builtin_amdgcn_mfma_f32_16x16x32_bf16(ah, bl[ni], acc[mi][ni], 0, 0, 0);
        acc[mi][ni] = __builtin_amdgcn_mfma_f32_16x16x32_bf16(al, bh[ni], acc[mi][ni], 0, 0, 0);
      }
    }
  }

  // epilogue: C/D layout col = lane&15, row = (lane>>4)*4 + r   [m89-verified]
#pragma unroll
  for (int ni = 0; ni < 4; ++ni) {
    int col = n0 + wn * 64 + ni * 16 + (lane & 15);
    float bc = bias[col];
    float s = 0.f, q = 0.f;
#pragma unroll
    for (int mi = 0; mi < 2; ++mi) {
      int rbase = m0 + wm * 32 + mi * 16 + (lane >> 4) * 4;
#pragma unroll
      for (int r = 0; r < 4; ++r) {
        int row = rbase + r;
        if (row < M) {
          float o = acc[mi][ni][r] + bc;
          if (STATS) { s += o; q += o * o; }
          if (OSPLIT) {
            o = fmaxf(o, 0.f);   // relu (head1)
            unsigned short h = f2bf(o);
            size_t oi = swz4_idx(row, col, Nld);
            OHi[oi] = h;
            OLo[oi] = f2bf(o - bf2f(h));
          } else {
            if (EPI == 1) o = fmaxf(o, 0.f);
            else if (EPI == 2) o = tanhf(o);
            else if (EPI == 3) o = fmaxf(tanhf(o), 0.f);
            if (OBF16) OutB[(size_t)row * Nld + col] = f2bf(o);
            else       Out[(size_t)row * Nld + col] = o;
          }
        }
      }
    }
    if (STATS) {
      s += __shfl_xor(s, 16); s += __shfl_xor(s, 32);
      q += __shfl_xor(q, 16); q += __shfl_xor(q, 32);
      if ((lane >> 4) == 0) {
        atomicAdd(&statsOut[col], s);
        atomicAdd(&statsOut[256 + col], q);
      }
    }
  }
}

// ---------------- pooling (bf16 input) ----------------
__global__ __launch_bounds__(256) void k_pool(const unsigned short* __restrict__ Hb,
                                              const int* __restrict__ gs,
                                              const int* __restrict__ ge,
                                              unsigned short* __restrict__ PHi,
                                              unsigned short* __restrict__ PLo) {
  __shared__ float4 red[4][64];
  int gi = blockIdx.x;
  int s = gs[gi], e = ge[gi];
  int w = threadIdx.x >> 6, lane = threadIdx.x & 63;
  float4 acc = {0.f, 0.f, 0.f, 0.f};
  for (int r = s + w; r < e; r += 4) {
    us4 v = *(const us4*)(Hb + (size_t)r * 256 + lane * 4);
    acc.x += bf2f(v[0]); acc.y += bf2f(v[1]);
    acc.z += bf2f(v[2]); acc.w += bf2f(v[3]);
  }
  red[w][lane] = acc;
  __syncthreads();
  if (w == 0) {
    float4 a = red[0][lane], b = red[1][lane], c = red[2][lane], d = red[3][lane];
    float inv = 1.0f / fmaxf((float)(e - s), 1.0f);
    float vv[4] = {(a.x + b.x + c.x + d.x) * inv, (a.y + b.y + c.y + d.y) * inv,
                   (a.z + b.z + c.z + d.z) * inv, (a.w + b.w + c.w + d.w) * inv};
    us4 hv, lv;
#pragma unroll
    for (int j = 0; j < 4; ++j) {
      unsigned short h = f2bf(vv[j]);
      hv[j] = h;
      lv[j] = f2bf(vv[j] - bf2f(h));
    }
    size_t oi = (size_t)gi * 256 + ((lane >> 3) << 5) +
                ((((lane >> 1) & 3) ^ swv(gi)) << 3) + ((lane & 1) << 2);
    *(us4*)(PHi + oi) = hv;
    *(us4*)(PLo + oi) = lv;
  }
}

// ---------------------------------------------------------------------------
extern "C" void kernel_launch(void* const* d_in, const int* in_sizes, int n_in,
                              void* d_out, int out_size, void* d_ws, size_t ws_size,
                              hipStream_t stream) {
  const float* x      = (const float*)d_in[0];
  const int* ei       = (const int*)d_in[1];    // int32 from harness
  const int* bat      = (const int*)d_in[2];    // int32 from harness
  const float* w1a = (const float*)d_in[3];  const float* b1a = (const float*)d_in[4];
  const float* g1  = (const float*)d_in[5];  const float* be1 = (const float*)d_in[6];
  const float* w1b = (const float*)d_in[7];  const float* b1b = (const float*)d_in[8];
  const float* w2a = (const float*)d_in[9];  const float* b2a = (const float*)d_in[10];
  const float* g2  = (const float*)d_in[11]; const float* be2 = (const float*)d_in[12];
  const float* w2b = (const float*)d_in[13]; const float* b2b = (const float*)d_in[14];
  const float* w3a = (const float*)d_in[15]; const float* b3a = (const float*)d_in[16];
  const float* g3  = (const float*)d_in[17]; const float* be3 = (const float*)d_in[18];
  const float* w3b = (const float*)d_in[19]; const float* b3b = (const float*)d_in[20];
  const float* wh1 = (const float*)d_in[21]; const float* bh1 = (const float*)d_in[22];
  const float* wh2 = (const float*)d_in[23]; const float* bh2 = (const float*)d_in[24];
  float* out = (float*)d_out;

  const int N = in_sizes[0] / 128;   // 50000
  const int E = in_sizes[1] / 2;     // 800000
  const int G = 512;

  // ---- workspace: 3 rotating 51.2MB regions + bf16 x ----
  char* ws = (char*)d_ws;
  size_t off = 0;
  auto alloc = [&](size_t bytes) {
    void* p = ws + off;
    off = (off + bytes + 255) & ~(size_t)255;
    return p;
  };
  char* reg0 = (char*)alloc((size_t)N * 256 * 4);
  char* reg1 = (char*)alloc((size_t)N * 256 * 4);
  char* reg2 = (char*)alloc((size_t)N * 256 * 4);
  unsigned short* xb = (unsigned short*)alloc((size_t)N * 128 * 2);
  int* adj     = (int*)alloc((size_t)E * 4);
  int* rowptr  = (int*)alloc((size_t)(N + 1) * 4);
  int* cursor  = (int*)alloc((size_t)N * 4);
  int* deg     = (int*)alloc((size_t)N * 4);
  int* partial = (int*)alloc((size_t)N * 4);
  int* bsum    = (int*)alloc(64 * 4);
  unsigned short* wHi = (unsigned short*)alloc(884736 * 2);
  unsigned short* wLo = (unsigned short*)alloc(884736 * 2);
  float* stats = (float*)alloc(512 * 4);
  int* gs      = (int*)alloc(G * 4);
  int* ge      = (int*)alloc(G * 4);
  unsigned short* poolHi = (unsigned short*)alloc((size_t)G * 256 * 2);
  unsigned short* poolLo = (unsigned short*)alloc((size_t)G * 256 * 2);
  unsigned short* thidHi = (unsigned short*)alloc((size_t)G * 512 * 2);
  unsigned short* thidLo = (unsigned short*)alloc((size_t)G * 512 * 2);

  // region views
  float* f0 = (float*)reg0; float* f1 = (float*)reg1; float* f2 = (float*)reg2;
  unsigned short* u0 = (unsigned short*)reg0;
  unsigned short* u1 = (unsigned short*)reg1;
  unsigned short* u2 = (unsigned short*)reg2;

  // transposed-weight element offsets (match k_prep_all segment table)
  const int o1a = 0, o1b = 32768, o2a = 98304, o2b = 163840, o3a = 229376, o3b = 294912;
  const int oh1 = 360448, oh2 = 491520;   // ends at 884736

  hipMemsetAsync(deg, 0, (size_t)N * 4, stream);
  hipMemsetAsync(gs, 0, (size_t)G * 4, stream);
  hipMemsetAsync(ge, 0, (size_t)G * 4, stream);

  int eb = (E + 255) / 256;
  int nbN = (N + 255) / 256;
  int nb1 = (N + 1023) >> 10;   // 49 (<=64 required by k_scan2)
  k_histbounds<<<eb + nbN, 256, 0, stream>>>(ei, deg, E, eb, bat, gs, ge, N);
  k_scan1<<<nb1, 1024, 0, stream>>>(deg, partial, bsum, N);
  k_scan2<<<1, 64, 0, stream>>>(bsum, nb1);
  k_scan3<<<nbN, 256, 0, stream>>>(deg, partial, bsum, rowptr, cursor, N);
  k_fill<<<eb, 256, 0, stream>>>(ei, cursor, adj, E);

  k_xbf<<<(N * 128 / 8 + 255) / 256, 256, 0, stream>>>(x, xb, N * 128);
  k_prep_all<<<3456, 256, 0, stream>>>(w1a, w1b, w2a, w2b, w3a, w3b, wh1, wh2, wHi, wLo);

  int nb4 = (N + 3) / 4;
  const int mb = (N + 63) / 64;          // 782 M-tiles of 64 rows
  const int per = (mb + 7) / 8;          // 98
  dim3 gg(per * 16);                     // XCD-pair swizzled flat grid (1568)

  // ---- layer 1: xb -> split@{reg0,reg1} -> z@reg2 -> actB@u0 ----
  k_agg<128><<<nb4, 256, 0, stream>>>(xb, u0, u1, rowptr, adj, N, stats);
  k_gemm<0, true, false, true, 0, false, false><<<gg, 256, 0, stream>>>(
      u0, u1, nullptr, N, 128, 256, mb, per, wHi + o1a, wLo + o1a, b1a,
      nullptr, nullptr, nullptr, f2, nullptr, nullptr, nullptr, stats);
  k_gemm<1, false, false, true, 2, false, true><<<gg, 256, 0, stream>>>(
      nullptr, nullptr, f2, N, 256, 256, mb, per, wHi + o1b, wLo + o1b, b1b,
      stats, g1, be1, nullptr, u0, nullptr, nullptr, nullptr);

  // ---- layer 2: actB@u0 -> split@{reg1,reg2} -> z@reg0 -> actB@u1 ----
  k_agg<256><<<nb4, 256, 0, stream>>>(u0, u1, u2, rowptr, adj, N, stats);
  k_gemm<0, true, false, true, 0, false, false><<<gg, 256, 0, stream>>>(
      u1, u2, nullptr, N, 256, 256, mb, per, wHi + o2a, wLo + o2a, b2a,
      nullptr, nullptr, nullptr, f0, nullptr, nullptr, nullptr, stats);
  k_gemm<3, false, false, true, 2, false, true><<<gg, 256, 0, stream>>>(
      nullptr, nullptr, f0, N, 256, 256, mb, per, wHi + o2b, wLo + o2b, b2b,
      stats, g2, be2, nullptr, u1, nullptr, nullptr, nullptr);

  // ---- layer 3: actB@u1 -> split@{reg2,reg0} -> z@reg1 -> actB@u2 ----
  k_agg<256><<<nb4, 256, 0, stream>>>(u1, u2, u0, rowptr, adj, N, stats);
  k_gemm<0, true, false, true, 0, false, false><<<gg, 256, 0, stream>>>(
      u2, u0, nullptr, N, 256, 256, mb, per, wHi + o3a, wLo + o3a, b3a,
      nullptr, nullptr, nullptr, f1, nullptr, nullptr, nullptr, stats);
  k_gemm<2, false, false, true, 2, false, true><<<gg, 256, 0, stream>>>(
      nullptr, nullptr, f1, N, 256, 256, mb, per, wHi + o3b, wLo + o3b, b3b,
      stats, g3, be3, nullptr, u2, nullptr, nullptr, nullptr);

  // ---- pool + MFMA heads (heads keep FULL 3-product split) ----
  k_pool<<<G, 256, 0, stream>>>(u2, gs, ge, poolHi, poolLo);
  dim3 gh1(8, 4);   // M=512/64 tiles, N=512/128 col-halves
  k_gemm<1, false, true, false, 0, true, false><<<gh1, 256, 0, stream>>>(
      poolHi, poolLo, nullptr, G, 256, 512, 0, 0, wHi + oh1, wLo + oh1, bh1,
      nullptr, nullptr, nullptr, nullptr, nullptr, thidHi, thidLo, nullptr);
  dim3 gh2(8, 6);   // M=512/64 tiles, N=768/128 col-halves
  k_gemm<0, false, false, false, 0, true, false><<<gh2, 256, 0, stream>>>(
      thidHi, thidLo, nullptr, G, 512, 768, 0, 0, wHi + oh2, wLo + oh2, bh2,
      nullptr, nullptr, nullptr, out, nullptr, nullptr, nullptr, nullptr);
}

// Round 17
// 602.338 us; speedup vs baseline: 1.5507x; 1.0245x over previous
//
#include <hip/hip_runtime.h>

// ---------------------------------------------------------------------------
// GIN GraphEncoder on MI355X.
// R17: PLAIN-BF16 main path. Evidence: absmax bit-frozen at 2^-10 through
// bf16 weights (R13) and bf16 activations (R14); GEMMs and agg both pinned
// at the same ~4 TB/s cache-service wall (R16 counters) -> only demand-byte
// reduction pays. Main GEMMs: 1-product bf16 x bf16 (MFMA f32 accum);
// h, z, activations all bf16 (z written bf16; BN stats still from f32 acc).
// Heads keep full 3-product split (their error feeds the output directly).
// 64x128 tile, BK=32, 12KB LDS, gload16 staging, bank-spread swizzle
// sw(row)=(row&3)^((row>>2)&3), XCD-pair swizzle, T14 z-prefetch in gemmB.
// Ledger: BN-fusion -56, 2-product -17, bf16-gather -120, T14 -21,
// 64x128 tile -37. Declared risk: absmax may rise to ~1.5-3e-3 (thr 3.9e-3).
// ---------------------------------------------------------------------------

typedef __attribute__((ext_vector_type(8))) short short8;   // 8 bf16 for MFMA
typedef __attribute__((ext_vector_type(4))) float f32x4;
typedef __attribute__((ext_vector_type(4))) unsigned short us4;
typedef __attribute__((ext_vector_type(8))) unsigned short us8;

__device__ __forceinline__ unsigned short f2bf(float f) {
  unsigned int b = __float_as_uint(f);
  unsigned int r = 0x7FFFu + ((b >> 16) & 1u);   // round-to-nearest-even
  return (unsigned short)((b + r) >> 16);
}
__device__ __forceinline__ float bf2f(unsigned short u) {
  return __uint_as_float(((unsigned int)u) << 16);
}

// bank-spread row swizzle value (4-group domain)
__device__ __forceinline__ int swv(int row) {
  return (row & 3) ^ ((row >> 2) & 3);
}

// global->LDS 16B async copy; LDS dest is wave-uniform base (HW adds lane*16)
typedef const __attribute__((address_space(1))) unsigned int* gas1;
typedef __attribute__((address_space(3))) unsigned int* las3;
__device__ __forceinline__ void gload16(const void* g, void* l) {
  __builtin_amdgcn_global_load_lds((gas1)g, (las3)l, 16, 0, 0);
}

// swizzled flat index of element (row, k), row length K:
// 16B groups (8 us) XORed within each 32-elem block: g' = g ^ swv(row)
__device__ __forceinline__ size_t swz4_idx(int row, int k, int K) {
  int g = k >> 3;
  return (size_t)row * K + ((g >> 2) << 5) + ((((g & 3) ^ swv(row)) << 3)) + (k & 7);
}

// ---------------- CSR build + graph bounds (fused) ----------------
__global__ void k_histbounds(const int* __restrict__ ei, int* __restrict__ deg, int E,
                             int eb, const int* __restrict__ batch,
                             int* __restrict__ gs, int* __restrict__ ge, int N) {
  int b = blockIdx.x;
  if (b < eb) {
    int e = b * 256 + threadIdx.x;
    if (e < E) atomicAdd(&deg[ei[E + e]], 1);
  } else {
    int i = (b - eb) * 256 + threadIdx.x;
    if (i < N) {
      int bb = batch[i];
      if (i == 0 || batch[i - 1] != bb) gs[bb] = i;
      if (i == N - 1 || batch[i + 1] != bb) ge[bb] = i + 1;
    }
  }
}

__global__ __launch_bounds__(1024) void k_scan1(const int* __restrict__ deg,
                                                int* __restrict__ partial,
                                                int* __restrict__ bsum, int N) {
  __shared__ int sd[1024];
  int tid = threadIdx.x;
  int i = blockIdx.x * 1024 + tid;
  int v = (i < N) ? deg[i] : 0;
  sd[tid] = v;
  __syncthreads();
  for (int off = 1; off < 1024; off <<= 1) {
    int t = (tid >= off) ? sd[tid - off] : 0;
    __syncthreads();
    sd[tid] += t;
    __syncthreads();
  }
  if (i < N) partial[i] = sd[tid];
  if (tid == 1023) bsum[blockIdx.x] = sd[1023];
}

__global__ void k_scan2(int* __restrict__ bsum, int nb) {
  int l = threadIdx.x;
  int orig = (l < nb) ? bsum[l] : 0;
  int v = orig;
  for (int off = 1; off < 64; off <<= 1) {
    int t = __shfl_up(v, off);
    if (l >= off) v += t;
  }
  if (l < nb) bsum[l] = v - orig;
}

__global__ void k_scan3(const int* __restrict__ deg, const int* __restrict__ partial,
                        const int* __restrict__ bsum, int* __restrict__ rowptr,
                        int* __restrict__ cursor, int N) {
  int i = blockIdx.x * 256 + threadIdx.x;
  if (i >= N) return;
  int incl = partial[i] + bsum[i >> 10];
  rowptr[i + 1] = incl;
  cursor[i] = incl - deg[i];
  if (i == 0) rowptr[0] = 0;
}

__global__ void k_fill(const int* __restrict__ ei, int* __restrict__ cursor,
                       int* __restrict__ adj, int E) {
  int e = blockIdx.x * 256 + threadIdx.x;
  if (e >= E) return;
  int s = ei[e];
  int d = ei[E + e];
  int pos = atomicAdd(&cursor[d], 1);
  adj[pos] = s;
}

// ---- x f32 -> bf16 (one-time; feeds layer-1 gather) ----
__global__ void k_xbf(const float* __restrict__ X, unsigned short* __restrict__ Xb,
                      int total) {
  int t = blockIdx.x * 256 + threadIdx.x;   // one 8-elem group
  if (t * 8 >= total) return;
  const float4 v0 = *(const float4*)(X + t * 8);
  const float4 v1 = *(const float4*)(X + t * 8 + 4);
  us8 o;
  o[0] = f2bf(v0.x); o[1] = f2bf(v0.y); o[2] = f2bf(v0.z); o[3] = f2bf(v0.w);
  o[4] = f2bf(v1.x); o[5] = f2bf(v1.y); o[6] = f2bf(v1.z); o[7] = f2bf(v1.w);
  *(us8*)(Xb + t * 8) = o;
}

// ---- ALL weights: transpose + split + swizzle in ONE kernel ----
__global__ void k_prep_all(const float* __restrict__ w1a, const float* __restrict__ w1b,
                           const float* __restrict__ w2a, const float* __restrict__ w2b,
                           const float* __restrict__ w3a, const float* __restrict__ w3b,
                           const float* __restrict__ wh1, const float* __restrict__ wh2,
                           unsigned short* __restrict__ Hi, unsigned short* __restrict__ Lo) {
  int idx = blockIdx.x * 256 + threadIdx.x;   // [0, 884736)
  const float* W; int K, Nout, lo_;
  if (idx < 32768)       { W = w1a; K = 128; Nout = 256; lo_ = 0; }
  else if (idx < 98304)  { W = w1b; K = 256; Nout = 256; lo_ = 32768; }
  else if (idx < 163840) { W = w2a; K = 256; Nout = 256; lo_ = 98304; }
  else if (idx < 229376) { W = w2b; K = 256; Nout = 256; lo_ = 163840; }
  else if (idx < 294912) { W = w3a; K = 256; Nout = 256; lo_ = 229376; }
  else if (idx < 360448) { W = w3b; K = 256; Nout = 256; lo_ = 294912; }
  else if (idx < 491520) { W = wh1; K = 256; Nout = 512; lo_ = 360448; }
  else                   { W = wh2; K = 512; Nout = 768; lo_ = 491520; }
  int li = idx - lo_;
  int n = li % Nout, k = li / Nout;
  float w = W[k * Nout + n];
  unsigned short h = f2bf(w);
  size_t oi = (size_t)lo_ + swz4_idx(n, k, K);
  Hi[oi] = h;
  Lo[oi] = f2bf(w - bf2f(h));   // only heads read Lo
}

// -------- aggregation: h = Xb[i] + sum Xb[adj[e]] (bf16 gather, f32 acc) ----
// Writes h as single bf16, swizzled. Block 0 zeroes stats[].
template <int C>
__global__ __launch_bounds__(256) void k_agg(const unsigned short* __restrict__ Xb,
                                             unsigned short* __restrict__ Hb,
                                             const int* __restrict__ rowptr,
                                             const int* __restrict__ adj, int N,
                                             float* __restrict__ statsZ) {
  if (blockIdx.x == 0) {
    statsZ[threadIdx.x] = 0.f;
    statsZ[256 + threadIdx.x] = 0.f;
  }
  int node = blockIdx.x * 4 + (threadIdx.x >> 6);
  if (node >= N) return;
  int lane = threadIdx.x & 63;
  int e0 = rowptr[node], e1 = rowptr[node + 1];
  if constexpr (C == 256) {
    us4 ov = *(const us4*)(Xb + (size_t)node * C + lane * 4);
    float a0 = bf2f(ov[0]), a1 = bf2f(ov[1]), a2 = bf2f(ov[2]), a3 = bf2f(ov[3]);
    int e = e0;
    for (; e + 4 <= e1; e += 4) {
      int s0 = adj[e], s1 = adj[e + 1], s2 = adj[e + 2], s3 = adj[e + 3];
      us4 v0 = *(const us4*)(Xb + (size_t)s0 * C + lane * 4);
      us4 v1 = *(const us4*)(Xb + (size_t)s1 * C + lane * 4);
      us4 v2 = *(const us4*)(Xb + (size_t)s2 * C + lane * 4);
      us4 v3 = *(const us4*)(Xb + (size_t)s3 * C + lane * 4);
      a0 += (bf2f(v0[0]) + bf2f(v1[0])) + (bf2f(v2[0]) + bf2f(v3[0]));
      a1 += (bf2f(v0[1]) + bf2f(v1[1])) + (bf2f(v2[1]) + bf2f(v3[1]));
      a2 += (bf2f(v0[2]) + bf2f(v1[2])) + (bf2f(v2[2]) + bf2f(v3[2]));
      a3 += (bf2f(v0[3]) + bf2f(v1[3])) + (bf2f(v2[3]) + bf2f(v3[3]));
    }
    for (; e < e1; ++e) {
      us4 v = *(const us4*)(Xb + (size_t)adj[e] * C + lane * 4);
      a0 += bf2f(v[0]); a1 += bf2f(v[1]); a2 += bf2f(v[2]); a3 += bf2f(v[3]);
    }
    us4 hv;
    hv[0] = f2bf(a0); hv[1] = f2bf(a1); hv[2] = f2bf(a2); hv[3] = f2bf(a3);
    size_t oi = (size_t)node * 256 + ((lane >> 3) << 5) +
                ((((lane >> 1) & 3) ^ swv(node)) << 3) + ((lane & 1) << 2);
    *(us4*)(Hb + oi) = hv;
  } else {  // C == 128
    ushort2 ov = *(const ushort2*)(Xb + (size_t)node * C + lane * 2);
    float a0 = bf2f(ov.x), a1 = bf2f(ov.y);
    int e = e0;
    for (; e + 4 <= e1; e += 4) {
      int s0 = adj[e], s1 = adj[e + 1], s2 = adj[e + 2], s3 = adj[e + 3];
      ushort2 v0 = *(const ushort2*)(Xb + (size_t)s0 * C + lane * 2);
      ushort2 v1 = *(const ushort2*)(Xb + (size_t)s1 * C + lane * 2);
      ushort2 v2 = *(const ushort2*)(Xb + (size_t)s2 * C + lane * 2);
      ushort2 v3 = *(const ushort2*)(Xb + (size_t)s3 * C + lane * 2);
      a0 += (bf2f(v0.x) + bf2f(v1.x)) + (bf2f(v2.x) + bf2f(v3.x));
      a1 += (bf2f(v0.y) + bf2f(v1.y)) + (bf2f(v2.y) + bf2f(v3.y));
    }
    for (; e < e1; ++e) {
      ushort2 v = *(const ushort2*)(Xb + (size_t)adj[e] * C + lane * 2);
      a0 += bf2f(v.x); a1 += bf2f(v.y);
    }
    ushort2 hv = {f2bf(a0), f2bf(a1)};
    size_t oi = (size_t)node * 128 + ((lane >> 4) << 5) +
                ((((lane >> 2) & 3) ^ swv(node)) << 3) + ((lane & 3) << 1);
    *(ushort2*)(Hb + oi) = hv;
  }
}

// ------------ MFMA GEMM: 64x128 tile, BK=32 ------------
// FULL=false (main): 1-product bf16 x bf16; A = single bf16 array (AHb,
//   swizzled) via gload16, or (ASRC=2) bf16 z reg-staged + BN+relu (T14
//   prefetch). LDS 12KB.
// FULL=true (heads): 3-product split (AHi/ALo presplit+swizzled), LDS 24KB.
// EPI: 0 none, 1 relu, 2 tanh, 3 relu(tanh). OBF16: bf16 out (z / act).
// OSPLIT: split+swizzled out (head1, relu). STATS: fused BN sum/sumsq
// (from f32 accumulators). XSWZ: XCD-pair swizzle.
template <int EPI, bool STATS, bool OSPLIT, bool XSWZ, int ASRC, bool FULL, bool OBF16>
__global__ __launch_bounds__(256) void k_gemm(
    const unsigned short* __restrict__ AHb, const unsigned short* __restrict__ ALo,
    const unsigned short* __restrict__ Zb,
    int M, int K, int Nld, int mb, int per,
    const unsigned short* __restrict__ WHi, const unsigned short* __restrict__ WLo,
    const float* __restrict__ bias,
    const float* __restrict__ statsIn, const float* __restrict__ gvec,
    const float* __restrict__ bevec,
    float* __restrict__ Out, unsigned short* __restrict__ OutB,
    unsigned short* __restrict__ OHi, unsigned short* __restrict__ OLo,
    float* __restrict__ statsOut) {
  __shared__ unsigned short aHi[2048], bHi[4096];
  __shared__ unsigned short aLo[FULL ? 2048 : 64], bLo[FULL ? 4096 : 64];
  __shared__ float sBNsc[ASRC == 2 ? 256 : 1], sBNsh[ASRC == 2 ? 256 : 1];
  int bx, by;
  if constexpr (XSWZ) {
    int xcd = blockIdx.x & 7, slot = blockIdx.x >> 3;
    bx = xcd * per + (slot >> 1);
    by = slot & 1;
    if (bx >= mb) return;
  } else {
    bx = blockIdx.x;
    by = blockIdx.y;
  }
  const int tid = threadIdx.x;
  const int lane = tid & 63, w = tid >> 6;
  const int wm = w >> 1, wn = w & 1;
  const int m0 = bx * 64, n0 = by * 128;

  if constexpr (ASRC == 2) {
    float mu = statsIn[tid] / (float)M;
    float var = statsIn[256 + tid] / (float)M - mu * mu;
    float sc = gvec[tid] * rsqrtf(var + 1e-5f);
    sBNsc[tid] = sc;
    sBNsh[tid] = bevec[tid] - mu * sc;
  }

  f32x4 zero = {0.f, 0.f, 0.f, 0.f};
  f32x4 acc[2][4];
#pragma unroll
  for (int i = 0; i < 2; ++i)
#pragma unroll
    for (int j = 0; j < 4; ++j) acc[i][j] = zero;

  const int rq = lane >> 2;     // 0..15
  const int k8s = lane & 3;     // 16B slot

  // T14 prefetch regs for ASRC==2: one us8 (8 bf16 z) per thread
  us8 zr;
  const unsigned short* zbase0 = nullptr;
  if constexpr (ASRC == 2) {
    int row0 = tid >> 2, gq0 = tid & 3;          // row0 0..63
    int ra0 = m0 + row0; if (ra0 >= M) ra0 = M - 1;
    zbase0 = Zb + (size_t)ra0 * K + gq0 * 8;
    zr = *(const us8*)(zbase0);
  }

  for (int kb = 0; kb < K; kb += 32) {
    __syncthreads();
    if constexpr (ASRC == 2) {
      // consume prefetched z: BN+relu -> bf16 -> swizzled ds_write
      int row = tid >> 2, gq = tid & 3;
      us8 hv;
#pragma unroll
      for (int jj = 0; jj < 8; ++jj) {
        int kc = kb + gq * 8 + jj;
        float o = fmaxf(bf2f(zr[jj]) * sBNsc[kc] + sBNsh[kc], 0.f);
        hv[jj] = f2bf(o);
      }
      int bo = row * 64 + ((gq ^ swv(row)) << 4);
      *(us8*)((char*)aHi + bo) = hv;
#pragma unroll
      for (int q = 0; q < 2; ++q) {
        int rloc = (w << 5) + (q << 4) + rq;
        size_t gb = (size_t)(n0 + rloc) * K + kb + k8s * 8;
        unsigned bo2 = (w << 11) + (q << 10);
        gload16(WHi + gb, (char*)bHi + bo2);
      }
    } else {
      // A: 64 rows x 32k bf16 = one gload16 round (wave w rows [16w,16w+16))
      int raA = m0 + (w << 4) + rq; if (raA >= M) raA = M - 1;
      size_t ga = (size_t)raA * K + kb + k8s * 8;   // swizzles cancel -> linear
      gload16(AHb + ga, (char*)aHi + (w << 10));
      if constexpr (FULL) gload16(ALo + ga, (char*)aLo + (w << 10));
      // B: 128 rows -- two rounds
#pragma unroll
      for (int q = 0; q < 2; ++q) {
        int rloc = (w << 5) + (q << 4) + rq;
        size_t gb = (size_t)(n0 + rloc) * K + kb + k8s * 8;
        unsigned bo2 = (w << 11) + (q << 10);
        gload16(WHi + gb, (char*)bHi + bo2);
        if constexpr (FULL) gload16(WLo + gb, (char*)bLo + bo2);
      }
    }
    __syncthreads();

    // T14: issue next tile's z loads under the MFMAs
    if constexpr (ASRC == 2) {
      if (kb + 32 < K) zr = *(const us8*)(zbase0 + kb + 32);
    }

    const int j = lane >> 4;
    short8 bh[4], bl[4];
#pragma unroll
    for (int ni = 0; ni < 4; ++ni) {
      int r = wn * 64 + ni * 16 + (lane & 15);
      int bo = r * 64 + ((j ^ swv(r)) << 4);
      bh[ni] = *(const short8*)((const char*)bHi + bo);
      if constexpr (FULL) bl[ni] = *(const short8*)((const char*)bLo + bo);
    }
#pragma unroll
    for (int mi = 0; mi < 2; ++mi) {
      int r = wm * 32 + mi * 16 + (lane & 15);
      int bo = r * 64 + ((j ^ swv(r)) << 4);
      short8 ah = *(const short8*)((const char*)aHi + bo);
#pragma unroll
      for (int ni = 0; ni < 4; ++ni) {
        acc[mi][ni] = __builtin_amdgcn_mfma_f32_16x16x32_bf16(ah, bh[ni], acc[mi][ni], 0, 0, 0);
        if constexpr (FULL) {
          short8 al = *(const short8*)((const char*)aLo + bo);
          acc[mi][ni] = __builtin_amdgcn_mfma_f32_16x16x32_bf16(ah, bl[ni], acc[mi][ni], 0, 0, 0);
          acc[mi][ni] = __builtin_amdgcn_mfma_f32_16x16x32_bf16(al, bh[ni], acc[mi][ni], 0, 0, 0);
        }
      }
    }
  }

  // epilogue: C/D layout col = lane&15, row = (lane>>4)*4 + r   [m89-verified]
#pragma unroll
  for (int ni = 0; ni < 4; ++ni) {
    int col = n0 + wn * 64 + ni * 16 + (lane & 15);
    float bc = bias[col];
    float s = 0.f, q = 0.f;
#pragma unroll
    for (int mi = 0; mi < 2; ++mi) {
      int rbase = m0 + wm * 32 + mi * 16 + (lane >> 4) * 4;
#pragma unroll
      for (int r = 0; r < 4; ++r) {
        int row = rbase + r;
        if (row < M) {
          float o = acc[mi][ni][r] + bc;
          if (STATS) { s += o; q += o * o; }
          if (OSPLIT) {
            o = fmaxf(o, 0.f);   // relu (head1)
            unsigned short h = f2bf(o);
            size_t oi = swz4_idx(row, col, Nld);
            OHi[oi] = h;
            OLo[oi] = f2bf(o - bf2f(h));
          } else {
            if (EPI == 1) o = fmaxf(o, 0.f);
            else if (EPI == 2) o = tanhf(o);
            else if (EPI == 3) o = fmaxf(tanhf(o), 0.f);
            if (OBF16) OutB[(size_t)row * Nld + col] = f2bf(o);
            else       Out[(size_t)row * Nld + col] = o;
          }
        }
      }
    }
    if (STATS) {
      s += __shfl_xor(s, 16); s += __shfl_xor(s, 32);
      q += __shfl_xor(q, 16); q += __shfl_xor(q, 32);
      if ((lane >> 4) == 0) {
        atomicAdd(&statsOut[col], s);
        atomicAdd(&statsOut[256 + col], q);
      }
    }
  }
}

// ---------------- pooling (bf16 input, split output for heads) ----------------
__global__ __launch_bounds__(256) void k_pool(const unsigned short* __restrict__ Hb,
                                              const int* __restrict__ gs,
                                              const int* __restrict__ ge,
                                              unsigned short* __restrict__ PHi,
                                              unsigned short* __restrict__ PLo) {
  __shared__ float4 red[4][64];
  int gi = blockIdx.x;
  int s = gs[gi], e = ge[gi];
  int w = threadIdx.x >> 6, lane = threadIdx.x & 63;
  float4 acc = {0.f, 0.f, 0.f, 0.f};
  for (int r = s + w; r < e; r += 4) {
    us4 v = *(const us4*)(Hb + (size_t)r * 256 + lane * 4);
    acc.x += bf2f(v[0]); acc.y += bf2f(v[1]);
    acc.z += bf2f(v[2]); acc.w += bf2f(v[3]);
  }
  red[w][lane] = acc;
  __syncthreads();
  if (w == 0) {
    float4 a = red[0][lane], b = red[1][lane], c = red[2][lane], d = red[3][lane];
    float inv = 1.0f / fmaxf((float)(e - s), 1.0f);
    float vv[4] = {(a.x + b.x + c.x + d.x) * inv, (a.y + b.y + c.y + d.y) * inv,
                   (a.z + b.z + c.z + d.z) * inv, (a.w + b.w + c.w + d.w) * inv};
    us4 hv, lv;
#pragma unroll
    for (int j = 0; j < 4; ++j) {
      unsigned short h = f2bf(vv[j]);
      hv[j] = h;
      lv[j] = f2bf(vv[j] - bf2f(h));
    }
    size_t oi = (size_t)gi * 256 + ((lane >> 3) << 5) +
                ((((lane >> 1) & 3) ^ swv(gi)) << 3) + ((lane & 1) << 2);
    *(us4*)(PHi + oi) = hv;
    *(us4*)(PLo + oi) = lv;
  }
}

// ---------------------------------------------------------------------------
extern "C" void kernel_launch(void* const* d_in, const int* in_sizes, int n_in,
                              void* d_out, int out_size, void* d_ws, size_t ws_size,
                              hipStream_t stream) {
  const float* x      = (const float*)d_in[0];
  const int* ei       = (const int*)d_in[1];    // int32 from harness
  const int* bat      = (const int*)d_in[2];    // int32 from harness
  const float* w1a = (const float*)d_in[3];  const float* b1a = (const float*)d_in[4];
  const float* g1  = (const float*)d_in[5];  const float* be1 = (const float*)d_in[6];
  const float* w1b = (const float*)d_in[7];  const float* b1b = (const float*)d_in[8];
  const float* w2a = (const float*)d_in[9];  const float* b2a = (const float*)d_in[10];
  const float* g2  = (const float*)d_in[11]; const float* be2 = (const float*)d_in[12];
  const float* w2b = (const float*)d_in[13]; const float* b2b = (const float*)d_in[14];
  const float* w3a = (const float*)d_in[15]; const float* b3a = (const float*)d_in[16];
  const float* g3  = (const float*)d_in[17]; const float* be3 = (const float*)d_in[18];
  const float* w3b = (const float*)d_in[19]; const float* b3b = (const float*)d_in[20];
  const float* wh1 = (const float*)d_in[21]; const float* bh1 = (const float*)d_in[22];
  const float* wh2 = (const float*)d_in[23]; const float* bh2 = (const float*)d_in[24];
  float* out = (float*)d_out;

  const int N = in_sizes[0] / 128;   // 50000
  const int E = in_sizes[1] / 2;     // 800000
  const int G = 512;

  // ---- workspace: 3 bf16 buffers (h swz | z | act) + bf16 x ----
  char* ws = (char*)d_ws;
  size_t off = 0;
  auto alloc = [&](size_t bytes) {
    void* p = ws + off;
    off = (off + bytes + 255) & ~(size_t)255;
    return p;
  };
  unsigned short* hb = (unsigned short*)alloc((size_t)N * 256 * 2);
  unsigned short* zb = (unsigned short*)alloc((size_t)N * 256 * 2);
  unsigned short* ab = (unsigned short*)alloc((size_t)N * 256 * 2);
  unsigned short* xb = (unsigned short*)alloc((size_t)N * 128 * 2);
  int* adj     = (int*)alloc((size_t)E * 4);
  int* rowptr  = (int*)alloc((size_t)(N + 1) * 4);
  int* cursor  = (int*)alloc((size_t)N * 4);
  int* deg     = (int*)alloc((size_t)N * 4);
  int* partial = (int*)alloc((size_t)N * 4);
  int* bsum    = (int*)alloc(64 * 4);
  unsigned short* wHi = (unsigned short*)alloc(884736 * 2);
  unsigned short* wLo = (unsigned short*)alloc(884736 * 2);
  float* stats = (float*)alloc(512 * 4);
  int* gs      = (int*)alloc(G * 4);
  int* ge      = (int*)alloc(G * 4);
  unsigned short* poolHi = (unsigned short*)alloc((size_t)G * 256 * 2);
  unsigned short* poolLo = (unsigned short*)alloc((size_t)G * 256 * 2);
  unsigned short* thidHi = (unsigned short*)alloc((size_t)G * 512 * 2);
  unsigned short* thidLo = (unsigned short*)alloc((size_t)G * 512 * 2);

  // transposed-weight element offsets (match k_prep_all segment table)
  const int o1a = 0, o1b = 32768, o2a = 98304, o2b = 163840, o3a = 229376, o3b = 294912;
  const int oh1 = 360448, oh2 = 491520;   // ends at 884736

  hipMemsetAsync(deg, 0, (size_t)N * 4, stream);
  hipMemsetAsync(gs, 0, (size_t)G * 4, stream);
  hipMemsetAsync(ge, 0, (size_t)G * 4, stream);

  int eb = (E + 255) / 256;
  int nbN = (N + 255) / 256;
  int nb1 = (N + 1023) >> 10;   // 49 (<=64 required by k_scan2)
  k_histbounds<<<eb + nbN, 256, 0, stream>>>(ei, deg, E, eb, bat, gs, ge, N);
  k_scan1<<<nb1, 1024, 0, stream>>>(deg, partial, bsum, N);
  k_scan2<<<1, 64, 0, stream>>>(bsum, nb1);
  k_scan3<<<nbN, 256, 0, stream>>>(deg, partial, bsum, rowptr, cursor, N);
  k_fill<<<eb, 256, 0, stream>>>(ei, cursor, adj, E);

  k_xbf<<<(N * 128 / 8 + 255) / 256, 256, 0, stream>>>(x, xb, N * 128);
  k_prep_all<<<3456, 256, 0, stream>>>(w1a, w1b, w2a, w2b, w3a, w3b, wh1, wh2, wHi, wLo);

  int nb4 = (N + 3) / 4;
  const int mb = (N + 63) / 64;          // 782 M-tiles of 64 rows
  const int per = (mb + 7) / 8;          // 98
  dim3 gg(per * 16);                     // XCD-pair swizzled flat grid (1568)

  // ---- layer 1: xb -> h@hb -> z@zb -> act@ab ----
  k_agg<128><<<nb4, 256, 0, stream>>>(xb, hb, rowptr, adj, N, stats);
  k_gemm<0, true, false, true, 0, false, true><<<gg, 256, 0, stream>>>(
      hb, nullptr, nullptr, N, 128, 256, mb, per, wHi + o1a, wLo + o1a, b1a,
      nullptr, nullptr, nullptr, nullptr, zb, nullptr, nullptr, stats);
  k_gemm<1, false, false, true, 2, false, true><<<gg, 256, 0, stream>>>(
      nullptr, nullptr, zb, N, 256, 256, mb, per, wHi + o1b, wLo + o1b, b1b,
      stats, g1, be1, nullptr, ab, nullptr, nullptr, nullptr);

  // ---- layer 2: act@ab -> h@hb -> z@zb -> act@ab ----
  k_agg<256><<<nb4, 256, 0, stream>>>(ab, hb, rowptr, adj, N, stats);
  k_gemm<0, true, false, true, 0, false, true><<<gg, 256, 0, stream>>>(
      hb, nullptr, nullptr, N, 256, 256, mb, per, wHi + o2a, wLo + o2a, b2a,
      nullptr, nullptr, nullptr, nullptr, zb, nullptr, nullptr, stats);
  k_gemm<3, false, false, true, 2, false, true><<<gg, 256, 0, stream>>>(
      nullptr, nullptr, zb, N, 256, 256, mb, per, wHi + o2b, wLo + o2b, b2b,
      stats, g2, be2, nullptr, ab, nullptr, nullptr, nullptr);

  // ---- layer 3: act@ab -> h@hb -> z@zb -> act@ab ----
  k_agg<256><<<nb4, 256, 0, stream>>>(ab, hb, rowptr, adj, N, stats);
  k_gemm<0, true, false, true, 0, false, true><<<gg, 256, 0, stream>>>(
      hb, nullptr, nullptr, N, 256, 256, mb, per, wHi + o3a, wLo + o3a, b3a,
      nullptr, nullptr, nullptr, nullptr, zb, nullptr, nullptr, stats);
  k_gemm<2, false, false, true, 2, false, true><<<gg, 256, 0, stream>>>(
      nullptr, nullptr, zb, N, 256, 256, mb, per, wHi + o3b, wLo + o3b, b3b,
      stats, g3, be3, nullptr, ab, nullptr, nullptr, nullptr);

  // ---- pool + MFMA heads (heads keep FULL 3-product split) ----
  k_pool<<<G, 256, 0, stream>>>(ab, gs, ge, poolHi, poolLo);
  dim3 gh1(8, 4);   // M=512/64 tiles, N=512/128 col-halves
  k_gemm<1, false, true, false, 0, true, false><<<gh1, 256, 0, stream>>>(
      poolHi, poolLo, nullptr, G, 256, 512, 0, 0, wHi + oh1, wLo + oh1, bh1,
      nullptr, nullptr, nullptr, nullptr, nullptr, thidHi, thidLo, nullptr);
  dim3 gh2(8, 6);   // M=512/64 tiles, N=768/128 col-halves
  k_gemm<0, false, false, false, 0, true, false><<<gh2, 256, 0, stream>>>(
      thidHi, thidLo, nullptr, G, 512, 768, 0, 0, wHi + oh2, wLo + oh2, bh2,
      nullptr, nullptr, nullptr, out, nullptr, nullptr, nullptr, nullptr);
}

// Round 18
// 581.460 us; speedup vs baseline: 1.6064x; 1.0359x over previous
//
#include <hip/hip_runtime.h>

// ---------------------------------------------------------------------------
// GIN GraphEncoder on MI355X.
// R18: BK=64 (was 32) -- GEMM dur was invariant (~65us) across halved VALU,
// doubled blocks, halved bytes => limiter is the per-K-iteration barrier
// latency (3.2K cyc/slot vs 600 content). Halve the iteration count.
// LDS 24KB (A 8K + B 16K bf16), 8-slot swizzle sw8(r)=(r&7)^((r>>3)&7)
// (2-way free on fragment reads; producers match; staging stays linear).
// R17: plain-bf16 main path (1-product bf16xbf16 MFMA, f32 stats).
// Heads keep full 3-product split. T14 z-prefetch in gemmB. XCD-pair swizzle.
// Ledger: BN-fusion -56, 2-product -17, bf16-gather -120, T14 -21,
// 64x128 tile -37, plain-bf16 -15 (bytes halved but GEMM latency-pinned).
// ---------------------------------------------------------------------------

typedef __attribute__((ext_vector_type(8))) short short8;   // 8 bf16 for MFMA
typedef __attribute__((ext_vector_type(4))) float f32x4;
typedef __attribute__((ext_vector_type(4))) unsigned short us4;
typedef __attribute__((ext_vector_type(8))) unsigned short us8;

__device__ __forceinline__ unsigned short f2bf(float f) {
  unsigned int b = __float_as_uint(f);
  unsigned int r = 0x7FFFu + ((b >> 16) & 1u);   // round-to-nearest-even
  return (unsigned short)((b + r) >> 16);
}
__device__ __forceinline__ float bf2f(unsigned short u) {
  return __uint_as_float(((unsigned int)u) << 16);
}

// bank-spread row swizzle (8-slot domain; LDS rows are 128B = bank space)
__device__ __forceinline__ int sw8(int row) {
  return (row & 7) ^ ((row >> 3) & 7);
}

// global->LDS 16B async copy; LDS dest is wave-uniform base (HW adds lane*16)
typedef const __attribute__((address_space(1))) unsigned int* gas1;
typedef __attribute__((address_space(3))) unsigned int* las3;
__device__ __forceinline__ void gload16(const void* g, void* l) {
  __builtin_amdgcn_global_load_lds((gas1)g, (las3)l, 16, 0, 0);
}

// swizzled flat index of element (row, k), row length K:
// 16B groups XORed within each 64-elem (8-group) block: g' = g ^ sw8(row)
__device__ __forceinline__ size_t swz8_idx(int row, int k, int K) {
  int g = k >> 3;
  return (size_t)row * K + ((g >> 3) << 6) + ((((g & 7) ^ sw8(row)) << 3)) + (k & 7);
}

// ---------------- CSR build + graph bounds (fused) ----------------
__global__ void k_histbounds(const int* __restrict__ ei, int* __restrict__ deg, int E,
                             int eb, const int* __restrict__ batch,
                             int* __restrict__ gs, int* __restrict__ ge, int N) {
  int b = blockIdx.x;
  if (b < eb) {
    int e = b * 256 + threadIdx.x;
    if (e < E) atomicAdd(&deg[ei[E + e]], 1);
  } else {
    int i = (b - eb) * 256 + threadIdx.x;
    if (i < N) {
      int bb = batch[i];
      if (i == 0 || batch[i - 1] != bb) gs[bb] = i;
      if (i == N - 1 || batch[i + 1] != bb) ge[bb] = i + 1;
    }
  }
}

__global__ __launch_bounds__(1024) void k_scan1(const int* __restrict__ deg,
                                                int* __restrict__ partial,
                                                int* __restrict__ bsum, int N) {
  __shared__ int sd[1024];
  int tid = threadIdx.x;
  int i = blockIdx.x * 1024 + tid;
  int v = (i < N) ? deg[i] : 0;
  sd[tid] = v;
  __syncthreads();
  for (int off = 1; off < 1024; off <<= 1) {
    int t = (tid >= off) ? sd[tid - off] : 0;
    __syncthreads();
    sd[tid] += t;
    __syncthreads();
  }
  if (i < N) partial[i] = sd[tid];
  if (tid == 1023) bsum[blockIdx.x] = sd[1023];
}

__global__ void k_scan2(int* __restrict__ bsum, int nb) {
  int l = threadIdx.x;
  int orig = (l < nb) ? bsum[l] : 0;
  int v = orig;
  for (int off = 1; off < 64; off <<= 1) {
    int t = __shfl_up(v, off);
    if (l >= off) v += t;
  }
  if (l < nb) bsum[l] = v - orig;
}

__global__ void k_scan3(const int* __restrict__ deg, const int* __restrict__ partial,
                        const int* __restrict__ bsum, int* __restrict__ rowptr,
                        int* __restrict__ cursor, int N) {
  int i = blockIdx.x * 256 + threadIdx.x;
  if (i >= N) return;
  int incl = partial[i] + bsum[i >> 10];
  rowptr[i + 1] = incl;
  cursor[i] = incl - deg[i];
  if (i == 0) rowptr[0] = 0;
}

__global__ void k_fill(const int* __restrict__ ei, int* __restrict__ cursor,
                       int* __restrict__ adj, int E) {
  int e = blockIdx.x * 256 + threadIdx.x;
  if (e >= E) return;
  int s = ei[e];
  int d = ei[E + e];
  int pos = atomicAdd(&cursor[d], 1);
  adj[pos] = s;
}

// ---- x f32 -> bf16 (one-time; feeds layer-1 gather) ----
__global__ void k_xbf(const float* __restrict__ X, unsigned short* __restrict__ Xb,
                      int total) {
  int t = blockIdx.x * 256 + threadIdx.x;   // one 8-elem group
  if (t * 8 >= total) return;
  const float4 v0 = *(const float4*)(X + t * 8);
  const float4 v1 = *(const float4*)(X + t * 8 + 4);
  us8 o;
  o[0] = f2bf(v0.x); o[1] = f2bf(v0.y); o[2] = f2bf(v0.z); o[3] = f2bf(v0.w);
  o[4] = f2bf(v1.x); o[5] = f2bf(v1.y); o[6] = f2bf(v1.z); o[7] = f2bf(v1.w);
  *(us8*)(Xb + t * 8) = o;
}

// ---- ALL weights: transpose + split + swizzle in ONE kernel ----
__global__ void k_prep_all(const float* __restrict__ w1a, const float* __restrict__ w1b,
                           const float* __restrict__ w2a, const float* __restrict__ w2b,
                           const float* __restrict__ w3a, const float* __restrict__ w3b,
                           const float* __restrict__ wh1, const float* __restrict__ wh2,
                           unsigned short* __restrict__ Hi, unsigned short* __restrict__ Lo) {
  int idx = blockIdx.x * 256 + threadIdx.x;   // [0, 884736)
  const float* W; int K, Nout, lo_;
  if (idx < 32768)       { W = w1a; K = 128; Nout = 256; lo_ = 0; }
  else if (idx < 98304)  { W = w1b; K = 256; Nout = 256; lo_ = 32768; }
  else if (idx < 163840) { W = w2a; K = 256; Nout = 256; lo_ = 98304; }
  else if (idx < 229376) { W = w2b; K = 256; Nout = 256; lo_ = 163840; }
  else if (idx < 294912) { W = w3a; K = 256; Nout = 256; lo_ = 229376; }
  else if (idx < 360448) { W = w3b; K = 256; Nout = 256; lo_ = 294912; }
  else if (idx < 491520) { W = wh1; K = 256; Nout = 512; lo_ = 360448; }
  else                   { W = wh2; K = 512; Nout = 768; lo_ = 491520; }
  int li = idx - lo_;
  int n = li % Nout, k = li / Nout;
  float w = W[k * Nout + n];
  unsigned short h = f2bf(w);
  size_t oi = (size_t)lo_ + swz8_idx(n, k, K);
  Hi[oi] = h;
  Lo[oi] = f2bf(w - bf2f(h));   // only heads read Lo
}

// -------- aggregation: h = Xb[i] + sum Xb[adj[e]] (bf16 gather, f32 acc) ----
// Writes h as single bf16, sw8-swizzled. Block 0 zeroes stats[].
template <int C>
__global__ __launch_bounds__(256) void k_agg(const unsigned short* __restrict__ Xb,
                                             unsigned short* __restrict__ Hb,
                                             const int* __restrict__ rowptr,
                                             const int* __restrict__ adj, int N,
                                             float* __restrict__ statsZ) {
  if (blockIdx.x == 0) {
    statsZ[threadIdx.x] = 0.f;
    statsZ[256 + threadIdx.x] = 0.f;
  }
  int node = blockIdx.x * 4 + (threadIdx.x >> 6);
  if (node >= N) return;
  int lane = threadIdx.x & 63;
  int e0 = rowptr[node], e1 = rowptr[node + 1];
  if constexpr (C == 256) {
    us4 ov = *(const us4*)(Xb + (size_t)node * C + lane * 4);
    float a0 = bf2f(ov[0]), a1 = bf2f(ov[1]), a2 = bf2f(ov[2]), a3 = bf2f(ov[3]);
    int e = e0;
    for (; e + 4 <= e1; e += 4) {
      int s0 = adj[e], s1 = adj[e + 1], s2 = adj[e + 2], s3 = adj[e + 3];
      us4 v0 = *(const us4*)(Xb + (size_t)s0 * C + lane * 4);
      us4 v1 = *(const us4*)(Xb + (size_t)s1 * C + lane * 4);
      us4 v2 = *(const us4*)(Xb + (size_t)s2 * C + lane * 4);
      us4 v3 = *(const us4*)(Xb + (size_t)s3 * C + lane * 4);
      a0 += (bf2f(v0[0]) + bf2f(v1[0])) + (bf2f(v2[0]) + bf2f(v3[0]));
      a1 += (bf2f(v0[1]) + bf2f(v1[1])) + (bf2f(v2[1]) + bf2f(v3[1]));
      a2 += (bf2f(v0[2]) + bf2f(v1[2])) + (bf2f(v2[2]) + bf2f(v3[2]));
      a3 += (bf2f(v0[3]) + bf2f(v1[3])) + (bf2f(v2[3]) + bf2f(v3[3]));
    }
    for (; e < e1; ++e) {
      us4 v = *(const us4*)(Xb + (size_t)adj[e] * C + lane * 4);
      a0 += bf2f(v[0]); a1 += bf2f(v[1]); a2 += bf2f(v[2]); a3 += bf2f(v[3]);
    }
    us4 hv;
    hv[0] = f2bf(a0); hv[1] = f2bf(a1); hv[2] = f2bf(a2); hv[3] = f2bf(a3);
    // lane covers cols lane*4..+3: group g = lane>>1 -> block lane>>4, ing (lane>>1)&7
    size_t oi = (size_t)node * 256 + ((lane >> 4) << 6) +
                ((((lane >> 1) & 7) ^ sw8(node)) << 3) + ((lane & 1) << 2);
    *(us4*)(Hb + oi) = hv;
  } else {  // C == 128
    ushort2 ov = *(const ushort2*)(Xb + (size_t)node * C + lane * 2);
    float a0 = bf2f(ov.x), a1 = bf2f(ov.y);
    int e = e0;
    for (; e + 4 <= e1; e += 4) {
      int s0 = adj[e], s1 = adj[e + 1], s2 = adj[e + 2], s3 = adj[e + 3];
      ushort2 v0 = *(const ushort2*)(Xb + (size_t)s0 * C + lane * 2);
      ushort2 v1 = *(const ushort2*)(Xb + (size_t)s1 * C + lane * 2);
      ushort2 v2 = *(const ushort2*)(Xb + (size_t)s2 * C + lane * 2);
      ushort2 v3 = *(const ushort2*)(Xb + (size_t)s3 * C + lane * 2);
      a0 += (bf2f(v0.x) + bf2f(v1.x)) + (bf2f(v2.x) + bf2f(v3.x));
      a1 += (bf2f(v0.y) + bf2f(v1.y)) + (bf2f(v2.y) + bf2f(v3.y));
    }
    for (; e < e1; ++e) {
      ushort2 v = *(const ushort2*)(Xb + (size_t)adj[e] * C + lane * 2);
      a0 += bf2f(v.x); a1 += bf2f(v.y);
    }
    ushort2 hv = {f2bf(a0), f2bf(a1)};
    // lane covers cols lane*2..+1: g = lane>>2 -> block lane>>5, ing (lane>>2)&7
    size_t oi = (size_t)node * 128 + ((lane >> 5) << 6) +
                ((((lane >> 2) & 7) ^ sw8(node)) << 3) + ((lane & 3) << 1);
    *(ushort2*)(Hb + oi) = hv;
  }
}

// ------------ MFMA GEMM: 64x128 tile, BK=64 (4 iters @K=256) ------------
// FULL=false (main): 1-product bf16 x bf16, LDS 24KB (A 8K + B 16K).
// FULL=true (heads): 3-product split, LDS 48KB.
// ASRC: 0 presplit gload16; 2 bf16 z reg-staged + BN+relu (T14 prefetch).
// EPI: 0 none, 1 relu, 2 tanh, 3 relu(tanh). OBF16: bf16 out (z / act).
// OSPLIT: split+swizzled out (head1, relu). STATS: fused BN sum/sumsq.
// XSWZ: XCD-pair swizzle.
template <int EPI, bool STATS, bool OSPLIT, bool XSWZ, int ASRC, bool FULL, bool OBF16>
__global__ __launch_bounds__(256) void k_gemm(
    const unsigned short* __restrict__ AHb, const unsigned short* __restrict__ ALo,
    const unsigned short* __restrict__ Zb,
    int M, int K, int Nld, int mb, int per,
    const unsigned short* __restrict__ WHi, const unsigned short* __restrict__ WLo,
    const float* __restrict__ bias,
    const float* __restrict__ statsIn, const float* __restrict__ gvec,
    const float* __restrict__ bevec,
    float* __restrict__ Out, unsigned short* __restrict__ OutB,
    unsigned short* __restrict__ OHi, unsigned short* __restrict__ OLo,
    float* __restrict__ statsOut) {
  __shared__ unsigned short aHi[4096], bHi[8192];             // 8K + 16K bytes
  __shared__ unsigned short aLo[FULL ? 4096 : 64], bLo[FULL ? 8192 : 64];
  __shared__ float sBNsc[ASRC == 2 ? 256 : 1], sBNsh[ASRC == 2 ? 256 : 1];
  int bx, by;
  if constexpr (XSWZ) {
    int xcd = blockIdx.x & 7, slot = blockIdx.x >> 3;
    bx = xcd * per + (slot >> 1);
    by = slot & 1;
    if (bx >= mb) return;
  } else {
    bx = blockIdx.x;
    by = blockIdx.y;
  }
  const int tid = threadIdx.x;
  const int lane = tid & 63, w = tid >> 6;
  const int wm = w >> 1, wn = w & 1;
  const int m0 = bx * 64, n0 = by * 128;

  if constexpr (ASRC == 2) {
    float mu = statsIn[tid] / (float)M;
    float var = statsIn[256 + tid] / (float)M - mu * mu;
    float sc = gvec[tid] * rsqrtf(var + 1e-5f);
    sBNsc[tid] = sc;
    sBNsh[tid] = bevec[tid] - mu * sc;
  }

  f32x4 zero = {0.f, 0.f, 0.f, 0.f};
  f32x4 acc[2][4];
#pragma unroll
  for (int i = 0; i < 2; ++i)
#pragma unroll
    for (int j = 0; j < 4; ++j) acc[i][j] = zero;

  const int l8 = lane >> 3;     // row sub-index in staging
  const int s8 = lane & 7;      // 16B slot in row (8 per 64-elem row)

  // T14 prefetch for ASRC==2: two tasks/thread (rows tid>>3 and 32+tid>>3)
  us8 zr0, zr1;
  const unsigned short* zb0 = nullptr;
  const unsigned short* zb1 = nullptr;
  if constexpr (ASRC == 2) {
    int r0 = tid >> 3, r1 = 32 + (tid >> 3);
    int ra0 = m0 + r0; if (ra0 >= M) ra0 = M - 1;
    int ra1 = m0 + r1; if (ra1 >= M) ra1 = M - 1;
    zb0 = Zb + (size_t)ra0 * K + (tid & 7) * 8;
    zb1 = Zb + (size_t)ra1 * K + (tid & 7) * 8;
    zr0 = *(const us8*)(zb0);
    zr1 = *(const us8*)(zb1);
  }

  for (int kb = 0; kb < K; kb += 64) {
    __syncthreads();
    if constexpr (ASRC == 2) {
      // consume prefetched z: BN+relu -> bf16 -> sw8 ds_write (2 tasks)
#pragma unroll
      for (int p = 0; p < 2; ++p) {
        int row = (p << 5) + (tid >> 3), gq = tid & 7;
        us8 zr = p ? zr1 : zr0;
        us8 hv;
#pragma unroll
        for (int jj = 0; jj < 8; ++jj) {
          int kc = kb + gq * 8 + jj;
          float o = fmaxf(bf2f(zr[jj]) * sBNsc[kc] + sBNsh[kc], 0.f);
          hv[jj] = f2bf(o);
        }
        int bo = row * 128 + ((gq ^ sw8(row)) << 4);
        *(us8*)((char*)aHi + bo) = hv;
      }
      // B: 128 rows x 64k bf16 = 1024 chunks = 4 gload16 rounds
#pragma unroll
      for (int q = 0; q < 4; ++q) {
        int row = (w << 5) + (q << 3) + l8;
        size_t gb = (size_t)(n0 + row) * K + kb + s8 * 8;
        unsigned bo2 = (w << 12) + (q << 10);
        gload16(WHi + gb, (char*)bHi + bo2);
      }
    } else {
      // A: 64 rows x 64k = 512 chunks = 2 rounds
#pragma unroll
      for (int q = 0; q < 2; ++q) {
        int row = (w << 4) + (q << 3) + l8;
        int ra = m0 + row; if (ra >= M) ra = M - 1;
        size_t ga = (size_t)ra * K + kb + s8 * 8;   // swizzles cancel -> linear
        unsigned boA = (w << 11) + (q << 10);
        gload16(AHb + ga, (char*)aHi + boA);
        if constexpr (FULL) gload16(ALo + ga, (char*)aLo + boA);
      }
      // B: 128 rows x 64k = 1024 chunks = 4 rounds
#pragma unroll
      for (int q = 0; q < 4; ++q) {
        int row = (w << 5) + (q << 3) + l8;
        size_t gb = (size_t)(n0 + row) * K + kb + s8 * 8;
        unsigned bo2 = (w << 12) + (q << 10);
        gload16(WHi + gb, (char*)bHi + bo2);
        if constexpr (FULL) gload16(WLo + gb, (char*)bLo + bo2);
      }
    }
    __syncthreads();

    // T14: issue next tile's z loads under the MFMAs
    if constexpr (ASRC == 2) {
      if (kb + 64 < K) {
        zr0 = *(const us8*)(zb0 + kb + 64);
        zr1 = *(const us8*)(zb1 + kb + 64);
      }
    }

    const int j = lane >> 4;
#pragma unroll
    for (int kk = 0; kk < 2; ++kk) {
      int g = (kk << 2) + j;        // 16B group within 64-elem row
      short8 bh[4], bl[4];
#pragma unroll
      for (int ni = 0; ni < 4; ++ni) {
        int r = wn * 64 + ni * 16 + (lane & 15);
        int bo = r * 128 + ((g ^ sw8(r)) << 4);
        bh[ni] = *(const short8*)((const char*)bHi + bo);
        if constexpr (FULL) bl[ni] = *(const short8*)((const char*)bLo + bo);
      }
#pragma unroll
      for (int mi = 0; mi < 2; ++mi) {
        int r = wm * 32 + mi * 16 + (lane & 15);
        int bo = r * 128 + ((g ^ sw8(r)) << 4);
        short8 ah = *(const short8*)((const char*)aHi + bo);
#pragma unroll
        for (int ni = 0; ni < 4; ++ni) {
          acc[mi][ni] = __builtin_amdgcn_mfma_f32_16x16x32_bf16(ah, bh[ni], acc[mi][ni], 0, 0, 0);
          if constexpr (FULL) {
            short8 al = *(const short8*)((const char*)aLo + bo);
            acc[mi][ni] = __builtin_amdgcn_mfma_f32_16x16x32_bf16(ah, bl[ni], acc[mi][ni], 0, 0, 0);
            acc[mi][ni] = __builtin_amdgcn_mfma_f32_16x16x32_bf16(al, bh[ni], acc[mi][ni], 0, 0, 0);
          }
        }
      }
    }
  }

  // epilogue: C/D layout col = lane&15, row = (lane>>4)*4 + r   [m89-verified]
#pragma unroll
  for (int ni = 0; ni < 4; ++ni) {
    int col = n0 + wn * 64 + ni * 16 + (lane & 15);
    float bc = bias[col];
    float s = 0.f, q = 0.f;
#pragma unroll
    for (int mi = 0; mi < 2; ++mi) {
      int rbase = m0 + wm * 32 + mi * 16 + (lane >> 4) * 4;
#pragma unroll
      for (int r = 0; r < 4; ++r) {
        int row = rbase + r;
        if (row < M) {
          float o = acc[mi][ni][r] + bc;
          if (STATS) { s += o; q += o * o; }
          if (OSPLIT) {
            o = fmaxf(o, 0.f);   // relu (head1)
            unsigned short h = f2bf(o);
            size_t oi = swz8_idx(row, col, Nld);
            OHi[oi] = h;
            OLo[oi] = f2bf(o - bf2f(h));
          } else {
            if (EPI == 1) o = fmaxf(o, 0.f);
            else if (EPI == 2) o = tanhf(o);
            else if (EPI == 3) o = fmaxf(tanhf(o), 0.f);
            if (OBF16) OutB[(size_t)row * Nld + col] = f2bf(o);
            else       Out[(size_t)row * Nld + col] = o;
          }
        }
      }
    }
    if (STATS) {
      s += __shfl_xor(s, 16); s += __shfl_xor(s, 32);
      q += __shfl_xor(q, 16); q += __shfl_xor(q, 32);
      if ((lane >> 4) == 0) {
        atomicAdd(&statsOut[col], s);
        atomicAdd(&statsOut[256 + col], q);
      }
    }
  }
}

// ---------------- pooling (bf16 input, split output for heads) ----------------
__global__ __launch_bounds__(256) void k_pool(const unsigned short* __restrict__ Hb,
                                              const int* __restrict__ gs,
                                              const int* __restrict__ ge,
                                              unsigned short* __restrict__ PHi,
                                              unsigned short* __restrict__ PLo) {
  __shared__ float4 red[4][64];
  int gi = blockIdx.x;
  int s = gs[gi], e = ge[gi];
  int w = threadIdx.x >> 6, lane = threadIdx.x & 63;
  float4 acc = {0.f, 0.f, 0.f, 0.f};
  for (int r = s + w; r < e; r += 4) {
    us4 v = *(const us4*)(Hb + (size_t)r * 256 + lane * 4);
    acc.x += bf2f(v[0]); acc.y += bf2f(v[1]);
    acc.z += bf2f(v[2]); acc.w += bf2f(v[3]);
  }
  red[w][lane] = acc;
  __syncthreads();
  if (w == 0) {
    float4 a = red[0][lane], b = red[1][lane], c = red[2][lane], d = red[3][lane];
    float inv = 1.0f / fmaxf((float)(e - s), 1.0f);
    float vv[4] = {(a.x + b.x + c.x + d.x) * inv, (a.y + b.y + c.y + d.y) * inv,
                   (a.z + b.z + c.z + d.z) * inv, (a.w + b.w + c.w + d.w) * inv};
    us4 hv, lv;
#pragma unroll
    for (int j = 0; j < 4; ++j) {
      unsigned short h = f2bf(vv[j]);
      hv[j] = h;
      lv[j] = f2bf(vv[j] - bf2f(h));
    }
    size_t oi = (size_t)gi * 256 + ((lane >> 4) << 6) +
                ((((lane >> 1) & 7) ^ sw8(gi)) << 3) + ((lane & 1) << 2);
    *(us4*)(PHi + oi) = hv;
    *(us4*)(PLo + oi) = lv;
  }
}

// ---------------------------------------------------------------------------
extern "C" void kernel_launch(void* const* d_in, const int* in_sizes, int n_in,
                              void* d_out, int out_size, void* d_ws, size_t ws_size,
                              hipStream_t stream) {
  const float* x      = (const float*)d_in[0];
  const int* ei       = (const int*)d_in[1];    // int32 from harness
  const int* bat      = (const int*)d_in[2];    // int32 from harness
  const float* w1a = (const float*)d_in[3];  const float* b1a = (const float*)d_in[4];
  const float* g1  = (const float*)d_in[5];  const float* be1 = (const float*)d_in[6];
  const float* w1b = (const float*)d_in[7];  const float* b1b = (const float*)d_in[8];
  const float* w2a = (const float*)d_in[9];  const float* b2a = (const float*)d_in[10];
  const float* g2  = (const float*)d_in[11]; const float* be2 = (const float*)d_in[12];
  const float* w2b = (const float*)d_in[13]; const float* b2b = (const float*)d_in[14];
  const float* w3a = (const float*)d_in[15]; const float* b3a = (const float*)d_in[16];
  const float* g3  = (const float*)d_in[17]; const float* be3 = (const float*)d_in[18];
  const float* w3b = (const float*)d_in[19]; const float* b3b = (const float*)d_in[20];
  const float* wh1 = (const float*)d_in[21]; const float* bh1 = (const float*)d_in[22];
  const float* wh2 = (const float*)d_in[23]; const float* bh2 = (const float*)d_in[24];
  float* out = (float*)d_out;

  const int N = in_sizes[0] / 128;   // 50000
  const int E = in_sizes[1] / 2;     // 800000
  const int G = 512;

  // ---- workspace: 3 bf16 buffers (h swz | z | act) + bf16 x ----
  char* ws = (char*)d_ws;
  size_t off = 0;
  auto alloc = [&](size_t bytes) {
    void* p = ws + off;
    off = (off + bytes + 255) & ~(size_t)255;
    return p;
  };
  unsigned short* hb = (unsigned short*)alloc((size_t)N * 256 * 2);
  unsigned short* zb = (unsigned short*)alloc((size_t)N * 256 * 2);
  unsigned short* ab = (unsigned short*)alloc((size_t)N * 256 * 2);
  unsigned short* xb = (unsigned short*)alloc((size_t)N * 128 * 2);
  int* adj     = (int*)alloc((size_t)E * 4);
  int* rowptr  = (int*)alloc((size_t)(N + 1) * 4);
  int* cursor  = (int*)alloc((size_t)N * 4);
  int* deg     = (int*)alloc((size_t)N * 4);
  int* partial = (int*)alloc((size_t)N * 4);
  int* bsum    = (int*)alloc(64 * 4);
  unsigned short* wHi = (unsigned short*)alloc(884736 * 2);
  unsigned short* wLo = (unsigned short*)alloc(884736 * 2);
  float* stats = (float*)alloc(512 * 4);
  int* gs      = (int*)alloc(G * 4);
  int* ge      = (int*)alloc(G * 4);
  unsigned short* poolHi = (unsigned short*)alloc((size_t)G * 256 * 2);
  unsigned short* poolLo = (unsigned short*)alloc((size_t)G * 256 * 2);
  unsigned short* thidHi = (unsigned short*)alloc((size_t)G * 512 * 2);
  unsigned short* thidLo = (unsigned short*)alloc((size_t)G * 512 * 2);

  // transposed-weight element offsets (match k_prep_all segment table)
  const int o1a = 0, o1b = 32768, o2a = 98304, o2b = 163840, o3a = 229376, o3b = 294912;
  const int oh1 = 360448, oh2 = 491520;   // ends at 884736

  hipMemsetAsync(deg, 0, (size_t)N * 4, stream);
  hipMemsetAsync(gs, 0, (size_t)G * 4, stream);
  hipMemsetAsync(ge, 0, (size_t)G * 4, stream);

  int eb = (E + 255) / 256;
  int nbN = (N + 255) / 256;
  int nb1 = (N + 1023) >> 10;   // 49 (<=64 required by k_scan2)
  k_histbounds<<<eb + nbN, 256, 0, stream>>>(ei, deg, E, eb, bat, gs, ge, N);
  k_scan1<<<nb1, 1024, 0, stream>>>(deg, partial, bsum, N);
  k_scan2<<<1, 64, 0, stream>>>(bsum, nb1);
  k_scan3<<<nbN, 256, 0, stream>>>(deg, partial, bsum, rowptr, cursor, N);
  k_fill<<<eb, 256, 0, stream>>>(ei, cursor, adj, E);

  k_xbf<<<(N * 128 / 8 + 255) / 256, 256, 0, stream>>>(x, xb, N * 128);
  k_prep_all<<<3456, 256, 0, stream>>>(w1a, w1b, w2a, w2b, w3a, w3b, wh1, wh2, wHi, wLo);

  int nb4 = (N + 3) / 4;
  const int mb = (N + 63) / 64;          // 782 M-tiles of 64 rows
  const int per = (mb + 7) / 8;          // 98
  dim3 gg(per * 16);                     // XCD-pair swizzled flat grid (1568)

  // ---- layer 1: xb -> h@hb -> z@zb -> act@ab ----
  k_agg<128><<<nb4, 256, 0, stream>>>(xb, hb, rowptr, adj, N, stats);
  k_gemm<0, true, false, true, 0, false, true><<<gg, 256, 0, stream>>>(
      hb, nullptr, nullptr, N, 128, 256, mb, per, wHi + o1a, wLo + o1a, b1a,
      nullptr, nullptr, nullptr, nullptr, zb, nullptr, nullptr, stats);
  k_gemm<1, false, false, true, 2, false, true><<<gg, 256, 0, stream>>>(
      nullptr, nullptr, zb, N, 256, 256, mb, per, wHi + o1b, wLo + o1b, b1b,
      stats, g1, be1, nullptr, ab, nullptr, nullptr, nullptr);

  // ---- layer 2: act@ab -> h@hb -> z@zb -> act@ab ----
  k_agg<256><<<nb4, 256, 0, stream>>>(ab, hb, rowptr, adj, N, stats);
  k_gemm<0, true, false, true, 0, false, true><<<gg, 256, 0, stream>>>(
      hb, nullptr, nullptr, N, 256, 256, mb, per, wHi + o2a, wLo + o2a, b2a,
      nullptr, nullptr, nullptr, nullptr, zb, nullptr, nullptr, stats);
  k_gemm<3, false, false, true, 2, false, true><<<gg, 256, 0, stream>>>(
      nullptr, nullptr, zb, N, 256, 256, mb, per, wHi + o2b, wLo + o2b, b2b,
      stats, g2, be2, nullptr, ab, nullptr, nullptr, nullptr);

  // ---- layer 3: act@ab -> h@hb -> z@zb -> act@ab ----
  k_agg<256><<<nb4, 256, 0, stream>>>(ab, hb, rowptr, adj, N, stats);
  k_gemm<0, true, false, true, 0, false, true><<<gg, 256, 0, stream>>>(
      hb, nullptr, nullptr, N, 256, 256, mb, per, wHi + o3a, wLo + o3a, b3a,
      nullptr, nullptr, nullptr, nullptr, zb, nullptr, nullptr, stats);
  k_gemm<2, false, false, true, 2, false, true><<<gg, 256, 0, stream>>>(
      nullptr, nullptr, zb, N, 256, 256, mb, per, wHi + o3b, wLo + o3b, b3b,
      stats, g3, be3, nullptr, ab, nullptr, nullptr, nullptr);

  // ---- pool + MFMA heads (heads keep FULL 3-product split) ----
  k_pool<<<G, 256, 0, stream>>>(ab, gs, ge, poolHi, poolLo);
  dim3 gh1(8, 4);   // M=512/64 tiles, N=512/128 col-halves
  k_gemm<1, false, true, false, 0, true, false><<<gh1, 256, 0, stream>>>(
      poolHi, poolLo, nullptr, G, 256, 512, 0, 0, wHi + oh1, wLo + oh1, bh1,
      nullptr, nullptr, nullptr, nullptr, nullptr, thidHi, thidLo, nullptr);
  dim3 gh2(8, 6);   // M=512/64 tiles, N=768/128 col-halves
  k_gemm<0, false, false, false, 0, true, false><<<gh2, 256, 0, stream>>>(
      thidHi, thidLo, nullptr, G, 512, 768, 0, 0, wHi + oh2, wLo + oh2, bh2,
      nullptr, nullptr, nullptr, out, nullptr, nullptr, nullptr, nullptr);
}

// Round 19
// 577.310 us; speedup vs baseline: 1.6179x; 1.0072x over previous
//
#include <hip/hip_runtime.h>

// ---------------------------------------------------------------------------
// GIN GraphEncoder on MI355X.
// R19: FULL REG-STAGED GEMM PIPELINE (T14 everywhere). Main GEMMs no longer
// use global_load_lds (whose in-flight loads force a vmcnt(0) drain at the
// barrier -- the invariant ~6K cyc/iter stall). Each iter: ds_write regs ->
// barrier -> issue NEXT tile's global loads into regs -> MFMA -> barrier.
// HBM/L2 latency rides under MFMA; barrier drains only cheap ds_writes.
// Heads keep gload16 (tiny). Math/order unchanged -> absmax bit-identical.
// R18: BK=64, 24KB LDS, sw8 swizzle. R17: plain-bf16 main path.
// Ledger: BN-fusion -56, 2-product -17, bf16-gather -120, T14(A) -21,
// 64x128 -37, plain-bf16 -15, BK64 -21.
// ---------------------------------------------------------------------------

typedef __attribute__((ext_vector_type(8))) short short8;   // 8 bf16 for MFMA
typedef __attribute__((ext_vector_type(4))) float f32x4;
typedef __attribute__((ext_vector_type(4))) unsigned short us4;
typedef __attribute__((ext_vector_type(8))) unsigned short us8;

__device__ __forceinline__ unsigned short f2bf(float f) {
  unsigned int b = __float_as_uint(f);
  unsigned int r = 0x7FFFu + ((b >> 16) & 1u);   // round-to-nearest-even
  return (unsigned short)((b + r) >> 16);
}
__device__ __forceinline__ float bf2f(unsigned short u) {
  return __uint_as_float(((unsigned int)u) << 16);
}

// bank-spread row swizzle (8-slot domain; LDS rows are 128B = bank space)
__device__ __forceinline__ int sw8(int row) {
  return (row & 7) ^ ((row >> 3) & 7);
}

// global->LDS 16B async copy (heads only); LDS dest is wave-uniform base
typedef const __attribute__((address_space(1))) unsigned int* gas1;
typedef __attribute__((address_space(3))) unsigned int* las3;
__device__ __forceinline__ void gload16(const void* g, void* l) {
  __builtin_amdgcn_global_load_lds((gas1)g, (las3)l, 16, 0, 0);
}

// swizzled flat index of element (row, k), row length K:
// 16B groups XORed within each 64-elem (8-group) block: g' = g ^ sw8(row)
__device__ __forceinline__ size_t swz8_idx(int row, int k, int K) {
  int g = k >> 3;
  return (size_t)row * K + ((g >> 3) << 6) + ((((g & 7) ^ sw8(row)) << 3)) + (k & 7);
}

// ---------------- CSR build + graph bounds (fused) ----------------
__global__ void k_histbounds(const int* __restrict__ ei, int* __restrict__ deg, int E,
                             int eb, const int* __restrict__ batch,
                             int* __restrict__ gs, int* __restrict__ ge, int N) {
  int b = blockIdx.x;
  if (b < eb) {
    int e = b * 256 + threadIdx.x;
    if (e < E) atomicAdd(&deg[ei[E + e]], 1);
  } else {
    int i = (b - eb) * 256 + threadIdx.x;
    if (i < N) {
      int bb = batch[i];
      if (i == 0 || batch[i - 1] != bb) gs[bb] = i;
      if (i == N - 1 || batch[i + 1] != bb) ge[bb] = i + 1;
    }
  }
}

__global__ __launch_bounds__(1024) void k_scan1(const int* __restrict__ deg,
                                                int* __restrict__ partial,
                                                int* __restrict__ bsum, int N) {
  __shared__ int sd[1024];
  int tid = threadIdx.x;
  int i = blockIdx.x * 1024 + tid;
  int v = (i < N) ? deg[i] : 0;
  sd[tid] = v;
  __syncthreads();
  for (int off = 1; off < 1024; off <<= 1) {
    int t = (tid >= off) ? sd[tid - off] : 0;
    __syncthreads();
    sd[tid] += t;
    __syncthreads();
  }
  if (i < N) partial[i] = sd[tid];
  if (tid == 1023) bsum[blockIdx.x] = sd[1023];
}

__global__ void k_scan2(int* __restrict__ bsum, int nb) {
  int l = threadIdx.x;
  int orig = (l < nb) ? bsum[l] : 0;
  int v = orig;
  for (int off = 1; off < 64; off <<= 1) {
    int t = __shfl_up(v, off);
    if (l >= off) v += t;
  }
  if (l < nb) bsum[l] = v - orig;
}

__global__ void k_scan3(const int* __restrict__ deg, const int* __restrict__ partial,
                        const int* __restrict__ bsum, int* __restrict__ rowptr,
                        int* __restrict__ cursor, int N) {
  int i = blockIdx.x * 256 + threadIdx.x;
  if (i >= N) return;
  int incl = partial[i] + bsum[i >> 10];
  rowptr[i + 1] = incl;
  cursor[i] = incl - deg[i];
  if (i == 0) rowptr[0] = 0;
}

__global__ void k_fill(const int* __restrict__ ei, int* __restrict__ cursor,
                       int* __restrict__ adj, int E) {
  int e = blockIdx.x * 256 + threadIdx.x;
  if (e >= E) return;
  int s = ei[e];
  int d = ei[E + e];
  int pos = atomicAdd(&cursor[d], 1);
  adj[pos] = s;
}

// ---- x f32 -> bf16 (one-time; feeds layer-1 gather) ----
__global__ void k_xbf(const float* __restrict__ X, unsigned short* __restrict__ Xb,
                      int total) {
  int t = blockIdx.x * 256 + threadIdx.x;   // one 8-elem group
  if (t * 8 >= total) return;
  const float4 v0 = *(const float4*)(X + t * 8);
  const float4 v1 = *(const float4*)(X + t * 8 + 4);
  us8 o;
  o[0] = f2bf(v0.x); o[1] = f2bf(v0.y); o[2] = f2bf(v0.z); o[3] = f2bf(v0.w);
  o[4] = f2bf(v1.x); o[5] = f2bf(v1.y); o[6] = f2bf(v1.z); o[7] = f2bf(v1.w);
  *(us8*)(Xb + t * 8) = o;
}

// ---- ALL weights: transpose + split + swizzle in ONE kernel ----
__global__ void k_prep_all(const float* __restrict__ w1a, const float* __restrict__ w1b,
                           const float* __restrict__ w2a, const float* __restrict__ w2b,
                           const float* __restrict__ w3a, const float* __restrict__ w3b,
                           const float* __restrict__ wh1, const float* __restrict__ wh2,
                           unsigned short* __restrict__ Hi, unsigned short* __restrict__ Lo) {
  int idx = blockIdx.x * 256 + threadIdx.x;   // [0, 884736)
  const float* W; int K, Nout, lo_;
  if (idx < 32768)       { W = w1a; K = 128; Nout = 256; lo_ = 0; }
  else if (idx < 98304)  { W = w1b; K = 256; Nout = 256; lo_ = 32768; }
  else if (idx < 163840) { W = w2a; K = 256; Nout = 256; lo_ = 98304; }
  else if (idx < 229376) { W = w2b; K = 256; Nout = 256; lo_ = 163840; }
  else if (idx < 294912) { W = w3a; K = 256; Nout = 256; lo_ = 229376; }
  else if (idx < 360448) { W = w3b; K = 256; Nout = 256; lo_ = 294912; }
  else if (idx < 491520) { W = wh1; K = 256; Nout = 512; lo_ = 360448; }
  else                   { W = wh2; K = 512; Nout = 768; lo_ = 491520; }
  int li = idx - lo_;
  int n = li % Nout, k = li / Nout;
  float w = W[k * Nout + n];
  unsigned short h = f2bf(w);
  size_t oi = (size_t)lo_ + swz8_idx(n, k, K);
  Hi[oi] = h;
  Lo[oi] = f2bf(w - bf2f(h));   // only heads read Lo
}

// -------- aggregation: h = Xb[i] + sum Xb[adj[e]] (bf16 gather, f32 acc) ----
// Writes h as single bf16, sw8-swizzled. Block 0 zeroes stats[].
template <int C>
__global__ __launch_bounds__(256) void k_agg(const unsigned short* __restrict__ Xb,
                                             unsigned short* __restrict__ Hb,
                                             const int* __restrict__ rowptr,
                                             const int* __restrict__ adj, int N,
                                             float* __restrict__ statsZ) {
  if (blockIdx.x == 0) {
    statsZ[threadIdx.x] = 0.f;
    statsZ[256 + threadIdx.x] = 0.f;
  }
  int node = blockIdx.x * 4 + (threadIdx.x >> 6);
  if (node >= N) return;
  int lane = threadIdx.x & 63;
  int e0 = rowptr[node], e1 = rowptr[node + 1];
  if constexpr (C == 256) {
    us4 ov = *(const us4*)(Xb + (size_t)node * C + lane * 4);
    float a0 = bf2f(ov[0]), a1 = bf2f(ov[1]), a2 = bf2f(ov[2]), a3 = bf2f(ov[3]);
    int e = e0;
    for (; e + 4 <= e1; e += 4) {
      int s0 = adj[e], s1 = adj[e + 1], s2 = adj[e + 2], s3 = adj[e + 3];
      us4 v0 = *(const us4*)(Xb + (size_t)s0 * C + lane * 4);
      us4 v1 = *(const us4*)(Xb + (size_t)s1 * C + lane * 4);
      us4 v2 = *(const us4*)(Xb + (size_t)s2 * C + lane * 4);
      us4 v3 = *(const us4*)(Xb + (size_t)s3 * C + lane * 4);
      a0 += (bf2f(v0[0]) + bf2f(v1[0])) + (bf2f(v2[0]) + bf2f(v3[0]));
      a1 += (bf2f(v0[1]) + bf2f(v1[1])) + (bf2f(v2[1]) + bf2f(v3[1]));
      a2 += (bf2f(v0[2]) + bf2f(v1[2])) + (bf2f(v2[2]) + bf2f(v3[2]));
      a3 += (bf2f(v0[3]) + bf2f(v1[3])) + (bf2f(v2[3]) + bf2f(v3[3]));
    }
    for (; e < e1; ++e) {
      us4 v = *(const us4*)(Xb + (size_t)adj[e] * C + lane * 4);
      a0 += bf2f(v[0]); a1 += bf2f(v[1]); a2 += bf2f(v[2]); a3 += bf2f(v[3]);
    }
    us4 hv;
    hv[0] = f2bf(a0); hv[1] = f2bf(a1); hv[2] = f2bf(a2); hv[3] = f2bf(a3);
    size_t oi = (size_t)node * 256 + ((lane >> 4) << 6) +
                ((((lane >> 1) & 7) ^ sw8(node)) << 3) + ((lane & 1) << 2);
    *(us4*)(Hb + oi) = hv;
  } else {  // C == 128
    ushort2 ov = *(const ushort2*)(Xb + (size_t)node * C + lane * 2);
    float a0 = bf2f(ov.x), a1 = bf2f(ov.y);
    int e = e0;
    for (; e + 4 <= e1; e += 4) {
      int s0 = adj[e], s1 = adj[e + 1], s2 = adj[e + 2], s3 = adj[e + 3];
      ushort2 v0 = *(const ushort2*)(Xb + (size_t)s0 * C + lane * 2);
      ushort2 v1 = *(const ushort2*)(Xb + (size_t)s1 * C + lane * 2);
      ushort2 v2 = *(const ushort2*)(Xb + (size_t)s2 * C + lane * 2);
      ushort2 v3 = *(const ushort2*)(Xb + (size_t)s3 * C + lane * 2);
      a0 += (bf2f(v0.x) + bf2f(v1.x)) + (bf2f(v2.x) + bf2f(v3.x));
      a1 += (bf2f(v0.y) + bf2f(v1.y)) + (bf2f(v2.y) + bf2f(v3.y));
    }
    for (; e < e1; ++e) {
      ushort2 v = *(const ushort2*)(Xb + (size_t)adj[e] * C + lane * 2);
      a0 += bf2f(v.x); a1 += bf2f(v.y);
    }
    ushort2 hv = {f2bf(a0), f2bf(a1)};
    size_t oi = (size_t)node * 128 + ((lane >> 5) << 6) +
                ((((lane >> 2) & 7) ^ sw8(node)) << 3) + ((lane & 3) << 1);
    *(ushort2*)(Hb + oi) = hv;
  }
}

// ------------ MFMA GEMM: 64x128 tile, BK=64, reg-staged pipeline ------------
// FULL=false (main): 1-product bf16 x bf16, LDS 24KB, REG-STAGED:
//   prologue loads tile0 regs; iter = {ds_write regs, bar, issue next-tile
//   loads, MFMA, bar}. ASRC: 0 = swizzled Hb/act (linear copy to LDS);
//   2 = plain bf16 z + BN+relu applied in WRITE phase (swizzled ds_write).
// FULL=true (heads): 3-product split via gload16 (unchanged).
// EPI: 0 none, 1 relu, 2 tanh, 3 relu(tanh). OBF16: bf16 out (z / act).
// OSPLIT: split+swizzled out (head1, relu). STATS: fused BN sum/sumsq.
// XSWZ: XCD-pair swizzle.
template <int EPI, bool STATS, bool OSPLIT, bool XSWZ, int ASRC, bool FULL, bool OBF16>
__global__ __launch_bounds__(256) void k_gemm(
    const unsigned short* __restrict__ AHb, const unsigned short* __restrict__ ALo,
    const unsigned short* __restrict__ Zb,
    int M, int K, int Nld, int mb, int per,
    const unsigned short* __restrict__ WHi, const unsigned short* __restrict__ WLo,
    const float* __restrict__ bias,
    const float* __restrict__ statsIn, const float* __restrict__ gvec,
    const float* __restrict__ bevec,
    float* __restrict__ Out, unsigned short* __restrict__ OutB,
    unsigned short* __restrict__ OHi, unsigned short* __restrict__ OLo,
    float* __restrict__ statsOut) {
  __shared__ unsigned short aHi[4096], bHi[8192];             // 8K + 16K bytes
  __shared__ unsigned short aLo[FULL ? 4096 : 64], bLo[FULL ? 8192 : 64];
  __shared__ float sBNsc[ASRC == 2 ? 256 : 1], sBNsh[ASRC == 2 ? 256 : 1];
  int bx, by;
  if constexpr (XSWZ) {
    int xcd = blockIdx.x & 7, slot = blockIdx.x >> 3;
    bx = xcd * per + (slot >> 1);
    by = slot & 1;
    if (bx >= mb) return;
  } else {
    bx = blockIdx.x;
    by = blockIdx.y;
  }
  const int tid = threadIdx.x;
  const int lane = tid & 63, w = tid >> 6;
  const int wm = w >> 1, wn = w & 1;
  const int m0 = bx * 64, n0 = by * 128;

  if constexpr (ASRC == 2) {
    float mu = statsIn[tid] / (float)M;
    float var = statsIn[256 + tid] / (float)M - mu * mu;
    float sc = gvec[tid] * rsqrtf(var + 1e-5f);
    sBNsc[tid] = sc;
    sBNsh[tid] = bevec[tid] - mu * sc;
    __syncthreads();   // publish BN consts before first WRITE phase
  }

  f32x4 zero = {0.f, 0.f, 0.f, 0.f};
  f32x4 acc[2][4];
#pragma unroll
  for (int i = 0; i < 2; ++i)
#pragma unroll
    for (int j = 0; j < 4; ++j) acc[i][j] = zero;

  const int l8 = lane >> 3;     // row sub-index in gload staging (heads)
  const int s8 = lane & 7;

  // ---- reg-staging state (main path) ----
  us8 arg[2], brg[4];
  const unsigned short* aptr[2];
  const unsigned short* bptr[4];
  if constexpr (!FULL) {
    const unsigned short* asrc = (ASRC == 2) ? Zb : AHb;
#pragma unroll
    for (int p = 0; p < 2; ++p) {
      int row = (p << 5) + (tid >> 3);
      int ra = m0 + row; if (ra >= M) ra = M - 1;    // clamp (junk never stored)
      aptr[p] = asrc + (size_t)ra * K + (tid & 7) * 8;
      arg[p] = *(const us8*)(aptr[p]);
    }
#pragma unroll
    for (int q = 0; q < 4; ++q) {
      int row = (q << 5) + (tid >> 3);
      bptr[q] = WHi + (size_t)(n0 + row) * K + (tid & 7) * 8;
      brg[q] = *(const us8*)(bptr[q]);
    }
  }

  for (int kb = 0; kb < K; kb += 64) {
    if constexpr (!FULL) {
      // ---- WRITE phase: regs -> LDS ----
      if constexpr (ASRC == 2) {
#pragma unroll
        for (int p = 0; p < 2; ++p) {
          int row = (p << 5) + (tid >> 3), gq = tid & 7;
          us8 hv;
#pragma unroll
          for (int jj = 0; jj < 8; ++jj) {
            int kc = kb + gq * 8 + jj;
            float o = fmaxf(bf2f(arg[p][jj]) * sBNsc[kc] + sBNsh[kc], 0.f);
            hv[jj] = f2bf(o);
          }
          int bo = row * 128 + ((gq ^ sw8(row)) << 4);   // apply swizzle (z is flat)
          *(us8*)((char*)aHi + bo) = hv;
        }
      } else {
#pragma unroll
        for (int p = 0; p < 2; ++p) {
          int row = (p << 5) + (tid >> 3);
          int bo = row * 128 + ((tid & 7) << 4);          // linear (src pre-swizzled)
          *(us8*)((char*)aHi + bo) = arg[p];
        }
      }
#pragma unroll
      for (int q = 0; q < 4; ++q) {
        int row = (q << 5) + (tid >> 3);
        int bo = row * 128 + ((tid & 7) << 4);            // linear (src pre-swizzled)
        *(us8*)((char*)bHi + bo) = brg[q];
      }
      __syncthreads();
      // ---- T14: issue next tile's loads; they complete under MFMA ----
      if (kb + 64 < K) {
#pragma unroll
        for (int p = 0; p < 2; ++p) arg[p] = *(const us8*)(aptr[p] + kb + 64);
#pragma unroll
        for (int q = 0; q < 4; ++q) brg[q] = *(const us8*)(bptr[q] + kb + 64);
      }
    } else {
      // ---- heads: gload16 staging (3-product split) ----
      __syncthreads();
#pragma unroll
      for (int q = 0; q < 2; ++q) {
        int row = (w << 4) + (q << 3) + l8;
        int ra = m0 + row; if (ra >= M) ra = M - 1;
        size_t ga = (size_t)ra * K + kb + s8 * 8;
        unsigned boA = (w << 11) + (q << 10);
        gload16(AHb + ga, (char*)aHi + boA);
        gload16(ALo + ga, (char*)aLo + boA);
      }
#pragma unroll
      for (int q = 0; q < 4; ++q) {
        int row = (w << 5) + (q << 3) + l8;
        size_t gb = (size_t)(n0 + row) * K + kb + s8 * 8;
        unsigned bo2 = (w << 12) + (q << 10);
        gload16(WHi + gb, (char*)bHi + bo2);
        gload16(WLo + gb, (char*)bLo + bo2);
      }
      __syncthreads();
    }

    // ---- COMPUTE phase ----
    const int j = lane >> 4;
#pragma unroll
    for (int kk = 0; kk < 2; ++kk) {
      int g = (kk << 2) + j;        // 16B group within 64-elem row
      short8 bh[4], bl[4];
#pragma unroll
      for (int ni = 0; ni < 4; ++ni) {
        int r = wn * 64 + ni * 16 + (lane & 15);
        int bo = r * 128 + ((g ^ sw8(r)) << 4);
        bh[ni] = *(const short8*)((const char*)bHi + bo);
        if constexpr (FULL) bl[ni] = *(const short8*)((const char*)bLo + bo);
      }
#pragma unroll
      for (int mi = 0; mi < 2; ++mi) {
        int r = wm * 32 + mi * 16 + (lane & 15);
        int bo = r * 128 + ((g ^ sw8(r)) << 4);
        short8 ah = *(const short8*)((const char*)aHi + bo);
#pragma unroll
        for (int ni = 0; ni < 4; ++ni) {
          acc[mi][ni] = __builtin_amdgcn_mfma_f32_16x16x32_bf16(ah, bh[ni], acc[mi][ni], 0, 0, 0);
          if constexpr (FULL) {
            short8 al = *(const short8*)((const char*)aLo + bo);
            acc[mi][ni] = __builtin_amdgcn_mfma_f32_16x16x32_bf16(ah, bl[ni], acc[mi][ni], 0, 0, 0);
            acc[mi][ni] = __builtin_amdgcn_mfma_f32_16x16x32_bf16(al, bh[ni], acc[mi][ni], 0, 0, 0);
          }
        }
      }
    }
    if constexpr (!FULL) __syncthreads();   // release LDS for next WRITE
  }

  // epilogue: C/D layout col = lane&15, row = (lane>>4)*4 + r   [m89-verified]
#pragma unroll
  for (int ni = 0; ni < 4; ++ni) {
    int col = n0 + wn * 64 + ni * 16 + (lane & 15);
    float bc = bias[col];
    float s = 0.f, q = 0.f;
#pragma unroll
    for (int mi = 0; mi < 2; ++mi) {
      int rbase = m0 + wm * 32 + mi * 16 + (lane >> 4) * 4;
#pragma unroll
      for (int r = 0; r < 4; ++r) {
        int row = rbase + r;
        if (row < M) {
          float o = acc[mi][ni][r] + bc;
          if (STATS) { s += o; q += o * o; }
          if (OSPLIT) {
            o = fmaxf(o, 0.f);   // relu (head1)
            unsigned short h = f2bf(o);
            size_t oi = swz8_idx(row, col, Nld);
            OHi[oi] = h;
            OLo[oi] = f2bf(o - bf2f(h));
          } else {
            if (EPI == 1) o = fmaxf(o, 0.f);
            else if (EPI == 2) o = tanhf(o);
            else if (EPI == 3) o = fmaxf(tanhf(o), 0.f);
            if (OBF16) OutB[(size_t)row * Nld + col] = f2bf(o);
            else       Out[(size_t)row * Nld + col] = o;
          }
        }
      }
    }
    if (STATS) {
      s += __shfl_xor(s, 16); s += __shfl_xor(s, 32);
      q += __shfl_xor(q, 16); q += __shfl_xor(q, 32);
      if ((lane >> 4) == 0) {
        atomicAdd(&statsOut[col], s);
        atomicAdd(&statsOut[256 + col], q);
      }
    }
  }
}

// ---------------- pooling (bf16 input, split output for heads) ----------------
__global__ __launch_bounds__(256) void k_pool(const unsigned short* __restrict__ Hb,
                                              const int* __restrict__ gs,
                                              const int* __restrict__ ge,
                                              unsigned short* __restrict__ PHi,
                                              unsigned short* __restrict__ PLo) {
  __shared__ float4 red[4][64];
  int gi = blockIdx.x;
  int s = gs[gi], e = ge[gi];
  int w = threadIdx.x >> 6, lane = threadIdx.x & 63;
  float4 acc = {0.f, 0.f, 0.f, 0.f};
  for (int r = s + w; r < e; r += 4) {
    us4 v = *(const us4*)(Hb + (size_t)r * 256 + lane * 4);
    acc.x += bf2f(v[0]); acc.y += bf2f(v[1]);
    acc.z += bf2f(v[2]); acc.w += bf2f(v[3]);
  }
  red[w][lane] = acc;
  __syncthreads();
  if (w == 0) {
    float4 a = red[0][lane], b = red[1][lane], c = red[2][lane], d = red[3][lane];
    float inv = 1.0f / fmaxf((float)(e - s), 1.0f);
    float vv[4] = {(a.x + b.x + c.x + d.x) * inv, (a.y + b.y + c.y + d.y) * inv,
                   (a.z + b.z + c.z + d.z) * inv, (a.w + b.w + c.w + d.w) * inv};
    us4 hv, lv;
#pragma unroll
    for (int j = 0; j < 4; ++j) {
      unsigned short h = f2bf(vv[j]);
      hv[j] = h;
      lv[j] = f2bf(vv[j] - bf2f(h));
    }
    size_t oi = (size_t)gi * 256 + ((lane >> 4) << 6) +
                ((((lane >> 1) & 7) ^ sw8(gi)) << 3) + ((lane & 1) << 2);
    *(us4*)(PHi + oi) = hv;
    *(us4*)(PLo + oi) = lv;
  }
}

// ---------------------------------------------------------------------------
extern "C" void kernel_launch(void* const* d_in, const int* in_sizes, int n_in,
                              void* d_out, int out_size, void* d_ws, size_t ws_size,
                              hipStream_t stream) {
  const float* x      = (const float*)d_in[0];
  const int* ei       = (const int*)d_in[1];    // int32 from harness
  const int* bat      = (const int*)d_in[2];    // int32 from harness
  const float* w1a = (const float*)d_in[3];  const float* b1a = (const float*)d_in[4];
  const float* g1  = (const float*)d_in[5];  const float* be1 = (const float*)d_in[6];
  const float* w1b = (const float*)d_in[7];  const float* b1b = (const float*)d_in[8];
  const float* w2a = (const float*)d_in[9];  const float* b2a = (const float*)d_in[10];
  const float* g2  = (const float*)d_in[11]; const float* be2 = (const float*)d_in[12];
  const float* w2b = (const float*)d_in[13]; const float* b2b = (const float*)d_in[14];
  const float* w3a = (const float*)d_in[15]; const float* b3a = (const float*)d_in[16];
  const float* g3  = (const float*)d_in[17]; const float* be3 = (const float*)d_in[18];
  const float* w3b = (const float*)d_in[19]; const float* b3b = (const float*)d_in[20];
  const float* wh1 = (const float*)d_in[21]; const float* bh1 = (const float*)d_in[22];
  const float* wh2 = (const float*)d_in[23]; const float* bh2 = (const float*)d_in[24];
  float* out = (float*)d_out;

  const int N = in_sizes[0] / 128;   // 50000
  const int E = in_sizes[1] / 2;     // 800000
  const int G = 512;

  // ---- workspace: 3 bf16 buffers (h swz | z | act) + bf16 x ----
  char* ws = (char*)d_ws;
  size_t off = 0;
  auto alloc = [&](size_t bytes) {
    void* p = ws + off;
    off = (off + bytes + 255) & ~(size_t)255;
    return p;
  };
  unsigned short* hb = (unsigned short*)alloc((size_t)N * 256 * 2);
  unsigned short* zb = (unsigned short*)alloc((size_t)N * 256 * 2);
  unsigned short* ab = (unsigned short*)alloc((size_t)N * 256 * 2);
  unsigned short* xb = (unsigned short*)alloc((size_t)N * 128 * 2);
  int* adj     = (int*)alloc((size_t)E * 4);
  int* rowptr  = (int*)alloc((size_t)(N + 1) * 4);
  int* cursor  = (int*)alloc((size_t)N * 4);
  int* deg     = (int*)alloc((size_t)N * 4);
  int* partial = (int*)alloc((size_t)N * 4);
  int* bsum    = (int*)alloc(64 * 4);
  unsigned short* wHi = (unsigned short*)alloc(884736 * 2);
  unsigned short* wLo = (unsigned short*)alloc(884736 * 2);
  float* stats = (float*)alloc(512 * 4);
  int* gs      = (int*)alloc(G * 4);
  int* ge      = (int*)alloc(G * 4);
  unsigned short* poolHi = (unsigned short*)alloc((size_t)G * 256 * 2);
  unsigned short* poolLo = (unsigned short*)alloc((size_t)G * 256 * 2);
  unsigned short* thidHi = (unsigned short*)alloc((size_t)G * 512 * 2);
  unsigned short* thidLo = (unsigned short*)alloc((size_t)G * 512 * 2);

  // transposed-weight element offsets (match k_prep_all segment table)
  const int o1a = 0, o1b = 32768, o2a = 98304, o2b = 163840, o3a = 229376, o3b = 294912;
  const int oh1 = 360448, oh2 = 491520;   // ends at 884736

  hipMemsetAsync(deg, 0, (size_t)N * 4, stream);
  hipMemsetAsync(gs, 0, (size_t)G * 4, stream);
  hipMemsetAsync(ge, 0, (size_t)G * 4, stream);

  int eb = (E + 255) / 256;
  int nbN = (N + 255) / 256;
  int nb1 = (N + 1023) >> 10;   // 49 (<=64 required by k_scan2)
  k_histbounds<<<eb + nbN, 256, 0, stream>>>(ei, deg, E, eb, bat, gs, ge, N);
  k_scan1<<<nb1, 1024, 0, stream>>>(deg, partial, bsum, N);
  k_scan2<<<1, 64, 0, stream>>>(bsum, nb1);
  k_scan3<<<nbN, 256, 0, stream>>>(deg, partial, bsum, rowptr, cursor, N);
  k_fill<<<eb, 256, 0, stream>>>(ei, cursor, adj, E);

  k_xbf<<<(N * 128 / 8 + 255) / 256, 256, 0, stream>>>(x, xb, N * 128);
  k_prep_all<<<3456, 256, 0, stream>>>(w1a, w1b, w2a, w2b, w3a, w3b, wh1, wh2, wHi, wLo);

  int nb4 = (N + 3) / 4;
  const int mb = (N + 63) / 64;          // 782 M-tiles of 64 rows
  const int per = (mb + 7) / 8;          // 98
  dim3 gg(per * 16);                     // XCD-pair swizzled flat grid (1568)

  // ---- layer 1: xb -> h@hb -> z@zb -> act@ab ----
  k_agg<128><<<nb4, 256, 0, stream>>>(xb, hb, rowptr, adj, N, stats);
  k_gemm<0, true, false, true, 0, false, true><<<gg, 256, 0, stream>>>(
      hb, nullptr, nullptr, N, 128, 256, mb, per, wHi + o1a, wLo + o1a, b1a,
      nullptr, nullptr, nullptr, nullptr, zb, nullptr, nullptr, stats);
  k_gemm<1, false, false, true, 2, false, true><<<gg, 256, 0, stream>>>(
      nullptr, nullptr, zb, N, 256, 256, mb, per, wHi + o1b, wLo + o1b, b1b,
      stats, g1, be1, nullptr, ab, nullptr, nullptr, nullptr);

  // ---- layer 2: act@ab -> h@hb -> z@zb -> act@ab ----
  k_agg<256><<<nb4, 256, 0, stream>>>(ab, hb, rowptr, adj, N, stats);
  k_gemm<0, true, false, true, 0, false, true><<<gg, 256, 0, stream>>>(
      hb, nullptr, nullptr, N, 256, 256, mb, per, wHi + o2a, wLo + o2a, b2a,
      nullptr, nullptr, nullptr, nullptr, zb, nullptr, nullptr, stats);
  k_gemm<3, false, false, true, 2, false, true><<<gg, 256, 0, stream>>>(
      nullptr, nullptr, zb, N, 256, 256, mb, per, wHi + o2b, wLo + o2b, b2b,
      stats, g2, be2, nullptr, ab, nullptr, nullptr, nullptr);

  // ---- layer 3: act@ab -> h@hb -> z@zb -> act@ab ----
  k_agg<256><<<nb4, 256, 0, stream>>>(ab, hb, rowptr, adj, N, stats);
  k_gemm<0, true, false, true, 0, false, true><<<gg, 256, 0, stream>>>(
      hb, nullptr, nullptr, N, 256, 256, mb, per, wHi + o3a, wLo + o3a, b3a,
      nullptr, nullptr, nullptr, nullptr, zb, nullptr, nullptr, stats);
  k_gemm<2, false, false, true, 2, false, true><<<gg, 256, 0, stream>>>(
      nullptr, nullptr, zb, N, 256, 256, mb, per, wHi + o3b, wLo + o3b, b3b,
      stats, g3, be3, nullptr, ab, nullptr, nullptr, nullptr);

  // ---- pool + MFMA heads (heads keep FULL 3-product split) ----
  k_pool<<<G, 256, 0, stream>>>(ab, gs, ge, poolHi, poolLo);
  dim3 gh1(8, 4);   // M=512/64 tiles, N=512/128 col-halves
  k_gemm<1, false, true, false, 0, true, false><<<gh1, 256, 0, stream>>>(
      poolHi, poolLo, nullptr, G, 256, 512, 0, 0, wHi + oh1, wLo + oh1, bh1,
      nullptr, nullptr, nullptr, nullptr, nullptr, thidHi, thidLo, nullptr);
  dim3 gh2(8, 6);   // M=512/64 tiles, N=768/128 col-halves
  k_gemm<0, false, false, false, 0, true, false><<<gh2, 256, 0, stream>>>(
      thidHi, thidLo, nullptr, G, 512, 768, 0, 0, wHi + oh2, wLo + oh2, bh2,
      nullptr, nullptr, nullptr, out, nullptr, nullptr, nullptr, nullptr);
}